// Round 1
// 569.090 us; speedup vs baseline: 1.0257x; 1.0257x over previous
//
#include <hip/hip_runtime.h>
#include <math.h>

#define D 128
#define WS_PAD 132  // 128+4: breaks stride-128 bank pattern, keeps 16B align

typedef short bf16x8 __attribute__((ext_vector_type(8)));  // 8 bf16 in 4 VGPRs
typedef float f32x4 __attribute__((ext_vector_type(4)));

__device__ __forceinline__ unsigned short f2bf(float f) {
  unsigned u = __float_as_uint(f);
  u += 0x7FFFu + ((u >> 16) & 1u);  // round-to-nearest-even
  return (unsigned short)(u >> 16);
}

// ---------------- degree count (+ fused W2->bf16 conversion in extra blocks) ----------------

__global__ __launch_bounds__(256) void count_deg_kernel(const int* __restrict__ dst, int E,
                                                        int* __restrict__ deg,
                                                        const float* __restrict__ W2,
                                                        unsigned short* __restrict__ W2bf) {
  int nbe = (E + 255) >> 8;
  int b = blockIdx.x;
  if (b >= nbe) {
    // 8 extra blocks: convert W2 (128x128 fp32) -> bf16 once, overlapped with atomics.
    if (W2bf != nullptr) {
      int t = (b - nbe) * 256 + threadIdx.x;  // 0..2047
      #pragma unroll
      for (int q = 0; q < 2; ++q) {
        int idx = t + q * 2048;  // float4 index, 0..4095
        float4 w = ((const float4*)W2)[idx];
        ushort4 o;
        o.x = f2bf(w.x); o.y = f2bf(w.y); o.z = f2bf(w.z); o.w = f2bf(w.w);
        ((ushort4*)W2bf)[idx] = o;
      }
    }
    return;
  }
  int e = b * 256 + threadIdx.x;
  if (e < E) atomicAdd(&deg[dst[e]], 1);
}

// ---------------- exclusive prefix scan of deg -> ptr ----------------

__global__ __launch_bounds__(256) void scan_blocksum_kernel(const int* __restrict__ deg, int n,
                                                            int* __restrict__ blockSums) {
  __shared__ int sm[256];
  int t = threadIdx.x;
  int i = blockIdx.x * 256 + t;
  sm[t] = (i < n) ? deg[i] : 0;
  __syncthreads();
  for (int off = 128; off > 0; off >>= 1) {
    if (t < off) sm[t] += sm[t + off];
    __syncthreads();
  }
  if (t == 0) blockSums[blockIdx.x] = sm[0];
}

// single block, 512 threads; nb <= 512
__global__ __launch_bounds__(512) void scan_top_kernel(int* __restrict__ blockSums, int nb) {
  __shared__ int sm[512];
  int t = threadIdx.x;
  int v = (t < nb) ? blockSums[t] : 0;
  sm[t] = v;
  __syncthreads();
  for (int off = 1; off < 512; off <<= 1) {
    int x = (t >= off) ? sm[t - off] : 0;
    __syncthreads();
    sm[t] += x;
    __syncthreads();
  }
  if (t < nb) blockSums[t] = sm[t] - v;  // exclusive
}

// also computes dinv (fused to save a launch)
__global__ __launch_bounds__(256) void scan_write_kernel(const int* __restrict__ deg, int n,
                                                         const int* __restrict__ blockSums,
                                                         int* __restrict__ ptr,
                                                         float* __restrict__ dinv) {
  __shared__ int sm[256];
  int t = threadIdx.x;
  int i = blockIdx.x * 256 + t;
  int v = (i < n) ? deg[i] : 0;
  sm[t] = v;
  __syncthreads();
  for (int off = 1; off < 256; off <<= 1) {
    int x = (t >= off) ? sm[t - off] : 0;
    __syncthreads();
    sm[t] += x;
    __syncthreads();
  }
  if (i < n) {
    ptr[i] = blockSums[blockIdx.x] + sm[t] - v;  // exclusive prefix
    dinv[i] = 1.0f / sqrtf((float)(v + 1));      // +1: self-loop
  }
}

// ---------------- shared GEMM body: H[n,128](bf16) = dinv[i] * (X @ W^T) ----------------

__device__ __forceinline__ void gemm_body(const float* __restrict__ X,
                                          const float* __restrict__ W,
                                          const float* __restrict__ dinv,
                                          unsigned short* __restrict__ H, int n,
                                          int bid, int nblocks,
                                          float* __restrict__ Ws, float* __restrict__ Xs) {
  const int tid = threadIdx.x;
  const int tx = tid & 31;
  const int ty = tid >> 5;
  const int ntiles = (n + 31) >> 5;

  for (int tile = bid; tile < ntiles; tile += nblocks) {
    const int row0 = tile << 5;
    const int rows_here = min(32, n - row0);
    __syncthreads();
    {
      const float4* Xg = (const float4*)(X + (size_t)row0 * D);
      int tmax = rows_here * 32;
      for (int t = tid; t < tmax; t += 256) ((float4*)Xs)[t] = Xg[t];
    }
    float acc[4][4] = {{0.f}};
    #pragma unroll
    for (int kt = 0; kt < 128; kt += 64) {
      __syncthreads();
      for (int t = tid; t < 2048; t += 256) {
        int j  = t >> 4;
        int k4 = (t & 15) << 2;
        float4 w = ((const float4*)W)[j * 32 + (kt >> 2) + (t & 15)];
        Ws[(k4 + 0) * WS_PAD + j] = w.x;
        Ws[(k4 + 1) * WS_PAD + j] = w.y;
        Ws[(k4 + 2) * WS_PAD + j] = w.z;
        Ws[(k4 + 3) * WS_PAD + j] = w.w;
      }
      __syncthreads();
      #pragma unroll 4
      for (int k = 0; k < 64; ++k) {
        float4 w = *(const float4*)&Ws[k * WS_PAD + (tx << 2)];
        #pragma unroll
        for (int r = 0; r < 4; ++r) {
          float xv = Xs[(ty + 8 * r) * 128 + (kt + k)];
          acc[r][0] += xv * w.x;
          acc[r][1] += xv * w.y;
          acc[r][2] += xv * w.z;
          acc[r][3] += xv * w.w;
        }
      }
    }
    #pragma unroll
    for (int r = 0; r < 4; ++r) {
      int row = row0 + ty + 8 * r;
      if (row < n) {
        float s = dinv[row];
        unsigned h0 = f2bf(s * acc[r][0]);
        unsigned h1 = f2bf(s * acc[r][1]);
        unsigned h2 = f2bf(s * acc[r][2]);
        unsigned h3 = f2bf(s * acc[r][3]);
        ((uint2*)(H + (size_t)row * D))[tx] = make_uint2(h0 | (h1 << 16), h2 | (h3 << 16));
      }
    }
  }
}

// ---------------- fused: CSR fill (atomic-latency-bound) || GEMM1 (VALU-bound) ----------------

#define FUSED_GRID 2048

__global__ __launch_bounds__(256) void fused_fill_gemm_kernel(
    const int* __restrict__ src, const int* __restrict__ dst,
    int* __restrict__ ptr, int* __restrict__ csr, int E,
    const float* __restrict__ X, const float* __restrict__ W,
    const float* __restrict__ dinv, unsigned short* __restrict__ H, int n) {
  __shared__ float Ws[64 * WS_PAD];
  __shared__ float Xs[32 * 128];
  int sub = blockIdx.x & 7;
  if (sub < 2) {
    int fb = (blockIdx.x >> 3) * 2 + sub;
    int stride = 512 * 256;
    for (int e = fb * 256 + threadIdx.x; e < E; e += stride) {
      int d = dst[e];
      int pos = atomicAdd(&ptr[d], 1);
      csr[pos] = src[e];
    }
  } else {
    int gb = (blockIdx.x >> 3) * 6 + (sub - 2);
    gemm_body(X, W, dinv, H, n, gb, 1536, Ws, Xs);
  }
}

__global__ __launch_bounds__(256) void gemm128_kernel(const float* __restrict__ X,
                                                      const float* __restrict__ W,
                                                      const float* __restrict__ dinv,
                                                      unsigned short* __restrict__ H, int n) {
  __shared__ float Ws[64 * WS_PAD];
  __shared__ float Xs[32 * 128];
  gemm_body(X, W, dinv, H, n, blockIdx.x, gridDim.x, Ws, Xs);
}

// ---------------- gather helper: accumulate row i of Hs (bf16) ----------------

__device__ __forceinline__ void gather_row(const int* __restrict__ csr,
                                           const int* __restrict__ rend,
                                           const unsigned* __restrict__ Hu,
                                           int i, int lane, float& ax, float& ay) {
  int start = (i == 0) ? 0 : rend[i - 1];
  int end = rend[i];
  unsigned v = Hu[(size_t)i * 64 + lane];  // self-loop term
  ax = __uint_as_float(v << 16);
  ay = __uint_as_float(v & 0xFFFF0000u);
  int e = start;
  for (; e + 8 <= end; e += 8) {
    unsigned w0 = Hu[(size_t)csr[e + 0] * 64 + lane];
    unsigned w1 = Hu[(size_t)csr[e + 1] * 64 + lane];
    unsigned w2 = Hu[(size_t)csr[e + 2] * 64 + lane];
    unsigned w3 = Hu[(size_t)csr[e + 3] * 64 + lane];
    unsigned w4 = Hu[(size_t)csr[e + 4] * 64 + lane];
    unsigned w5 = Hu[(size_t)csr[e + 5] * 64 + lane];
    unsigned w6 = Hu[(size_t)csr[e + 6] * 64 + lane];
    unsigned w7 = Hu[(size_t)csr[e + 7] * 64 + lane];
    ax += __uint_as_float(w0 << 16) + __uint_as_float(w1 << 16) +
          __uint_as_float(w2 << 16) + __uint_as_float(w3 << 16) +
          __uint_as_float(w4 << 16) + __uint_as_float(w5 << 16) +
          __uint_as_float(w6 << 16) + __uint_as_float(w7 << 16);
    ay += __uint_as_float(w0 & 0xFFFF0000u) + __uint_as_float(w1 & 0xFFFF0000u) +
          __uint_as_float(w2 & 0xFFFF0000u) + __uint_as_float(w3 & 0xFFFF0000u) +
          __uint_as_float(w4 & 0xFFFF0000u) + __uint_as_float(w5 & 0xFFFF0000u) +
          __uint_as_float(w6 & 0xFFFF0000u) + __uint_as_float(w7 & 0xFFFF0000u);
  }
  for (; e < end; ++e) {
    unsigned w = Hu[(size_t)csr[e] * 64 + lane];
    ax += __uint_as_float(w << 16);
    ay += __uint_as_float(w & 0xFFFF0000u);
  }
}

// ---------------- standalone gather (final layer / fallback) ----------------

__global__ __launch_bounds__(256, 8) void gather_kernel(const int* __restrict__ csr,
                                                        const int* __restrict__ rend,
                                                        const float* __restrict__ dinv,
                                                        const unsigned* __restrict__ Hu,
                                                        const float* __restrict__ bias,
                                                        const float* __restrict__ perturb,
                                                        float* __restrict__ out, int n) {
  int i = (blockIdx.x << 2) + (threadIdx.x >> 6);
  if (i >= n) return;
  int lane = threadIdx.x & 63;
  float ax, ay;
  gather_row(csr, rend, Hu, i, lane, ax, ay);
  float di = dinv[i];
  float2 p = ((const float2*)(perturb + (size_t)i * D))[lane];
  float2 o;
  o.x = bias[2 * lane + 0] + p.x + di * ax;
  o.y = bias[2 * lane + 1] + p.y + di * ay;
  ((float2*)(out + (size_t)i * D))[lane] = o;
}

// ---------------- fused gather1 + GEMM2 (MFMA bf16) ----------------
// Block of 512 threads handles 32 nodes:
//  phase 1: 8 waves x 4 nodes gather -> out1 rows (fp32) -> bf16 LDS tile Ts[32][128]
//  phase 2: H2s[i] = dinv[i] * (Ts @ W2bf^T) via mfma_f32_16x16x32_bf16
// W2 is NOT staged in LDS: it's a 32 KB bf16 table pre-converted once (count_deg
// extra blocks) and read-shared by all blocks via L1/L2. This drops LDS from
// 43.5 KB -> 8.7 KB, lifting occupancy from 3 blocks/CU (24 waves) to the
// 32-wave cap (4 blocks/CU) -- phase 1's random-row gather is latency-bound
// and needs the extra waves in flight. __launch_bounds__(512,8) pins the
// allocator at <=64 VGPR (current use: 40).

#define GG_PITCH 136

__global__ __launch_bounds__(512, 8) void gather_gemm_kernel(
    const int* __restrict__ csr, const int* __restrict__ rend,
    const float* __restrict__ dinv, const unsigned* __restrict__ Hu,
    const float* __restrict__ bias, const float* __restrict__ perturb,
    const unsigned short* __restrict__ W2bf, unsigned short* __restrict__ H2, int n) {
  __shared__ unsigned short Ts[32 * GG_PITCH];  // 8.5 KB
  const int tid = threadIdx.x;
  const int wv = tid >> 6;
  const int lane = tid & 63;
  const int base = blockIdx.x << 5;  // 32 nodes per block

  // phase 1: gather 4 nodes per wave -> Ts
  #pragma unroll
  for (int j = 0; j < 4; ++j) {
    int row = (wv << 2) + j;
    int i = base + row;
    if (i < n) {
      float ax, ay;
      gather_row(csr, rend, Hu, i, lane, ax, ay);
      float di = dinv[i];
      float2 p = ((const float2*)(perturb + (size_t)i * D))[lane];
      float ox = bias[2 * lane + 0] + p.x + di * ax;
      float oy = bias[2 * lane + 1] + p.y + di * ay;
      unsigned pack = (unsigned)f2bf(ox) | ((unsigned)f2bf(oy) << 16);
      *(unsigned*)&Ts[row * GG_PITCH + (lane << 1)] = pack;
    }
  }
  __syncthreads();

  // phase 2: R[32][128] = Ts @ W2bf^T ; wave wv: m-tile = wv>>2, n-tiles {wv&3, (wv&3)+4}
  const int mt = wv >> 2;
  const int nt0 = wv & 3;
  const int m = lane & 15;
  const int quad = lane >> 4;  // 0..3
  const unsigned short* Wrow0 = W2bf + (size_t)(nt0 * 16 + m) * 128;
  const unsigned short* Wrow1 = W2bf + (size_t)((nt0 + 4) * 16 + m) * 128;
  f32x4 acc0 = {0.f, 0.f, 0.f, 0.f};
  f32x4 acc1 = {0.f, 0.f, 0.f, 0.f};
  #pragma unroll
  for (int s = 0; s < 4; ++s) {
    int k = (s << 5) + (quad << 3);
    bf16x8 a  = *(const bf16x8*)&Ts[(mt * 16 + m) * GG_PITCH + k];
    bf16x8 b0 = *(const bf16x8*)&Wrow0[k];
    bf16x8 b1 = *(const bf16x8*)&Wrow1[k];
    acc0 = __builtin_amdgcn_mfma_f32_16x16x32_bf16(a, b0, acc0, 0, 0, 0);
    acc1 = __builtin_amdgcn_mfma_f32_16x16x32_bf16(a, b1, acc1, 0, 0, 0);
  }
  // C/D layout: col = lane&15, row = quad*4 + reg
  #pragma unroll
  for (int r = 0; r < 4; ++r) {
    int row = mt * 16 + (quad << 2) + r;
    int g = base + row;
    if (g < n) {
      float s = dinv[g];
      H2[(size_t)g * D + nt0 * 16 + m]       = f2bf(s * acc0[r]);
      H2[(size_t)g * D + (nt0 + 4) * 16 + m] = f2bf(s * acc1[r]);
    }
  }
}

// ---------------- launch ----------------

extern "C" void kernel_launch(void* const* d_in, const int* in_sizes, int n_in,
                              void* d_out, int out_size, void* d_ws, size_t ws_size,
                              hipStream_t stream) {
  const float* x  = (const float*)d_in[0];
  const int*   ei = (const int*)d_in[1];
  const float* pf = (const float*)d_in[2];
  const float* pl = (const float*)d_in[3];
  const float* W1 = (const float*)d_in[4];
  const float* b1 = (const float*)d_in[5];
  const float* W2 = (const float*)d_in[6];
  const float* b2 = (const float*)d_in[7];
  float* out = (float*)d_out;

  const int n = in_sizes[0] / D;
  const int E = in_sizes[1] / 2;
  const int* src = ei;      // edge_index[0]
  const int* dst = ei + E;  // edge_index[1]

  // workspace layout
  int*   deg       = (int*)d_ws;                 // [n]
  float* dinv      = (float*)d_ws + n;           // [n]
  int*   ptr       = (int*)d_ws + 2 * n;         // [n] (becomes row_end after fill)
  int*   blockSums = (int*)d_ws + 3 * n;         // [<=512]
  int*   csr       = (int*)d_ws + 3 * n + 512;   // [E]
  size_t a1_off = ((size_t)(3 * n + 512 + E) * 4 + 255) & ~(size_t)255;
  unsigned short* A1 = (unsigned short*)((char*)d_ws + a1_off);
  unsigned short* A2 = A1 + (size_t)n * D;
  unsigned short* W2bf = A2 + (size_t)n * D;     // [128*128] bf16, 32 KB
  size_t needed = a1_off + (2 * (size_t)n * D + 128 * 128) * sizeof(unsigned short);
  const bool fused_l2 = (ws_size >= needed);  // constant across calls -> capture-safe

  const int nb_n = (n + 255) / 256;
  const int nb_e = (E + 255) / 256;
  const int nb_g = (n + 3) / 4;

  hipMemsetAsync(deg, 0, (size_t)n * sizeof(int), stream);
  count_deg_kernel<<<nb_e + 8, 256, 0, stream>>>(dst, E, deg, W2,
                                                 fused_l2 ? W2bf : (unsigned short*)nullptr);
  scan_blocksum_kernel<<<nb_n, 256, 0, stream>>>(deg, n, blockSums);
  scan_top_kernel<<<1, 512, 0, stream>>>(blockSums, nb_n);
  scan_write_kernel<<<nb_n, 256, 0, stream>>>(deg, n, blockSums, ptr, dinv);

  // layer 1: CSR fill || Hs1 = dinv*(x@W1^T) -> A1
  fused_fill_gemm_kernel<<<FUSED_GRID, 256, 0, stream>>>(src, dst, ptr, csr, E, x, W1, dinv, A1, n);

  if (fused_l2) {
    // gather1 + GEMM2 fused -> A2 ; gather2 -> out
    gather_gemm_kernel<<<(n + 31) / 32, 512, 0, stream>>>(csr, ptr, dinv, (const unsigned*)A1,
                                                          b1, pf, W2bf, A2, n);
    gather_kernel<<<nb_g, 256, 0, stream>>>(csr, ptr, dinv, (const unsigned*)A2, b2, pl, out, n);
  } else {
    // fallback (round-3 path): gather1 -> out ; gemm2 -> A1 ; gather2 -> out
    gather_kernel<<<nb_g, 256, 0, stream>>>(csr, ptr, dinv, (const unsigned*)A1, b1, pf, out, n);
    gemm128_kernel<<<1024, 256, 0, stream>>>(out, W2, dinv, A1, n);
    gather_kernel<<<nb_g, 256, 0, stream>>>(csr, ptr, dinv, (const unsigned*)A1, b2, pl, out, n);
  }
}

// Round 2
// 564.651 us; speedup vs baseline: 1.0338x; 1.0079x over previous
//
#include <hip/hip_runtime.h>
#include <math.h>

#define D 128
#define WS_PAD 132  // 128+4: breaks stride-128 bank pattern, keeps 16B align

typedef short bf16x8 __attribute__((ext_vector_type(8)));  // 8 bf16 in 4 VGPRs
typedef float f32x4 __attribute__((ext_vector_type(4)));

__device__ __forceinline__ unsigned short f2bf(float f) {
  unsigned u = __float_as_uint(f);
  u += 0x7FFFu + ((u >> 16) & 1u);  // round-to-nearest-even
  return (unsigned short)(u >> 16);
}

__device__ __forceinline__ float bf2f(unsigned short h) {
  return __uint_as_float(((unsigned)h) << 16);
}

// ---------------- degree count (+ fused weight-table prep in extra blocks) ----------------
// extra blocks: 8 for W2->bf16, 8 for W1->(hi,lo) bf16 split (for MFMA bf16x3 GEMM1)

__global__ __launch_bounds__(256) void count_deg_kernel(const int* __restrict__ dst, int E,
                                                        int* __restrict__ deg,
                                                        const float* __restrict__ W2,
                                                        unsigned short* __restrict__ W2bf,
                                                        const float* __restrict__ W1,
                                                        unsigned short* __restrict__ W1h,
                                                        unsigned short* __restrict__ W1l) {
  int nbe = (E + 255) >> 8;
  int b = blockIdx.x;
  if (b >= nbe) {
    if (W2bf == nullptr) return;
    int which = b - nbe;  // 0..15
    if (which < 8) {
      // convert W2 (128x128 fp32) -> bf16 once
      int t = which * 256 + threadIdx.x;  // 0..2047
      #pragma unroll
      for (int q = 0; q < 2; ++q) {
        int idx = t + q * 2048;  // float4 index, 0..4095
        float4 w = ((const float4*)W2)[idx];
        ushort4 o;
        o.x = f2bf(w.x); o.y = f2bf(w.y); o.z = f2bf(w.z); o.w = f2bf(w.w);
        ((ushort4*)W2bf)[idx] = o;
      }
    } else {
      // split W1 -> bf16 hi + lo (residual) for bf16x3 fp32-accurate MFMA
      int t = (which - 8) * 256 + threadIdx.x;  // 0..2047
      #pragma unroll
      for (int q = 0; q < 2; ++q) {
        int idx = t + q * 2048;
        float4 w = ((const float4*)W1)[idx];
        ushort4 hi, lo;
        hi.x = f2bf(w.x); lo.x = f2bf(w.x - bf2f(hi.x));
        hi.y = f2bf(w.y); lo.y = f2bf(w.y - bf2f(hi.y));
        hi.z = f2bf(w.z); lo.z = f2bf(w.z - bf2f(hi.z));
        hi.w = f2bf(w.w); lo.w = f2bf(w.w - bf2f(hi.w));
        ((ushort4*)W1h)[idx] = hi;
        ((ushort4*)W1l)[idx] = lo;
      }
    }
    return;
  }
  int e = b * 256 + threadIdx.x;
  if (e < E) atomicAdd(&deg[dst[e]], 1);
}

// ---------------- exclusive prefix scan of deg -> ptr ----------------

__global__ __launch_bounds__(256) void scan_blocksum_kernel(const int* __restrict__ deg, int n,
                                                            int* __restrict__ blockSums) {
  __shared__ int sm[256];
  int t = threadIdx.x;
  int i = blockIdx.x * 256 + t;
  sm[t] = (i < n) ? deg[i] : 0;
  __syncthreads();
  for (int off = 128; off > 0; off >>= 1) {
    if (t < off) sm[t] += sm[t + off];
    __syncthreads();
  }
  if (t == 0) blockSums[blockIdx.x] = sm[0];
}

// single block, 512 threads; nb <= 512
__global__ __launch_bounds__(512) void scan_top_kernel(int* __restrict__ blockSums, int nb) {
  __shared__ int sm[512];
  int t = threadIdx.x;
  int v = (t < nb) ? blockSums[t] : 0;
  sm[t] = v;
  __syncthreads();
  for (int off = 1; off < 512; off <<= 1) {
    int x = (t >= off) ? sm[t - off] : 0;
    __syncthreads();
    sm[t] += x;
    __syncthreads();
  }
  if (t < nb) blockSums[t] = sm[t] - v;  // exclusive
}

// also computes dinv (fused to save a launch)
__global__ __launch_bounds__(256) void scan_write_kernel(const int* __restrict__ deg, int n,
                                                         const int* __restrict__ blockSums,
                                                         int* __restrict__ ptr,
                                                         float* __restrict__ dinv) {
  __shared__ int sm[256];
  int t = threadIdx.x;
  int i = blockIdx.x * 256 + t;
  int v = (i < n) ? deg[i] : 0;
  sm[t] = v;
  __syncthreads();
  for (int off = 1; off < 256; off <<= 1) {
    int x = (t >= off) ? sm[t - off] : 0;
    __syncthreads();
    sm[t] += x;
    __syncthreads();
  }
  if (i < n) {
    ptr[i] = blockSums[blockIdx.x] + sm[t] - v;  // exclusive prefix
    dinv[i] = 1.0f / sqrtf((float)(v + 1));      // +1: self-loop
  }
}

// ---------------- legacy fp32 VALU GEMM body (fallback path only) ----------------

__device__ __forceinline__ void gemm_body(const float* __restrict__ X,
                                          const float* __restrict__ W,
                                          const float* __restrict__ dinv,
                                          unsigned short* __restrict__ H, int n,
                                          int bid, int nblocks,
                                          float* __restrict__ Ws, float* __restrict__ Xs) {
  const int tid = threadIdx.x;
  const int tx = tid & 31;
  const int ty = tid >> 5;
  const int ntiles = (n + 31) >> 5;

  for (int tile = bid; tile < ntiles; tile += nblocks) {
    const int row0 = tile << 5;
    const int rows_here = min(32, n - row0);
    __syncthreads();
    {
      const float4* Xg = (const float4*)(X + (size_t)row0 * D);
      int tmax = rows_here * 32;
      for (int t = tid; t < tmax; t += 256) ((float4*)Xs)[t] = Xg[t];
    }
    float acc[4][4] = {{0.f}};
    #pragma unroll
    for (int kt = 0; kt < 128; kt += 64) {
      __syncthreads();
      for (int t = tid; t < 2048; t += 256) {
        int j  = t >> 4;
        int k4 = (t & 15) << 2;
        float4 w = ((const float4*)W)[j * 32 + (kt >> 2) + (t & 15)];
        Ws[(k4 + 0) * WS_PAD + j] = w.x;
        Ws[(k4 + 1) * WS_PAD + j] = w.y;
        Ws[(k4 + 2) * WS_PAD + j] = w.z;
        Ws[(k4 + 3) * WS_PAD + j] = w.w;
      }
      __syncthreads();
      #pragma unroll 4
      for (int k = 0; k < 64; ++k) {
        float4 w = *(const float4*)&Ws[k * WS_PAD + (tx << 2)];
        #pragma unroll
        for (int r = 0; r < 4; ++r) {
          float xv = Xs[(ty + 8 * r) * 128 + (kt + k)];
          acc[r][0] += xv * w.x;
          acc[r][1] += xv * w.y;
          acc[r][2] += xv * w.z;
          acc[r][3] += xv * w.w;
        }
      }
    }
    #pragma unroll
    for (int r = 0; r < 4; ++r) {
      int row = row0 + ty + 8 * r;
      if (row < n) {
        float s = dinv[row];
        unsigned h0 = f2bf(s * acc[r][0]);
        unsigned h1 = f2bf(s * acc[r][1]);
        unsigned h2 = f2bf(s * acc[r][2]);
        unsigned h3 = f2bf(s * acc[r][3]);
        ((uint2*)(H + (size_t)row * D))[tx] = make_uint2(h0 | (h1 << 16), h2 | (h3 << 16));
      }
    }
  }
}

// ---------------- legacy fused fill+GEMM (fallback path only) ----------------

__global__ __launch_bounds__(256) void fused_fill_gemm_kernel(
    const int* __restrict__ src, const int* __restrict__ dst,
    int* __restrict__ ptr, int* __restrict__ csr, int E,
    const float* __restrict__ X, const float* __restrict__ W,
    const float* __restrict__ dinv, unsigned short* __restrict__ H, int n) {
  __shared__ float Ws[64 * WS_PAD];
  __shared__ float Xs[32 * 128];
  int sub = blockIdx.x & 7;
  if (sub < 2) {
    int fb = (blockIdx.x >> 3) * 2 + sub;
    int stride = 512 * 256;
    for (int e = fb * 256 + threadIdx.x; e < E; e += stride) {
      int d = dst[e];
      int pos = atomicAdd(&ptr[d], 1);
      csr[pos] = src[e];
    }
  } else {
    int gb = (blockIdx.x >> 3) * 6 + (sub - 2);
    gemm_body(X, W, dinv, H, n, gb, 1536, Ws, Xs);
  }
}

__global__ __launch_bounds__(256) void gemm128_kernel(const float* __restrict__ X,
                                                      const float* __restrict__ W,
                                                      const float* __restrict__ dinv,
                                                      unsigned short* __restrict__ H, int n) {
  __shared__ float Ws[64 * WS_PAD];
  __shared__ float Xs[32 * 128];
  gemm_body(X, W, dinv, H, n, blockIdx.x, gridDim.x, Ws, Xs);
}

// ---------------- fused: CSR fill || GEMM1 via MFMA bf16x3 ----------------
// GEMM1: H[n,128](bf16) = dinv[i] * (X @ W1^T), fp32-accurate via split:
//   X = Xh + Xl (bf16 hi + residual), W1 = Wh + Wl (pre-split tables in global)
//   C = Xh@Wh + Xl@Wh + Xh@Wl   (Xl@Wl term ~2^-18 rel, dropped)
// LDS: only the X tile (hi+lo, 32 x pitch136 bf16 = 17.4 KB). W1h/W1l come from
// global (64 KB total, L1/L2-resident, shared by all blocks). This lifts
// occupancy from 3 blocks/CU (50 KB LDS) to the 8-block/2048-thread cap and
// kills the Ws-staging bank conflicts (was 11.2M/dispatch).

#define FUSED_GRID 2048
#define G1_PITCH 136

__global__ __launch_bounds__(256) void fused_fill_mfma_kernel(
    const int* __restrict__ src, const int* __restrict__ dst,
    int* __restrict__ ptr, int* __restrict__ csr, int E,
    const float* __restrict__ X,
    const unsigned short* __restrict__ W1h, const unsigned short* __restrict__ W1l,
    const float* __restrict__ dinv, unsigned short* __restrict__ H, int n) {
  __shared__ unsigned short Ths[32 * G1_PITCH];  // 8.7 KB
  __shared__ unsigned short Tls[32 * G1_PITCH];  // 8.7 KB
  int sub = blockIdx.x & 7;
  if (sub < 4) {
    // CSR fill: 1024 blocks (atomic+scatter bound; needs parallelism, not ALU)
    int fb = (blockIdx.x >> 3) * 4 + sub;
    int stride = 1024 * 256;
    for (int e = fb * 256 + threadIdx.x; e < E; e += stride) {
      int d = dst[e];
      int pos = atomicAdd(&ptr[d], 1);
      csr[pos] = src[e];
    }
  } else {
    // GEMM1: 1024 blocks, 32 rows per tile, grid-strided
    int gb = (blockIdx.x >> 3) * 4 + (sub - 4);
    const int tid = threadIdx.x;
    const int wv = tid >> 6;       // 0..3
    const int lane = tid & 63;
    const int m = lane & 15;
    const int quad = lane >> 4;    // 0..3
    const int mt = wv >> 1;        // 0..1  (16-row m-tile)
    const int ntb = (wv & 1) * 4;  // n-tile base: 4 consecutive 16-col tiles
    const int ntiles = (n + 31) >> 5;

    for (int tile = gb; tile < ntiles; tile += 1024) {
      const int row0 = tile << 5;
      const int rows_here = min(32, n - row0);
      __syncthreads();  // protect LDS from previous iteration's readers
      {
        const float4* Xg = (const float4*)(X + (size_t)row0 * D);
        int tmax = rows_here * 32;
        for (int t = tid; t < tmax; t += 256) {
          float4 xv = Xg[t];
          int r = t >> 5, c4 = (t & 31) << 2;
          ushort4 hi, lo;
          hi.x = f2bf(xv.x); lo.x = f2bf(xv.x - bf2f(hi.x));
          hi.y = f2bf(xv.y); lo.y = f2bf(xv.y - bf2f(hi.y));
          hi.z = f2bf(xv.z); lo.z = f2bf(xv.z - bf2f(hi.z));
          hi.w = f2bf(xv.w); lo.w = f2bf(xv.w - bf2f(hi.w));
          *(ushort4*)&Ths[r * G1_PITCH + c4] = hi;
          *(ushort4*)&Tls[r * G1_PITCH + c4] = lo;
        }
      }
      __syncthreads();

      f32x4 acc0 = {0.f, 0.f, 0.f, 0.f};
      f32x4 acc1 = {0.f, 0.f, 0.f, 0.f};
      f32x4 acc2 = {0.f, 0.f, 0.f, 0.f};
      f32x4 acc3 = {0.f, 0.f, 0.f, 0.f};
      #pragma unroll
      for (int s = 0; s < 4; ++s) {
        int k = (s << 5) + (quad << 3);
        bf16x8 ah = *(const bf16x8*)&Ths[(mt * 16 + m) * G1_PITCH + k];
        bf16x8 al = *(const bf16x8*)&Tls[(mt * 16 + m) * G1_PITCH + k];
        bf16x8 bh0 = *(const bf16x8*)&W1h[(size_t)((ntb + 0) * 16 + m) * 128 + k];
        bf16x8 bl0 = *(const bf16x8*)&W1l[(size_t)((ntb + 0) * 16 + m) * 128 + k];
        acc0 = __builtin_amdgcn_mfma_f32_16x16x32_bf16(ah, bh0, acc0, 0, 0, 0);
        acc0 = __builtin_amdgcn_mfma_f32_16x16x32_bf16(al, bh0, acc0, 0, 0, 0);
        acc0 = __builtin_amdgcn_mfma_f32_16x16x32_bf16(ah, bl0, acc0, 0, 0, 0);
        bf16x8 bh1 = *(const bf16x8*)&W1h[(size_t)((ntb + 1) * 16 + m) * 128 + k];
        bf16x8 bl1 = *(const bf16x8*)&W1l[(size_t)((ntb + 1) * 16 + m) * 128 + k];
        acc1 = __builtin_amdgcn_mfma_f32_16x16x32_bf16(ah, bh1, acc1, 0, 0, 0);
        acc1 = __builtin_amdgcn_mfma_f32_16x16x32_bf16(al, bh1, acc1, 0, 0, 0);
        acc1 = __builtin_amdgcn_mfma_f32_16x16x32_bf16(ah, bl1, acc1, 0, 0, 0);
        bf16x8 bh2 = *(const bf16x8*)&W1h[(size_t)((ntb + 2) * 16 + m) * 128 + k];
        bf16x8 bl2 = *(const bf16x8*)&W1l[(size_t)((ntb + 2) * 16 + m) * 128 + k];
        acc2 = __builtin_amdgcn_mfma_f32_16x16x32_bf16(ah, bh2, acc2, 0, 0, 0);
        acc2 = __builtin_amdgcn_mfma_f32_16x16x32_bf16(al, bh2, acc2, 0, 0, 0);
        acc2 = __builtin_amdgcn_mfma_f32_16x16x32_bf16(ah, bl2, acc2, 0, 0, 0);
        bf16x8 bh3 = *(const bf16x8*)&W1h[(size_t)((ntb + 3) * 16 + m) * 128 + k];
        bf16x8 bl3 = *(const bf16x8*)&W1l[(size_t)((ntb + 3) * 16 + m) * 128 + k];
        acc3 = __builtin_amdgcn_mfma_f32_16x16x32_bf16(ah, bh3, acc3, 0, 0, 0);
        acc3 = __builtin_amdgcn_mfma_f32_16x16x32_bf16(al, bh3, acc3, 0, 0, 0);
        acc3 = __builtin_amdgcn_mfma_f32_16x16x32_bf16(ah, bl3, acc3, 0, 0, 0);
      }
      // C/D layout: col = lane&15 (m), row = quad*4 + r
      #pragma unroll
      for (int r = 0; r < 4; ++r) {
        int row = mt * 16 + (quad << 2) + r;
        int g = row0 + row;
        if (g < n) {
          float sc = dinv[g];
          H[(size_t)g * D + (ntb + 0) * 16 + m] = f2bf(sc * acc0[r]);
          H[(size_t)g * D + (ntb + 1) * 16 + m] = f2bf(sc * acc1[r]);
          H[(size_t)g * D + (ntb + 2) * 16 + m] = f2bf(sc * acc2[r]);
          H[(size_t)g * D + (ntb + 3) * 16 + m] = f2bf(sc * acc3[r]);
        }
      }
    }
  }
}

// ---------------- gather helper: accumulate row i of Hs (bf16) ----------------

__device__ __forceinline__ void gather_row(const int* __restrict__ csr,
                                           const int* __restrict__ rend,
                                           const unsigned* __restrict__ Hu,
                                           int i, int lane, float& ax, float& ay) {
  int start = (i == 0) ? 0 : rend[i - 1];
  int end = rend[i];
  unsigned v = Hu[(size_t)i * 64 + lane];  // self-loop term
  ax = __uint_as_float(v << 16);
  ay = __uint_as_float(v & 0xFFFF0000u);
  int e = start;
  for (; e + 8 <= end; e += 8) {
    unsigned w0 = Hu[(size_t)csr[e + 0] * 64 + lane];
    unsigned w1 = Hu[(size_t)csr[e + 1] * 64 + lane];
    unsigned w2 = Hu[(size_t)csr[e + 2] * 64 + lane];
    unsigned w3 = Hu[(size_t)csr[e + 3] * 64 + lane];
    unsigned w4 = Hu[(size_t)csr[e + 4] * 64 + lane];
    unsigned w5 = Hu[(size_t)csr[e + 5] * 64 + lane];
    unsigned w6 = Hu[(size_t)csr[e + 6] * 64 + lane];
    unsigned w7 = Hu[(size_t)csr[e + 7] * 64 + lane];
    ax += __uint_as_float(w0 << 16) + __uint_as_float(w1 << 16) +
          __uint_as_float(w2 << 16) + __uint_as_float(w3 << 16) +
          __uint_as_float(w4 << 16) + __uint_as_float(w5 << 16) +
          __uint_as_float(w6 << 16) + __uint_as_float(w7 << 16);
    ay += __uint_as_float(w0 & 0xFFFF0000u) + __uint_as_float(w1 & 0xFFFF0000u) +
          __uint_as_float(w2 & 0xFFFF0000u) + __uint_as_float(w3 & 0xFFFF0000u) +
          __uint_as_float(w4 & 0xFFFF0000u) + __uint_as_float(w5 & 0xFFFF0000u) +
          __uint_as_float(w6 & 0xFFFF0000u) + __uint_as_float(w7 & 0xFFFF0000u);
  }
  for (; e < end; ++e) {
    unsigned w = Hu[(size_t)csr[e] * 64 + lane];
    ax += __uint_as_float(w << 16);
    ay += __uint_as_float(w & 0xFFFF0000u);
  }
}

// ---------------- standalone gather (final layer / fallback) ----------------

__global__ __launch_bounds__(256, 8) void gather_kernel(const int* __restrict__ csr,
                                                        const int* __restrict__ rend,
                                                        const float* __restrict__ dinv,
                                                        const unsigned* __restrict__ Hu,
                                                        const float* __restrict__ bias,
                                                        const float* __restrict__ perturb,
                                                        float* __restrict__ out, int n) {
  int i = (blockIdx.x << 2) + (threadIdx.x >> 6);
  if (i >= n) return;
  int lane = threadIdx.x & 63;
  float ax, ay;
  gather_row(csr, rend, Hu, i, lane, ax, ay);
  float di = dinv[i];
  float2 p = ((const float2*)(perturb + (size_t)i * D))[lane];
  float2 o;
  o.x = bias[2 * lane + 0] + p.x + di * ax;
  o.y = bias[2 * lane + 1] + p.y + di * ay;
  ((float2*)(out + (size_t)i * D))[lane] = o;
}

// ---------------- fused gather1 + GEMM2 (MFMA bf16) ----------------

#define GG_PITCH 136

__global__ __launch_bounds__(512, 8) void gather_gemm_kernel(
    const int* __restrict__ csr, const int* __restrict__ rend,
    const float* __restrict__ dinv, const unsigned* __restrict__ Hu,
    const float* __restrict__ bias, const float* __restrict__ perturb,
    const unsigned short* __restrict__ W2bf, unsigned short* __restrict__ H2, int n) {
  __shared__ unsigned short Ts[32 * GG_PITCH];  // 8.5 KB
  const int tid = threadIdx.x;
  const int wv = tid >> 6;
  const int lane = tid & 63;
  const int base = blockIdx.x << 5;  // 32 nodes per block

  // phase 1: gather 4 nodes per wave -> Ts
  #pragma unroll
  for (int j = 0; j < 4; ++j) {
    int row = (wv << 2) + j;
    int i = base + row;
    if (i < n) {
      float ax, ay;
      gather_row(csr, rend, Hu, i, lane, ax, ay);
      float di = dinv[i];
      float2 p = ((const float2*)(perturb + (size_t)i * D))[lane];
      float ox = bias[2 * lane + 0] + p.x + di * ax;
      float oy = bias[2 * lane + 1] + p.y + di * ay;
      unsigned pack = (unsigned)f2bf(ox) | ((unsigned)f2bf(oy) << 16);
      *(unsigned*)&Ts[row * GG_PITCH + (lane << 1)] = pack;
    }
  }
  __syncthreads();

  // phase 2: R[32][128] = Ts @ W2bf^T ; wave wv: m-tile = wv>>2, n-tiles {wv&3, (wv&3)+4}
  const int mt = wv >> 2;
  const int nt0 = wv & 3;
  const int m = lane & 15;
  const int quad = lane >> 4;  // 0..3
  const unsigned short* Wrow0 = W2bf + (size_t)(nt0 * 16 + m) * 128;
  const unsigned short* Wrow1 = W2bf + (size_t)((nt0 + 4) * 16 + m) * 128;
  f32x4 acc0 = {0.f, 0.f, 0.f, 0.f};
  f32x4 acc1 = {0.f, 0.f, 0.f, 0.f};
  #pragma unroll
  for (int s = 0; s < 4; ++s) {
    int k = (s << 5) + (quad << 3);
    bf16x8 a  = *(const bf16x8*)&Ts[(mt * 16 + m) * GG_PITCH + k];
    bf16x8 b0 = *(const bf16x8*)&Wrow0[k];
    bf16x8 b1 = *(const bf16x8*)&Wrow1[k];
    acc0 = __builtin_amdgcn_mfma_f32_16x16x32_bf16(a, b0, acc0, 0, 0, 0);
    acc1 = __builtin_amdgcn_mfma_f32_16x16x32_bf16(a, b1, acc1, 0, 0, 0);
  }
  // C/D layout: col = lane&15, row = quad*4 + reg
  #pragma unroll
  for (int r = 0; r < 4; ++r) {
    int row = mt * 16 + (quad << 2) + r;
    int g = base + row;
    if (g < n) {
      float s = dinv[g];
      H2[(size_t)g * D + nt0 * 16 + m]       = f2bf(s * acc0[r]);
      H2[(size_t)g * D + (nt0 + 4) * 16 + m] = f2bf(s * acc1[r]);
    }
  }
}

// ---------------- launch ----------------

extern "C" void kernel_launch(void* const* d_in, const int* in_sizes, int n_in,
                              void* d_out, int out_size, void* d_ws, size_t ws_size,
                              hipStream_t stream) {
  const float* x  = (const float*)d_in[0];
  const int*   ei = (const int*)d_in[1];
  const float* pf = (const float*)d_in[2];
  const float* pl = (const float*)d_in[3];
  const float* W1 = (const float*)d_in[4];
  const float* b1 = (const float*)d_in[5];
  const float* W2 = (const float*)d_in[6];
  const float* b2 = (const float*)d_in[7];
  float* out = (float*)d_out;

  const int n = in_sizes[0] / D;
  const int E = in_sizes[1] / 2;
  const int* src = ei;      // edge_index[0]
  const int* dst = ei + E;  // edge_index[1]

  // workspace layout
  int*   deg       = (int*)d_ws;                 // [n]
  float* dinv      = (float*)d_ws + n;           // [n]
  int*   ptr       = (int*)d_ws + 2 * n;         // [n] (becomes row_end after fill)
  int*   blockSums = (int*)d_ws + 3 * n;         // [<=512]
  int*   csr       = (int*)d_ws + 3 * n + 512;   // [E]
  size_t a1_off = ((size_t)(3 * n + 512 + E) * 4 + 255) & ~(size_t)255;
  unsigned short* A1 = (unsigned short*)((char*)d_ws + a1_off);
  unsigned short* A2 = A1 + (size_t)n * D;
  unsigned short* W2bf = A2 + (size_t)n * D;     // [128*128] bf16, 32 KB
  unsigned short* W1h  = W2bf + 128 * 128;       // [128*128] bf16, 32 KB
  unsigned short* W1l  = W1h + 128 * 128;        // [128*128] bf16, 32 KB
  size_t needed = a1_off + (2 * (size_t)n * D + 3 * 128 * 128) * sizeof(unsigned short);
  const bool fused_l2 = (ws_size >= needed);  // constant across calls -> capture-safe

  const int nb_n = (n + 255) / 256;
  const int nb_e = (E + 255) / 256;
  const int nb_g = (n + 3) / 4;

  hipMemsetAsync(deg, 0, (size_t)n * sizeof(int), stream);
  count_deg_kernel<<<nb_e + 16, 256, 0, stream>>>(
      dst, E, deg, W2, fused_l2 ? W2bf : (unsigned short*)nullptr, W1, W1h, W1l);
  scan_blocksum_kernel<<<nb_n, 256, 0, stream>>>(deg, n, blockSums);
  scan_top_kernel<<<1, 512, 0, stream>>>(blockSums, nb_n);
  scan_write_kernel<<<nb_n, 256, 0, stream>>>(deg, n, blockSums, ptr, dinv);

  if (fused_l2) {
    // layer 1: CSR fill || Hs1 = dinv*(x@W1^T) via MFMA bf16x3 -> A1
    fused_fill_mfma_kernel<<<FUSED_GRID, 256, 0, stream>>>(src, dst, ptr, csr, E, x, W1h, W1l,
                                                           dinv, A1, n);
    // gather1 + GEMM2 fused -> A2 ; gather2 -> out
    gather_gemm_kernel<<<(n + 31) / 32, 512, 0, stream>>>(csr, ptr, dinv, (const unsigned*)A1,
                                                          b1, pf, W2bf, A2, n);
    gather_kernel<<<nb_g, 256, 0, stream>>>(csr, ptr, dinv, (const unsigned*)A2, b2, pl, out, n);
  } else {
    // fallback (round-3 path): fp32 VALU gemm, unfused layers
    fused_fill_gemm_kernel<<<FUSED_GRID, 256, 0, stream>>>(src, dst, ptr, csr, E, x, W1, dinv, A1, n);
    gather_kernel<<<nb_g, 256, 0, stream>>>(csr, ptr, dinv, (const unsigned*)A1, b1, pf, out, n);
    gemm128_kernel<<<1024, 256, 0, stream>>>(out, W2, dinv, A1, n);
    gather_kernel<<<nb_g, 256, 0, stream>>>(csr, ptr, dinv, (const unsigned*)A1, b2, pl, out, n);
  }
}

// Round 3
// 559.665 us; speedup vs baseline: 1.0430x; 1.0089x over previous
//
#include <hip/hip_runtime.h>
#include <math.h>

#define D 128
#define WS_PAD 132  // 128+4: breaks stride-128 bank pattern, keeps 16B align

typedef short bf16x8 __attribute__((ext_vector_type(8)));  // 8 bf16 in 4 VGPRs
typedef float f32x4 __attribute__((ext_vector_type(4)));

__device__ __forceinline__ unsigned short f2bf(float f) {
  unsigned u = __float_as_uint(f);
  u += 0x7FFFu + ((u >> 16) & 1u);  // round-to-nearest-even
  return (unsigned short)(u >> 16);
}

__device__ __forceinline__ float bf2f(unsigned short h) {
  return __uint_as_float(((unsigned)h) << 16);
}

// ---------------- degree count (+ fused weight-table prep in extra blocks) ----------------
// extra blocks: 8 for W2->bf16, 8 for W1->(hi,lo) bf16 split (for MFMA bf16x3 GEMM1)

__global__ __launch_bounds__(256) void count_deg_kernel(const int* __restrict__ dst, int E,
                                                        int* __restrict__ deg,
                                                        const float* __restrict__ W2,
                                                        unsigned short* __restrict__ W2bf,
                                                        const float* __restrict__ W1,
                                                        unsigned short* __restrict__ W1h,
                                                        unsigned short* __restrict__ W1l) {
  int nbe = (E + 255) >> 8;
  int b = blockIdx.x;
  if (b >= nbe) {
    if (W2bf == nullptr) return;
    int which = b - nbe;  // 0..15
    if (which < 8) {
      // convert W2 (128x128 fp32) -> bf16 once
      int t = which * 256 + threadIdx.x;  // 0..2047
      #pragma unroll
      for (int q = 0; q < 2; ++q) {
        int idx = t + q * 2048;  // float4 index, 0..4095
        float4 w = ((const float4*)W2)[idx];
        ushort4 o;
        o.x = f2bf(w.x); o.y = f2bf(w.y); o.z = f2bf(w.z); o.w = f2bf(w.w);
        ((ushort4*)W2bf)[idx] = o;
      }
    } else {
      // split W1 -> bf16 hi + lo (residual) for bf16x3 fp32-accurate MFMA
      int t = (which - 8) * 256 + threadIdx.x;  // 0..2047
      #pragma unroll
      for (int q = 0; q < 2; ++q) {
        int idx = t + q * 2048;
        float4 w = ((const float4*)W1)[idx];
        ushort4 hi, lo;
        hi.x = f2bf(w.x); lo.x = f2bf(w.x - bf2f(hi.x));
        hi.y = f2bf(w.y); lo.y = f2bf(w.y - bf2f(hi.y));
        hi.z = f2bf(w.z); lo.z = f2bf(w.z - bf2f(hi.z));
        hi.w = f2bf(w.w); lo.w = f2bf(w.w - bf2f(hi.w));
        ((ushort4*)W1h)[idx] = hi;
        ((ushort4*)W1l)[idx] = lo;
      }
    }
    return;
  }
  int e = b * 256 + threadIdx.x;
  if (e < E) atomicAdd(&deg[dst[e]], 1);
}

// ---------------- exclusive prefix scan of deg -> ptr ----------------

__global__ __launch_bounds__(256) void scan_blocksum_kernel(const int* __restrict__ deg, int n,
                                                            int* __restrict__ blockSums) {
  __shared__ int sm[256];
  int t = threadIdx.x;
  int i = blockIdx.x * 256 + t;
  sm[t] = (i < n) ? deg[i] : 0;
  __syncthreads();
  for (int off = 128; off > 0; off >>= 1) {
    if (t < off) sm[t] += sm[t + off];
    __syncthreads();
  }
  if (t == 0) blockSums[blockIdx.x] = sm[0];
}

// single block, 512 threads; nb <= 512
__global__ __launch_bounds__(512) void scan_top_kernel(int* __restrict__ blockSums, int nb) {
  __shared__ int sm[512];
  int t = threadIdx.x;
  int v = (t < nb) ? blockSums[t] : 0;
  sm[t] = v;
  __syncthreads();
  for (int off = 1; off < 512; off <<= 1) {
    int x = (t >= off) ? sm[t - off] : 0;
    __syncthreads();
    sm[t] += x;
    __syncthreads();
  }
  if (t < nb) blockSums[t] = sm[t] - v;  // exclusive
}

// also computes dinv (fused to save a launch)
__global__ __launch_bounds__(256) void scan_write_kernel(const int* __restrict__ deg, int n,
                                                         const int* __restrict__ blockSums,
                                                         int* __restrict__ ptr,
                                                         float* __restrict__ dinv) {
  __shared__ int sm[256];
  int t = threadIdx.x;
  int i = blockIdx.x * 256 + t;
  int v = (i < n) ? deg[i] : 0;
  sm[t] = v;
  __syncthreads();
  for (int off = 1; off < 256; off <<= 1) {
    int x = (t >= off) ? sm[t - off] : 0;
    __syncthreads();
    sm[t] += x;
    __syncthreads();
  }
  if (i < n) {
    ptr[i] = blockSums[blockIdx.x] + sm[t] - v;  // exclusive prefix
    dinv[i] = 1.0f / sqrtf((float)(v + 1));      // +1: self-loop
  }
}

// ---------------- legacy fp32 VALU GEMM body (fallback path only) ----------------

__device__ __forceinline__ void gemm_body(const float* __restrict__ X,
                                          const float* __restrict__ W,
                                          const float* __restrict__ dinv,
                                          unsigned short* __restrict__ H, int n,
                                          int bid, int nblocks,
                                          float* __restrict__ Ws, float* __restrict__ Xs) {
  const int tid = threadIdx.x;
  const int tx = tid & 31;
  const int ty = tid >> 5;
  const int ntiles = (n + 31) >> 5;

  for (int tile = bid; tile < ntiles; tile += nblocks) {
    const int row0 = tile << 5;
    const int rows_here = min(32, n - row0);
    __syncthreads();
    {
      const float4* Xg = (const float4*)(X + (size_t)row0 * D);
      int tmax = rows_here * 32;
      for (int t = tid; t < tmax; t += 256) ((float4*)Xs)[t] = Xg[t];
    }
    float acc[4][4] = {{0.f}};
    #pragma unroll
    for (int kt = 0; kt < 128; kt += 64) {
      __syncthreads();
      for (int t = tid; t < 2048; t += 256) {
        int j  = t >> 4;
        int k4 = (t & 15) << 2;
        float4 w = ((const float4*)W)[j * 32 + (kt >> 2) + (t & 15)];
        Ws[(k4 + 0) * WS_PAD + j] = w.x;
        Ws[(k4 + 1) * WS_PAD + j] = w.y;
        Ws[(k4 + 2) * WS_PAD + j] = w.z;
        Ws[(k4 + 3) * WS_PAD + j] = w.w;
      }
      __syncthreads();
      #pragma unroll 4
      for (int k = 0; k < 64; ++k) {
        float4 w = *(const float4*)&Ws[k * WS_PAD + (tx << 2)];
        #pragma unroll
        for (int r = 0; r < 4; ++r) {
          float xv = Xs[(ty + 8 * r) * 128 + (kt + k)];
          acc[r][0] += xv * w.x;
          acc[r][1] += xv * w.y;
          acc[r][2] += xv * w.z;
          acc[r][3] += xv * w.w;
        }
      }
    }
    #pragma unroll
    for (int r = 0; r < 4; ++r) {
      int row = row0 + ty + 8 * r;
      if (row < n) {
        float s = dinv[row];
        unsigned h0 = f2bf(s * acc[r][0]);
        unsigned h1 = f2bf(s * acc[r][1]);
        unsigned h2 = f2bf(s * acc[r][2]);
        unsigned h3 = f2bf(s * acc[r][3]);
        ((uint2*)(H + (size_t)row * D))[tx] = make_uint2(h0 | (h1 << 16), h2 | (h3 << 16));
      }
    }
  }
}

// ---------------- legacy fused fill+GEMM (fallback path only) ----------------

__global__ __launch_bounds__(256) void fused_fill_gemm_kernel(
    const int* __restrict__ src, const int* __restrict__ dst,
    int* __restrict__ ptr, int* __restrict__ csr, int E,
    const float* __restrict__ X, const float* __restrict__ W,
    const float* __restrict__ dinv, unsigned short* __restrict__ H, int n) {
  __shared__ float Ws[64 * WS_PAD];
  __shared__ float Xs[32 * 128];
  int sub = blockIdx.x & 7;
  if (sub < 2) {
    int fb = (blockIdx.x >> 3) * 2 + sub;
    int stride = 512 * 256;
    for (int e = fb * 256 + threadIdx.x; e < E; e += stride) {
      int d = dst[e];
      int pos = atomicAdd(&ptr[d], 1);
      csr[pos] = src[e];
    }
  } else {
    int gb = (blockIdx.x >> 3) * 6 + (sub - 2);
    gemm_body(X, W, dinv, H, n, gb, 1536, Ws, Xs);
  }
}

__global__ __launch_bounds__(256) void gemm128_kernel(const float* __restrict__ X,
                                                      const float* __restrict__ W,
                                                      const float* __restrict__ dinv,
                                                      unsigned short* __restrict__ H, int n) {
  __shared__ float Ws[64 * WS_PAD];
  __shared__ float Xs[32 * 128];
  gemm_body(X, W, dinv, H, n, blockIdx.x, gridDim.x, Ws, Xs);
}

// ---------------- fused: CSR fill (batched atomics) || GEMM1 via MFMA bf16x3 ----------------
// Fill: the atomicAdd->store dependency forces one atomic in flight per thread if
// written naively (R1 measured: fill ~136us, insensitive to block count => latency
// chain, not throughput). Batch 8 edges/thread: 2x int4 coalesced loads, 8
// INDEPENDENT atomicAdds (one waitcnt covers all), then 8 scatter stores.
// GEMM1: H[n,128](bf16) = dinv[i]*(X@W1^T) fp32-accurate via bf16 hi/lo split.

#define FUSED_GRID 2048
#define G1_PITCH 136

__global__ __launch_bounds__(256) void fused_fill_mfma_kernel(
    const int* __restrict__ src, const int* __restrict__ dst,
    int* __restrict__ ptr, int* __restrict__ csr, int E,
    const float* __restrict__ X,
    const unsigned short* __restrict__ W1h, const unsigned short* __restrict__ W1l,
    const float* __restrict__ dinv, unsigned short* __restrict__ H, int n) {
  __shared__ unsigned short Ths[32 * G1_PITCH];  // 8.7 KB
  __shared__ unsigned short Tls[32 * G1_PITCH];  // 8.7 KB
  int sub = blockIdx.x & 7;
  if (sub < 4) {
    // CSR fill, 1024 blocks, 8 edges per thread batched for atomic MLP
    int fb = (blockIdx.x >> 3) * 4 + sub;
    const long long T = 1024 * 256;
    long long t = fb * 256 + threadIdx.x;
    const bool al16 = ((E & 3) == 0);  // int4-aligned edge halves (true for bench E)
    for (long long e0 = t * 8; e0 < E; e0 += T * 8) {
      if (e0 + 8 <= (long long)E && al16) {
        int4 d0 = ((const int4*)(dst + e0))[0];
        int4 d1 = ((const int4*)(dst + e0))[1];
        int4 s0 = ((const int4*)(src + e0))[0];
        int4 s1 = ((const int4*)(src + e0))[1];
        int p0 = atomicAdd(&ptr[d0.x], 1);
        int p1 = atomicAdd(&ptr[d0.y], 1);
        int p2 = atomicAdd(&ptr[d0.z], 1);
        int p3 = atomicAdd(&ptr[d0.w], 1);
        int p4 = atomicAdd(&ptr[d1.x], 1);
        int p5 = atomicAdd(&ptr[d1.y], 1);
        int p6 = atomicAdd(&ptr[d1.z], 1);
        int p7 = atomicAdd(&ptr[d1.w], 1);
        csr[p0] = s0.x; csr[p1] = s0.y; csr[p2] = s0.z; csr[p3] = s0.w;
        csr[p4] = s1.x; csr[p5] = s1.y; csr[p6] = s1.z; csr[p7] = s1.w;
      } else {
        for (long long e = e0; e < E && e < e0 + 8; ++e) {
          int d = dst[e];
          csr[atomicAdd(&ptr[d], 1)] = src[e];
        }
      }
    }
  } else {
    // GEMM1: 1024 blocks, 32 rows per tile, grid-strided
    int gb = (blockIdx.x >> 3) * 4 + (sub - 4);
    const int tid = threadIdx.x;
    const int wv = tid >> 6;       // 0..3
    const int lane = tid & 63;
    const int m = lane & 15;
    const int quad = lane >> 4;    // 0..3
    const int mt = wv >> 1;        // 0..1  (16-row m-tile)
    const int ntb = (wv & 1) * 4;  // n-tile base: 4 consecutive 16-col tiles
    const int ntiles = (n + 31) >> 5;

    for (int tile = gb; tile < ntiles; tile += 1024) {
      const int row0 = tile << 5;
      const int rows_here = min(32, n - row0);
      __syncthreads();  // protect LDS from previous iteration's readers
      {
        const float4* Xg = (const float4*)(X + (size_t)row0 * D);
        int tmax = rows_here * 32;
        for (int t = tid; t < tmax; t += 256) {
          float4 xv = Xg[t];
          int r = t >> 5, c4 = (t & 31) << 2;
          ushort4 hi, lo;
          hi.x = f2bf(xv.x); lo.x = f2bf(xv.x - bf2f(hi.x));
          hi.y = f2bf(xv.y); lo.y = f2bf(xv.y - bf2f(hi.y));
          hi.z = f2bf(xv.z); lo.z = f2bf(xv.z - bf2f(hi.z));
          hi.w = f2bf(xv.w); lo.w = f2bf(xv.w - bf2f(hi.w));
          *(ushort4*)&Ths[r * G1_PITCH + c4] = hi;
          *(ushort4*)&Tls[r * G1_PITCH + c4] = lo;
        }
      }
      __syncthreads();

      f32x4 acc0 = {0.f, 0.f, 0.f, 0.f};
      f32x4 acc1 = {0.f, 0.f, 0.f, 0.f};
      f32x4 acc2 = {0.f, 0.f, 0.f, 0.f};
      f32x4 acc3 = {0.f, 0.f, 0.f, 0.f};
      #pragma unroll
      for (int s = 0; s < 4; ++s) {
        int k = (s << 5) + (quad << 3);
        bf16x8 ah = *(const bf16x8*)&Ths[(mt * 16 + m) * G1_PITCH + k];
        bf16x8 al = *(const bf16x8*)&Tls[(mt * 16 + m) * G1_PITCH + k];
        bf16x8 bh0 = *(const bf16x8*)&W1h[(size_t)((ntb + 0) * 16 + m) * 128 + k];
        bf16x8 bl0 = *(const bf16x8*)&W1l[(size_t)((ntb + 0) * 16 + m) * 128 + k];
        acc0 = __builtin_amdgcn_mfma_f32_16x16x32_bf16(ah, bh0, acc0, 0, 0, 0);
        acc0 = __builtin_amdgcn_mfma_f32_16x16x32_bf16(al, bh0, acc0, 0, 0, 0);
        acc0 = __builtin_amdgcn_mfma_f32_16x16x32_bf16(ah, bl0, acc0, 0, 0, 0);
        bf16x8 bh1 = *(const bf16x8*)&W1h[(size_t)((ntb + 1) * 16 + m) * 128 + k];
        bf16x8 bl1 = *(const bf16x8*)&W1l[(size_t)((ntb + 1) * 16 + m) * 128 + k];
        acc1 = __builtin_amdgcn_mfma_f32_16x16x32_bf16(ah, bh1, acc1, 0, 0, 0);
        acc1 = __builtin_amdgcn_mfma_f32_16x16x32_bf16(al, bh1, acc1, 0, 0, 0);
        acc1 = __builtin_amdgcn_mfma_f32_16x16x32_bf16(ah, bl1, acc1, 0, 0, 0);
        bf16x8 bh2 = *(const bf16x8*)&W1h[(size_t)((ntb + 2) * 16 + m) * 128 + k];
        bf16x8 bl2 = *(const bf16x8*)&W1l[(size_t)((ntb + 2) * 16 + m) * 128 + k];
        acc2 = __builtin_amdgcn_mfma_f32_16x16x32_bf16(ah, bh2, acc2, 0, 0, 0);
        acc2 = __builtin_amdgcn_mfma_f32_16x16x32_bf16(al, bh2, acc2, 0, 0, 0);
        acc2 = __builtin_amdgcn_mfma_f32_16x16x32_bf16(ah, bl2, acc2, 0, 0, 0);
        bf16x8 bh3 = *(const bf16x8*)&W1h[(size_t)((ntb + 3) * 16 + m) * 128 + k];
        bf16x8 bl3 = *(const bf16x8*)&W1l[(size_t)((ntb + 3) * 16 + m) * 128 + k];
        acc3 = __builtin_amdgcn_mfma_f32_16x16x32_bf16(ah, bh3, acc3, 0, 0, 0);
        acc3 = __builtin_amdgcn_mfma_f32_16x16x32_bf16(al, bh3, acc3, 0, 0, 0);
        acc3 = __builtin_amdgcn_mfma_f32_16x16x32_bf16(ah, bl3, acc3, 0, 0, 0);
      }
      // C/D layout: col = lane&15 (m), row = quad*4 + r
      #pragma unroll
      for (int r = 0; r < 4; ++r) {
        int row = mt * 16 + (quad << 2) + r;
        int g = row0 + row;
        if (g < n) {
          float sc = dinv[g];
          H[(size_t)g * D + (ntb + 0) * 16 + m] = f2bf(sc * acc0[r]);
          H[(size_t)g * D + (ntb + 1) * 16 + m] = f2bf(sc * acc1[r]);
          H[(size_t)g * D + (ntb + 2) * 16 + m] = f2bf(sc * acc2[r]);
          H[(size_t)g * D + (ntb + 3) * 16 + m] = f2bf(sc * acc3[r]);
        }
      }
    }
  }
}

// ---------------- gather helper: accumulate row i of Hs (bf16) ----------------

__device__ __forceinline__ void gather_row(const int* __restrict__ csr,
                                           const int* __restrict__ rend,
                                           const unsigned* __restrict__ Hu,
                                           int i, int lane, float& ax, float& ay) {
  int start = (i == 0) ? 0 : rend[i - 1];
  int end = rend[i];
  unsigned v = Hu[(size_t)i * 64 + lane];  // self-loop term
  ax = __uint_as_float(v << 16);
  ay = __uint_as_float(v & 0xFFFF0000u);
  int e = start;
  for (; e + 8 <= end; e += 8) {
    unsigned w0 = Hu[(size_t)csr[e + 0] * 64 + lane];
    unsigned w1 = Hu[(size_t)csr[e + 1] * 64 + lane];
    unsigned w2 = Hu[(size_t)csr[e + 2] * 64 + lane];
    unsigned w3 = Hu[(size_t)csr[e + 3] * 64 + lane];
    unsigned w4 = Hu[(size_t)csr[e + 4] * 64 + lane];
    unsigned w5 = Hu[(size_t)csr[e + 5] * 64 + lane];
    unsigned w6 = Hu[(size_t)csr[e + 6] * 64 + lane];
    unsigned w7 = Hu[(size_t)csr[e + 7] * 64 + lane];
    ax += __uint_as_float(w0 << 16) + __uint_as_float(w1 << 16) +
          __uint_as_float(w2 << 16) + __uint_as_float(w3 << 16) +
          __uint_as_float(w4 << 16) + __uint_as_float(w5 << 16) +
          __uint_as_float(w6 << 16) + __uint_as_float(w7 << 16);
    ay += __uint_as_float(w0 & 0xFFFF0000u) + __uint_as_float(w1 & 0xFFFF0000u) +
          __uint_as_float(w2 & 0xFFFF0000u) + __uint_as_float(w3 & 0xFFFF0000u) +
          __uint_as_float(w4 & 0xFFFF0000u) + __uint_as_float(w5 & 0xFFFF0000u) +
          __uint_as_float(w6 & 0xFFFF0000u) + __uint_as_float(w7 & 0xFFFF0000u);
  }
  for (; e < end; ++e) {
    unsigned w = Hu[(size_t)csr[e] * 64 + lane];
    ax += __uint_as_float(w << 16);
    ay += __uint_as_float(w & 0xFFFF0000u);
  }
}

// ---------------- standalone gather (final layer / fallback) ----------------

__global__ __launch_bounds__(256, 8) void gather_kernel(const int* __restrict__ csr,
                                                        const int* __restrict__ rend,
                                                        const float* __restrict__ dinv,
                                                        const unsigned* __restrict__ Hu,
                                                        const float* __restrict__ bias,
                                                        const float* __restrict__ perturb,
                                                        float* __restrict__ out, int n) {
  int i = (blockIdx.x << 2) + (threadIdx.x >> 6);
  if (i >= n) return;
  int lane = threadIdx.x & 63;
  float ax, ay;
  gather_row(csr, rend, Hu, i, lane, ax, ay);
  float di = dinv[i];
  float2 p = ((const float2*)(perturb + (size_t)i * D))[lane];
  float2 o;
  o.x = bias[2 * lane + 0] + p.x + di * ax;
  o.y = bias[2 * lane + 1] + p.y + di * ay;
  ((float2*)(out + (size_t)i * D))[lane] = o;
}

// ---------------- fused gather1 + GEMM2 (MFMA bf16) ----------------

#define GG_PITCH 136

__global__ __launch_bounds__(512, 8) void gather_gemm_kernel(
    const int* __restrict__ csr, const int* __restrict__ rend,
    const float* __restrict__ dinv, const unsigned* __restrict__ Hu,
    const float* __restrict__ bias, const float* __restrict__ perturb,
    const unsigned short* __restrict__ W2bf, unsigned short* __restrict__ H2, int n) {
  __shared__ unsigned short Ts[32 * GG_PITCH];  // 8.5 KB
  const int tid = threadIdx.x;
  const int wv = tid >> 6;
  const int lane = tid & 63;
  const int base = blockIdx.x << 5;  // 32 nodes per block

  // phase 1: gather 4 nodes per wave -> Ts
  #pragma unroll
  for (int j = 0; j < 4; ++j) {
    int row = (wv << 2) + j;
    int i = base + row;
    if (i < n) {
      float ax, ay;
      gather_row(csr, rend, Hu, i, lane, ax, ay);
      float di = dinv[i];
      float2 p = ((const float2*)(perturb + (size_t)i * D))[lane];
      float ox = bias[2 * lane + 0] + p.x + di * ax;
      float oy = bias[2 * lane + 1] + p.y + di * ay;
      unsigned pack = (unsigned)f2bf(ox) | ((unsigned)f2bf(oy) << 16);
      *(unsigned*)&Ts[row * GG_PITCH + (lane << 1)] = pack;
    }
  }
  __syncthreads();

  // phase 2: R[32][128] = Ts @ W2bf^T ; wave wv: m-tile = wv>>2, n-tiles {wv&3, (wv&3)+4}
  const int mt = wv >> 2;
  const int nt0 = wv & 3;
  const int m = lane & 15;
  const int quad = lane >> 4;  // 0..3
  const unsigned short* Wrow0 = W2bf + (size_t)(nt0 * 16 + m) * 128;
  const unsigned short* Wrow1 = W2bf + (size_t)((nt0 + 4) * 16 + m) * 128;
  f32x4 acc0 = {0.f, 0.f, 0.f, 0.f};
  f32x4 acc1 = {0.f, 0.f, 0.f, 0.f};
  #pragma unroll
  for (int s = 0; s < 4; ++s) {
    int k = (s << 5) + (quad << 3);
    bf16x8 a  = *(const bf16x8*)&Ts[(mt * 16 + m) * GG_PITCH + k];
    bf16x8 b0 = *(const bf16x8*)&Wrow0[k];
    bf16x8 b1 = *(const bf16x8*)&Wrow1[k];
    acc0 = __builtin_amdgcn_mfma_f32_16x16x32_bf16(a, b0, acc0, 0, 0, 0);
    acc1 = __builtin_amdgcn_mfma_f32_16x16x32_bf16(a, b1, acc1, 0, 0, 0);
  }
  // C/D layout: col = lane&15, row = quad*4 + reg
  #pragma unroll
  for (int r = 0; r < 4; ++r) {
    int row = mt * 16 + (quad << 2) + r;
    int g = base + row;
    if (g < n) {
      float s = dinv[g];
      H2[(size_t)g * D + nt0 * 16 + m]       = f2bf(s * acc0[r]);
      H2[(size_t)g * D + (nt0 + 4) * 16 + m] = f2bf(s * acc1[r]);
    }
  }
}

// ---------------- launch ----------------

extern "C" void kernel_launch(void* const* d_in, const int* in_sizes, int n_in,
                              void* d_out, int out_size, void* d_ws, size_t ws_size,
                              hipStream_t stream) {
  const float* x  = (const float*)d_in[0];
  const int*   ei = (const int*)d_in[1];
  const float* pf = (const float*)d_in[2];
  const float* pl = (const float*)d_in[3];
  const float* W1 = (const float*)d_in[4];
  const float* b1 = (const float*)d_in[5];
  const float* W2 = (const float*)d_in[6];
  const float* b2 = (const float*)d_in[7];
  float* out = (float*)d_out;

  const int n = in_sizes[0] / D;
  const int E = in_sizes[1] / 2;
  const int* src = ei;      // edge_index[0]
  const int* dst = ei + E;  // edge_index[1]

  // workspace layout
  int*   deg       = (int*)d_ws;                 // [n]
  float* dinv      = (float*)d_ws + n;           // [n]
  int*   ptr       = (int*)d_ws + 2 * n;         // [n] (becomes row_end after fill)
  int*   blockSums = (int*)d_ws + 3 * n;         // [<=512]
  int*   csr       = (int*)d_ws + 3 * n + 512;   // [E]
  size_t a1_off = ((size_t)(3 * n + 512 + E) * 4 + 255) & ~(size_t)255;
  unsigned short* A1 = (unsigned short*)((char*)d_ws + a1_off);
  unsigned short* A2 = A1 + (size_t)n * D;
  unsigned short* W2bf = A2 + (size_t)n * D;     // [128*128] bf16, 32 KB
  unsigned short* W1h  = W2bf + 128 * 128;       // [128*128] bf16, 32 KB
  unsigned short* W1l  = W1h + 128 * 128;        // [128*128] bf16, 32 KB
  size_t needed = a1_off + (2 * (size_t)n * D + 3 * 128 * 128) * sizeof(unsigned short);
  const bool fused_l2 = (ws_size >= needed);  // constant across calls -> capture-safe

  const int nb_n = (n + 255) / 256;
  const int nb_e = (E + 255) / 256;
  const int nb_g = (n + 3) / 4;

  hipMemsetAsync(deg, 0, (size_t)n * sizeof(int), stream);
  count_deg_kernel<<<nb_e + 16, 256, 0, stream>>>(
      dst, E, deg, W2, fused_l2 ? W2bf : (unsigned short*)nullptr, W1, W1h, W1l);
  scan_blocksum_kernel<<<nb_n, 256, 0, stream>>>(deg, n, blockSums);
  scan_top_kernel<<<1, 512, 0, stream>>>(blockSums, nb_n);
  scan_write_kernel<<<nb_n, 256, 0, stream>>>(deg, n, blockSums, ptr, dinv);

  if (fused_l2) {
    // layer 1: CSR fill || Hs1 = dinv*(x@W1^T) via MFMA bf16x3 -> A1
    fused_fill_mfma_kernel<<<FUSED_GRID, 256, 0, stream>>>(src, dst, ptr, csr, E, x, W1h, W1l,
                                                           dinv, A1, n);
    // gather1 + GEMM2 fused -> A2 ; gather2 -> out
    gather_gemm_kernel<<<(n + 31) / 32, 512, 0, stream>>>(csr, ptr, dinv, (const unsigned*)A1,
                                                          b1, pf, W2bf, A2, n);
    gather_kernel<<<nb_g, 256, 0, stream>>>(csr, ptr, dinv, (const unsigned*)A2, b2, pl, out, n);
  } else {
    // fallback (round-3 path): fp32 VALU gemm, unfused layers
    fused_fill_gemm_kernel<<<FUSED_GRID, 256, 0, stream>>>(src, dst, ptr, csr, E, x, W1, dinv, A1, n);
    gather_kernel<<<nb_g, 256, 0, stream>>>(csr, ptr, dinv, (const unsigned*)A1, b1, pf, out, n);
    gemm128_kernel<<<1024, 256, 0, stream>>>(out, W2, dinv, A1, n);
    gather_kernel<<<nb_g, 256, 0, stream>>>(csr, ptr, dinv, (const unsigned*)A1, b2, pl, out, n);
  }
}

// Round 6
// 525.674 us; speedup vs baseline: 1.1104x; 1.0647x over previous
//
#include <hip/hip_runtime.h>
#include <math.h>

#define D 128
#define WS_PAD 132  // 128+4: breaks stride-128 bank pattern, keeps 16B align

typedef short bf16x8 __attribute__((ext_vector_type(8)));  // 8 bf16 in 4 VGPRs
typedef float f32x4 __attribute__((ext_vector_type(4)));

__device__ __forceinline__ unsigned short f2bf(float f) {
  unsigned u = __float_as_uint(f);
  u += 0x7FFFu + ((u >> 16) & 1u);  // round-to-nearest-even
  return (unsigned short)(u >> 16);
}

__device__ __forceinline__ float bf2f(unsigned short h) {
  return __uint_as_float(((unsigned)h) << 16);
}

// ---------------- degree count + edge rank (+ fused weight-table prep) ----------------
// rank[e] = position of edge e within its dst row = atomicAdd return value.
// This is the SAME atomic the old CSR fill re-did; saving it makes the fill atomic-free.
// rank aliases the A2 buffer (dead until gather_gemm). 4 edges/thread for atomic MLP;
// rank stores are coalesced int4.

__global__ __launch_bounds__(256) void count_deg_kernel(const int* __restrict__ dst, int E,
                                                        int* __restrict__ deg,
                                                        int* __restrict__ rank,
                                                        const float* __restrict__ W2,
                                                        unsigned short* __restrict__ W2bf,
                                                        const float* __restrict__ W1,
                                                        unsigned short* __restrict__ W1h,
                                                        unsigned short* __restrict__ W1l) {
  int nbe = (E + 1023) >> 10;  // 4 edges per thread
  int b = blockIdx.x;
  if (b >= nbe) {
    if (W2bf == nullptr) return;
    int which = b - nbe;  // 0..15
    if (which < 8) {
      // convert W2 (128x128 fp32) -> bf16 once
      int t = which * 256 + threadIdx.x;  // 0..2047
      #pragma unroll
      for (int q = 0; q < 2; ++q) {
        int idx = t + q * 2048;  // float4 index, 0..4095
        float4 w = ((const float4*)W2)[idx];
        ushort4 o;
        o.x = f2bf(w.x); o.y = f2bf(w.y); o.z = f2bf(w.z); o.w = f2bf(w.w);
        ((ushort4*)W2bf)[idx] = o;
      }
    } else {
      // split W1 -> bf16 hi + lo (residual) for bf16x3 fp32-accurate MFMA
      int t = (which - 8) * 256 + threadIdx.x;  // 0..2047
      #pragma unroll
      for (int q = 0; q < 2; ++q) {
        int idx = t + q * 2048;
        float4 w = ((const float4*)W1)[idx];
        ushort4 hi, lo;
        hi.x = f2bf(w.x); lo.x = f2bf(w.x - bf2f(hi.x));
        hi.y = f2bf(w.y); lo.y = f2bf(w.y - bf2f(hi.y));
        hi.z = f2bf(w.z); lo.z = f2bf(w.z - bf2f(hi.z));
        hi.w = f2bf(w.w); lo.w = f2bf(w.w - bf2f(hi.w));
        ((ushort4*)W1h)[idx] = hi;
        ((ushort4*)W1l)[idx] = lo;
      }
    }
    return;
  }
  int e0 = (b * 256 + threadIdx.x) * 4;
  if (rank != nullptr) {
    if (e0 + 4 <= E && ((E & 3) == 0)) {  // dst = ei+E is int4-aligned when E%4==0
      int4 d = *(const int4*)(dst + e0);
      int r0 = atomicAdd(&deg[d.x], 1);
      int r1 = atomicAdd(&deg[d.y], 1);
      int r2 = atomicAdd(&deg[d.z], 1);
      int r3 = atomicAdd(&deg[d.w], 1);
      *(int4*)(rank + e0) = make_int4(r0, r1, r2, r3);
    } else {
      for (int e = e0; e < E && e < e0 + 4; ++e) rank[e] = atomicAdd(&deg[dst[e]], 1);
    }
  } else {
    for (int e = e0; e < E && e < e0 + 4; ++e) atomicAdd(&deg[dst[e]], 1);
  }
}

// ---------------- exclusive prefix scan of deg -> ptr ----------------

__global__ __launch_bounds__(256) void scan_blocksum_kernel(const int* __restrict__ deg, int n,
                                                            int* __restrict__ blockSums) {
  __shared__ int sm[256];
  int t = threadIdx.x;
  int i = blockIdx.x * 256 + t;
  sm[t] = (i < n) ? deg[i] : 0;
  __syncthreads();
  for (int off = 128; off > 0; off >>= 1) {
    if (t < off) sm[t] += sm[t + off];
    __syncthreads();
  }
  if (t == 0) blockSums[blockIdx.x] = sm[0];
}

// single block, 512 threads; nb <= 512
__global__ __launch_bounds__(512) void scan_top_kernel(int* __restrict__ blockSums, int nb) {
  __shared__ int sm[512];
  int t = threadIdx.x;
  int v = (t < nb) ? blockSums[t] : 0;
  sm[t] = v;
  __syncthreads();
  for (int off = 1; off < 512; off <<= 1) {
    int x = (t >= off) ? sm[t - off] : 0;
    __syncthreads();
    sm[t] += x;
    __syncthreads();
  }
  if (t < nb) blockSums[t] = sm[t] - v;  // exclusive
}

// also computes dinv, and writes ptr[n] = E (ptr stays an immutable start-offset array)
__global__ __launch_bounds__(256) void scan_write_kernel(const int* __restrict__ deg, int n,
                                                         const int* __restrict__ blockSums,
                                                         int* __restrict__ ptr,
                                                         float* __restrict__ dinv) {
  __shared__ int sm[256];
  int t = threadIdx.x;
  int i = blockIdx.x * 256 + t;
  int v = (i < n) ? deg[i] : 0;
  sm[t] = v;
  __syncthreads();
  for (int off = 1; off < 256; off <<= 1) {
    int x = (t >= off) ? sm[t - off] : 0;
    __syncthreads();
    sm[t] += x;
    __syncthreads();
  }
  if (i < n) {
    int ex = blockSums[blockIdx.x] + sm[t] - v;
    ptr[i] = ex;                             // exclusive prefix (row start)
    dinv[i] = 1.0f / sqrtf((float)(v + 1));  // +1: self-loop
    if (i == n - 1) ptr[n] = ex + v;         // = E
  }
}

// ---------------- legacy fp32 VALU GEMM body (fallback path only) ----------------

__device__ __forceinline__ void gemm_body(const float* __restrict__ X,
                                          const float* __restrict__ W,
                                          const float* __restrict__ dinv,
                                          unsigned short* __restrict__ H, int n,
                                          int bid, int nblocks,
                                          float* __restrict__ Ws, float* __restrict__ Xs) {
  const int tid = threadIdx.x;
  const int tx = tid & 31;
  const int ty = tid >> 5;
  const int ntiles = (n + 31) >> 5;

  for (int tile = bid; tile < ntiles; tile += nblocks) {
    const int row0 = tile << 5;
    const int rows_here = min(32, n - row0);
    __syncthreads();
    {
      const float4* Xg = (const float4*)(X + (size_t)row0 * D);
      int tmax = rows_here * 32;
      for (int t = tid; t < tmax; t += 256) ((float4*)Xs)[t] = Xg[t];
    }
    float acc[4][4] = {{0.f}};
    #pragma unroll
    for (int kt = 0; kt < 128; kt += 64) {
      __syncthreads();
      for (int t = tid; t < 2048; t += 256) {
        int j  = t >> 4;
        int k4 = (t & 15) << 2;
        float4 w = ((const float4*)W)[j * 32 + (kt >> 2) + (t & 15)];
        Ws[(k4 + 0) * WS_PAD + j] = w.x;
        Ws[(k4 + 1) * WS_PAD + j] = w.y;
        Ws[(k4 + 2) * WS_PAD + j] = w.z;
        Ws[(k4 + 3) * WS_PAD + j] = w.w;
      }
      __syncthreads();
      #pragma unroll 4
      for (int k = 0; k < 64; ++k) {
        float4 w = *(const float4*)&Ws[k * WS_PAD + (tx << 2)];
        #pragma unroll
        for (int r = 0; r < 4; ++r) {
          float xv = Xs[(ty + 8 * r) * 128 + (kt + k)];
          acc[r][0] += xv * w.x;
          acc[r][1] += xv * w.y;
          acc[r][2] += xv * w.z;
          acc[r][3] += xv * w.w;
        }
      }
    }
    #pragma unroll
    for (int r = 0; r < 4; ++r) {
      int row = row0 + ty + 8 * r;
      if (row < n) {
        float s = dinv[row];
        unsigned h0 = f2bf(s * acc[r][0]);
        unsigned h1 = f2bf(s * acc[r][1]);
        unsigned h2 = f2bf(s * acc[r][2]);
        unsigned h3 = f2bf(s * acc[r][3]);
        ((uint2*)(H + (size_t)row * D))[tx] = make_uint2(h0 | (h1 << 16), h2 | (h3 << 16));
      }
    }
  }
}

// ---------------- legacy fused fill+GEMM (fallback path only; atomic fill) ----------------

__global__ __launch_bounds__(256) void fused_fill_gemm_kernel(
    const int* __restrict__ src, const int* __restrict__ dst,
    int* __restrict__ ptr, int* __restrict__ csr, int E,
    const float* __restrict__ X, const float* __restrict__ W,
    const float* __restrict__ dinv, unsigned short* __restrict__ H, int n) {
  __shared__ float Ws[64 * WS_PAD];
  __shared__ float Xs[32 * 128];
  int sub = blockIdx.x & 7;
  if (sub < 2) {
    int fb = (blockIdx.x >> 3) * 2 + sub;
    int stride = 512 * 256;
    for (int e = fb * 256 + threadIdx.x; e < E; e += stride) {
      int d = dst[e];
      int pos = atomicAdd(&ptr[d], 1);
      csr[pos] = src[e];
    }
  } else {
    int gb = (blockIdx.x >> 3) * 6 + (sub - 2);
    gemm_body(X, W, dinv, H, n, gb, 1536, Ws, Xs);
  }
}

__global__ __launch_bounds__(256) void gemm128_kernel(const float* __restrict__ X,
                                                      const float* __restrict__ W,
                                                      const float* __restrict__ dinv,
                                                      unsigned short* __restrict__ H, int n) {
  __shared__ float Ws[64 * WS_PAD];
  __shared__ float Xs[32 * 128];
  gemm_body(X, W, dinv, H, n, blockIdx.x, gridDim.x, Ws, Xs);
}

// ---------------- fused: atomic-free CSR fill || GEMM1 via MFMA bf16x3 ----------------
// Fill: csr[ptr[d] + rank[e]] = src[e]. No atomics, no RMW — just coalesced loads
// (dst, src, rank), one L2-cached random read (ptr[d]), one scatter store.
// GEMM1: H[n,128](bf16) = dinv[i]*(X@W1^T) fp32-accurate via bf16 hi/lo split.

#define FUSED_GRID 2048
#define G1_PITCH 136

__global__ __launch_bounds__(256) void fused_fill_mfma_kernel(
    const int* __restrict__ src, const int* __restrict__ dst,
    const int* __restrict__ ptr, const int* __restrict__ rank,
    int* __restrict__ csr, int E,
    const float* __restrict__ X,
    const unsigned short* __restrict__ W1h, const unsigned short* __restrict__ W1l,
    const float* __restrict__ dinv, unsigned short* __restrict__ H, int n) {
  __shared__ unsigned short Ths[32 * G1_PITCH];  // 8.7 KB
  __shared__ unsigned short Tls[32 * G1_PITCH];  // 8.7 KB
  int sub = blockIdx.x & 7;
  if (sub < 2) {
    // atomic-free CSR fill, 512 blocks, 8 edges per thread
    int fb = (blockIdx.x >> 3) * 2 + sub;
    const int T8 = 512 * 256 * 8;
    int t = fb * 256 + threadIdx.x;
    const bool al16 = ((E & 3) == 0);
    for (int e0 = t * 8; e0 < E; e0 += T8) {
      if (e0 + 8 <= E && al16) {
        int4 d0 = ((const int4*)(dst + e0))[0];
        int4 d1 = ((const int4*)(dst + e0))[1];
        int4 s0 = ((const int4*)(src + e0))[0];
        int4 s1 = ((const int4*)(src + e0))[1];
        int4 r0 = ((const int4*)(rank + e0))[0];
        int4 r1 = ((const int4*)(rank + e0))[1];
        int p0 = ptr[d0.x] + r0.x;
        int p1 = ptr[d0.y] + r0.y;
        int p2 = ptr[d0.z] + r0.z;
        int p3 = ptr[d0.w] + r0.w;
        int p4 = ptr[d1.x] + r1.x;
        int p5 = ptr[d1.y] + r1.y;
        int p6 = ptr[d1.z] + r1.z;
        int p7 = ptr[d1.w] + r1.w;
        csr[p0] = s0.x; csr[p1] = s0.y; csr[p2] = s0.z; csr[p3] = s0.w;
        csr[p4] = s1.x; csr[p5] = s1.y; csr[p6] = s1.z; csr[p7] = s1.w;
      } else {
        for (int e = e0; e < E && e < e0 + 8; ++e)
          csr[ptr[dst[e]] + rank[e]] = src[e];
      }
    }
  } else {
    // GEMM1: 1536 blocks, 32 rows per tile, grid-strided
    int gb = (blockIdx.x >> 3) * 6 + (sub - 2);
    const int tid = threadIdx.x;
    const int wv = tid >> 6;       // 0..3
    const int lane = tid & 63;
    const int m = lane & 15;
    const int quad = lane >> 4;    // 0..3
    const int mt = wv >> 1;        // 0..1  (16-row m-tile)
    const int ntb = (wv & 1) * 4;  // n-tile base: 4 consecutive 16-col tiles
    const int ntiles = (n + 31) >> 5;

    for (int tile = gb; tile < ntiles; tile += 1536) {
      const int row0 = tile << 5;
      const int rows_here = min(32, n - row0);
      __syncthreads();  // protect LDS from previous iteration's readers
      {
        const float4* Xg = (const float4*)(X + (size_t)row0 * D);
        int tmax = rows_here * 32;
        for (int t = tid; t < tmax; t += 256) {
          float4 xv = Xg[t];
          int r = t >> 5, c4 = (t & 31) << 2;
          ushort4 hi, lo;
          hi.x = f2bf(xv.x); lo.x = f2bf(xv.x - bf2f(hi.x));
          hi.y = f2bf(xv.y); lo.y = f2bf(xv.y - bf2f(hi.y));
          hi.z = f2bf(xv.z); lo.z = f2bf(xv.z - bf2f(hi.z));
          hi.w = f2bf(xv.w); lo.w = f2bf(xv.w - bf2f(hi.w));
          *(ushort4*)&Ths[r * G1_PITCH + c4] = hi;
          *(ushort4*)&Tls[r * G1_PITCH + c4] = lo;
        }
      }
      __syncthreads();

      f32x4 acc0 = {0.f, 0.f, 0.f, 0.f};
      f32x4 acc1 = {0.f, 0.f, 0.f, 0.f};
      f32x4 acc2 = {0.f, 0.f, 0.f, 0.f};
      f32x4 acc3 = {0.f, 0.f, 0.f, 0.f};
      #pragma unroll
      for (int s = 0; s < 4; ++s) {
        int k = (s << 5) + (quad << 3);
        bf16x8 ah = *(const bf16x8*)&Ths[(mt * 16 + m) * G1_PITCH + k];
        bf16x8 al = *(const bf16x8*)&Tls[(mt * 16 + m) * G1_PITCH + k];
        bf16x8 bh0 = *(const bf16x8*)&W1h[(size_t)((ntb + 0) * 16 + m) * 128 + k];
        bf16x8 bl0 = *(const bf16x8*)&W1l[(size_t)((ntb + 0) * 16 + m) * 128 + k];
        acc0 = __builtin_amdgcn_mfma_f32_16x16x32_bf16(ah, bh0, acc0, 0, 0, 0);
        acc0 = __builtin_amdgcn_mfma_f32_16x16x32_bf16(al, bh0, acc0, 0, 0, 0);
        acc0 = __builtin_amdgcn_mfma_f32_16x16x32_bf16(ah, bl0, acc0, 0, 0, 0);
        bf16x8 bh1 = *(const bf16x8*)&W1h[(size_t)((ntb + 1) * 16 + m) * 128 + k];
        bf16x8 bl1 = *(const bf16x8*)&W1l[(size_t)((ntb + 1) * 16 + m) * 128 + k];
        acc1 = __builtin_amdgcn_mfma_f32_16x16x32_bf16(ah, bh1, acc1, 0, 0, 0);
        acc1 = __builtin_amdgcn_mfma_f32_16x16x32_bf16(al, bh1, acc1, 0, 0, 0);
        acc1 = __builtin_amdgcn_mfma_f32_16x16x32_bf16(ah, bl1, acc1, 0, 0, 0);
        bf16x8 bh2 = *(const bf16x8*)&W1h[(size_t)((ntb + 2) * 16 + m) * 128 + k];
        bf16x8 bl2 = *(const bf16x8*)&W1l[(size_t)((ntb + 2) * 16 + m) * 128 + k];
        acc2 = __builtin_amdgcn_mfma_f32_16x16x32_bf16(ah, bh2, acc2, 0, 0, 0);
        acc2 = __builtin_amdgcn_mfma_f32_16x16x32_bf16(al, bh2, acc2, 0, 0, 0);
        acc2 = __builtin_amdgcn_mfma_f32_16x16x32_bf16(ah, bl2, acc2, 0, 0, 0);
        bf16x8 bh3 = *(const bf16x8*)&W1h[(size_t)((ntb + 3) * 16 + m) * 128 + k];
        bf16x8 bl3 = *(const bf16x8*)&W1l[(size_t)((ntb + 3) * 16 + m) * 128 + k];
        acc3 = __builtin_amdgcn_mfma_f32_16x16x32_bf16(ah, bh3, acc3, 0, 0, 0);
        acc3 = __builtin_amdgcn_mfma_f32_16x16x32_bf16(al, bh3, acc3, 0, 0, 0);
        acc3 = __builtin_amdgcn_mfma_f32_16x16x32_bf16(ah, bl3, acc3, 0, 0, 0);
      }
      // C/D layout: col = lane&15 (m), row = quad*4 + r
      #pragma unroll
      for (int r = 0; r < 4; ++r) {
        int row = mt * 16 + (quad << 2) + r;
        int g = row0 + row;
        if (g < n) {
          float sc = dinv[g];
          H[(size_t)g * D + (ntb + 0) * 16 + m] = f2bf(sc * acc0[r]);
          H[(size_t)g * D + (ntb + 1) * 16 + m] = f2bf(sc * acc1[r]);
          H[(size_t)g * D + (ntb + 2) * 16 + m] = f2bf(sc * acc2[r]);
          H[(size_t)g * D + (ntb + 3) * 16 + m] = f2bf(sc * acc3[r]);
        }
      }
    }
  }
}

// ---------------- gather helper: accumulate row i of Hs (bf16), explicit bounds ----------------

__device__ __forceinline__ void gather_row(const int* __restrict__ csr, int start, int end,
                                           const unsigned* __restrict__ Hu,
                                           int i, int lane, float& ax, float& ay) {
  unsigned v = Hu[(size_t)i * 64 + lane];  // self-loop term
  ax = __uint_as_float(v << 16);
  ay = __uint_as_float(v & 0xFFFF0000u);
  int e = start;
  for (; e + 8 <= end; e += 8) {
    unsigned w0 = Hu[(size_t)csr[e + 0] * 64 + lane];
    unsigned w1 = Hu[(size_t)csr[e + 1] * 64 + lane];
    unsigned w2 = Hu[(size_t)csr[e + 2] * 64 + lane];
    unsigned w3 = Hu[(size_t)csr[e + 3] * 64 + lane];
    unsigned w4 = Hu[(size_t)csr[e + 4] * 64 + lane];
    unsigned w5 = Hu[(size_t)csr[e + 5] * 64 + lane];
    unsigned w6 = Hu[(size_t)csr[e + 6] * 64 + lane];
    unsigned w7 = Hu[(size_t)csr[e + 7] * 64 + lane];
    ax += __uint_as_float(w0 << 16) + __uint_as_float(w1 << 16) +
          __uint_as_float(w2 << 16) + __uint_as_float(w3 << 16) +
          __uint_as_float(w4 << 16) + __uint_as_float(w5 << 16) +
          __uint_as_float(w6 << 16) + __uint_as_float(w7 << 16);
    ay += __uint_as_float(w0 & 0xFFFF0000u) + __uint_as_float(w1 & 0xFFFF0000u) +
          __uint_as_float(w2 & 0xFFFF0000u) + __uint_as_float(w3 & 0xFFFF0000u) +
          __uint_as_float(w4 & 0xFFFF0000u) + __uint_as_float(w5 & 0xFFFF0000u) +
          __uint_as_float(w6 & 0xFFFF0000u) + __uint_as_float(w7 & 0xFFFF0000u);
  }
  for (; e < end; ++e) {
    unsigned w = Hu[(size_t)csr[e] * 64 + lane];
    ax += __uint_as_float(w << 16);
    ay += __uint_as_float(w & 0xFFFF0000u);
  }
}

// ---------------- standalone gather: new semantics (rptr[i], rptr[i+1]) ----------------

__global__ __launch_bounds__(256, 8) void gather_kernel(const int* __restrict__ csr,
                                                        const int* __restrict__ rptr,
                                                        const float* __restrict__ dinv,
                                                        const unsigned* __restrict__ Hu,
                                                        const float* __restrict__ bias,
                                                        const float* __restrict__ perturb,
                                                        float* __restrict__ out, int n) {
  int i = (blockIdx.x << 2) + (threadIdx.x >> 6);
  if (i >= n) return;
  int lane = threadIdx.x & 63;
  float ax, ay;
  gather_row(csr, rptr[i], rptr[i + 1], Hu, i, lane, ax, ay);
  float di = dinv[i];
  float2 p = ((const float2*)(perturb + (size_t)i * D))[lane];
  float2 o;
  o.x = bias[2 * lane + 0] + p.x + di * ax;
  o.y = bias[2 * lane + 1] + p.y + di * ay;
  ((float2*)(out + (size_t)i * D))[lane] = o;
}

// legacy semantics (rend[i-1], rend[i]) for the atomic-fill fallback path
__global__ __launch_bounds__(256, 8) void gather_kernel_old(const int* __restrict__ csr,
                                                            const int* __restrict__ rend,
                                                            const float* __restrict__ dinv,
                                                            const unsigned* __restrict__ Hu,
                                                            const float* __restrict__ bias,
                                                            const float* __restrict__ perturb,
                                                            float* __restrict__ out, int n) {
  int i = (blockIdx.x << 2) + (threadIdx.x >> 6);
  if (i >= n) return;
  int lane = threadIdx.x & 63;
  int start = (i == 0) ? 0 : rend[i - 1];
  float ax, ay;
  gather_row(csr, start, rend[i], Hu, i, lane, ax, ay);
  float di = dinv[i];
  float2 p = ((const float2*)(perturb + (size_t)i * D))[lane];
  float2 o;
  o.x = bias[2 * lane + 0] + p.x + di * ax;
  o.y = bias[2 * lane + 1] + p.y + di * ay;
  ((float2*)(out + (size_t)i * D))[lane] = o;
}

// ---------------- fused gather1 + GEMM2 (MFMA bf16) ----------------

#define GG_PITCH 136

__global__ __launch_bounds__(512, 8) void gather_gemm_kernel(
    const int* __restrict__ csr, const int* __restrict__ rptr,
    const float* __restrict__ dinv, const unsigned* __restrict__ Hu,
    const float* __restrict__ bias, const float* __restrict__ perturb,
    const unsigned short* __restrict__ W2bf, unsigned short* __restrict__ H2, int n) {
  __shared__ unsigned short Ts[32 * GG_PITCH];  // 8.5 KB
  const int tid = threadIdx.x;
  const int wv = tid >> 6;
  const int lane = tid & 63;
  const int base = blockIdx.x << 5;  // 32 nodes per block

  // phase 1: gather 4 nodes per wave -> Ts
  #pragma unroll
  for (int j = 0; j < 4; ++j) {
    int row = (wv << 2) + j;
    int i = base + row;
    if (i < n) {
      float ax, ay;
      gather_row(csr, rptr[i], rptr[i + 1], Hu, i, lane, ax, ay);
      float di = dinv[i];
      float2 p = ((const float2*)(perturb + (size_t)i * D))[lane];
      float ox = bias[2 * lane + 0] + p.x + di * ax;
      float oy = bias[2 * lane + 1] + p.y + di * ay;
      unsigned pack = (unsigned)f2bf(ox) | ((unsigned)f2bf(oy) << 16);
      *(unsigned*)&Ts[row * GG_PITCH + (lane << 1)] = pack;
    }
  }
  __syncthreads();

  // phase 2: R[32][128] = Ts @ W2bf^T ; wave wv: m-tile = wv>>2, n-tiles {wv&3, (wv&3)+4}
  const int mt = wv >> 2;
  const int nt0 = wv & 3;
  const int m = lane & 15;
  const int quad = lane >> 4;  // 0..3
  const unsigned short* Wrow0 = W2bf + (size_t)(nt0 * 16 + m) * 128;
  const unsigned short* Wrow1 = W2bf + (size_t)((nt0 + 4) * 16 + m) * 128;
  f32x4 acc0 = {0.f, 0.f, 0.f, 0.f};
  f32x4 acc1 = {0.f, 0.f, 0.f, 0.f};
  #pragma unroll
  for (int s = 0; s < 4; ++s) {
    int k = (s << 5) + (quad << 3);
    bf16x8 a  = *(const bf16x8*)&Ts[(mt * 16 + m) * GG_PITCH + k];
    bf16x8 b0 = *(const bf16x8*)&Wrow0[k];
    bf16x8 b1 = *(const bf16x8*)&Wrow1[k];
    acc0 = __builtin_amdgcn_mfma_f32_16x16x32_bf16(a, b0, acc0, 0, 0, 0);
    acc1 = __builtin_amdgcn_mfma_f32_16x16x32_bf16(a, b1, acc1, 0, 0, 0);
  }
  // C/D layout: col = lane&15, row = quad*4 + reg
  #pragma unroll
  for (int r = 0; r < 4; ++r) {
    int row = mt * 16 + (quad << 2) + r;
    int g = base + row;
    if (g < n) {
      float s = dinv[g];
      H2[(size_t)g * D + nt0 * 16 + m]       = f2bf(s * acc0[r]);
      H2[(size_t)g * D + (nt0 + 4) * 16 + m] = f2bf(s * acc1[r]);
    }
  }
}

// ---------------- launch ----------------

extern "C" void kernel_launch(void* const* d_in, const int* in_sizes, int n_in,
                              void* d_out, int out_size, void* d_ws, size_t ws_size,
                              hipStream_t stream) {
  const float* x  = (const float*)d_in[0];
  const int*   ei = (const int*)d_in[1];
  const float* pf = (const float*)d_in[2];
  const float* pl = (const float*)d_in[3];
  const float* W1 = (const float*)d_in[4];
  const float* b1 = (const float*)d_in[5];
  const float* W2 = (const float*)d_in[6];
  const float* b2 = (const float*)d_in[7];
  float* out = (float*)d_out;

  const int n = in_sizes[0] / D;
  const int E = in_sizes[1] / 2;
  const int* src = ei;      // edge_index[0]
  const int* dst = ei + E;  // edge_index[1]

  // workspace layout
  int*   deg       = (int*)d_ws;                     // [n]
  float* dinv      = (float*)d_ws + n;               // [n]
  int*   ptr       = (int*)d_ws + 2 * n;             // [n+1] (start offsets; immutable in fused path)
  int*   blockSums = (int*)d_ws + 3 * n + 1;         // [<=512]
  int*   csr       = (int*)d_ws + 3 * n + 1 + 512;   // [E]
  size_t a1_off = ((size_t)(3 * n + 1 + 512 + E) * 4 + 255) & ~(size_t)255;
  unsigned short* A1 = (unsigned short*)((char*)d_ws + a1_off);
  unsigned short* A2 = A1 + (size_t)n * D;
  unsigned short* W2bf = A2 + (size_t)n * D;     // [128*128] bf16, 32 KB
  unsigned short* W1h  = W2bf + 128 * 128;       // [128*128] bf16, 32 KB
  unsigned short* W1l  = W1h + 128 * 128;        // [128*128] bf16, 32 KB
  int* rank = (int*)A2;                          // [E] aliases A2 (dead until gather_gemm)
  size_t needed = a1_off + (2 * (size_t)n * D + 3 * 128 * 128) * sizeof(unsigned short);
  const bool fused_l2 = (ws_size >= needed);  // constant across calls -> capture-safe

  const int nb_n = (n + 255) / 256;
  const int nb_e4 = (E + 1023) / 1024;
  const int nb_g = (n + 3) / 4;

  hipMemsetAsync(deg, 0, (size_t)n * sizeof(int), stream);
  count_deg_kernel<<<nb_e4 + 16, 256, 0, stream>>>(
      dst, E, deg, fused_l2 ? rank : (int*)nullptr, W2,
      fused_l2 ? W2bf : (unsigned short*)nullptr, W1, W1h, W1l);
  scan_blocksum_kernel<<<nb_n, 256, 0, stream>>>(deg, n, blockSums);
  scan_top_kernel<<<1, 512, 0, stream>>>(blockSums, nb_n);
  scan_write_kernel<<<nb_n, 256, 0, stream>>>(deg, n, blockSums, ptr, dinv);

  if (fused_l2) {
    // layer 1: atomic-free CSR fill || Hs1 = dinv*(x@W1^T) via MFMA bf16x3 -> A1
    fused_fill_mfma_kernel<<<FUSED_GRID, 256, 0, stream>>>(src, dst, ptr, rank, csr, E, x,
                                                           W1h, W1l, dinv, A1, n);
    // gather1 + GEMM2 fused -> A2 (rank is dead from here) ; gather2 -> out
    gather_gemm_kernel<<<(n + 31) / 32, 512, 0, stream>>>(csr, ptr, dinv, (const unsigned*)A1,
                                                          b1, pf, W2bf, A2, n);
    gather_kernel<<<nb_g, 256, 0, stream>>>(csr, ptr, dinv, (const unsigned*)A2, b2, pl, out, n);
  } else {
    // fallback: fp32 VALU gemm, atomic fill (ptr becomes row_end), legacy gathers
    fused_fill_gemm_kernel<<<FUSED_GRID, 256, 0, stream>>>(src, dst, ptr, csr, E, x, W1, dinv, A1, n);
    gather_kernel_old<<<nb_g, 256, 0, stream>>>(csr, ptr, dinv, (const unsigned*)A1, b1, pf, out, n);
    gemm128_kernel<<<1024, 256, 0, stream>>>(out, W2, dinv, A1, n);
    gather_kernel_old<<<nb_g, 256, 0, stream>>>(csr, ptr, dinv, (const unsigned*)A1, b2, pl, out, n);
  }
}

// Round 7
// 525.037 us; speedup vs baseline: 1.1118x; 1.0012x over previous
//
#include <hip/hip_runtime.h>
#include <math.h>

#define D 128
#define WS_PAD 132  // 128+4: breaks stride-128 bank pattern, keeps 16B align

typedef short bf16x8 __attribute__((ext_vector_type(8)));  // 8 bf16 in 4 VGPRs
typedef float f32x4 __attribute__((ext_vector_type(4)));

__device__ __forceinline__ unsigned short f2bf(float f) {
  unsigned u = __float_as_uint(f);
  u += 0x7FFFu + ((u >> 16) & 1u);  // round-to-nearest-even
  return (unsigned short)(u >> 16);
}

__device__ __forceinline__ float bf2f(unsigned short h) {
  return __uint_as_float(((unsigned)h) << 16);
}

// ---------------- degree count + edge rank (+ fused weight-table prep) ----------------
// rank[e] = position of edge e within its dst row = atomicAdd return value.
// Saving it makes the CSR fill atomic-free (R3 win: fill kernel 135us -> off top-5).

__global__ __launch_bounds__(256) void count_deg_kernel(const int* __restrict__ dst, int E,
                                                        int* __restrict__ deg,
                                                        int* __restrict__ rank,
                                                        const float* __restrict__ W2,
                                                        unsigned short* __restrict__ W2bf,
                                                        const float* __restrict__ W1,
                                                        unsigned short* __restrict__ W1h,
                                                        unsigned short* __restrict__ W1l) {
  int nbe = (E + 1023) >> 10;  // 4 edges per thread
  int b = blockIdx.x;
  if (b >= nbe) {
    if (W2bf == nullptr) return;
    int which = b - nbe;  // 0..15
    if (which < 8) {
      // convert W2 (128x128 fp32) -> bf16 once
      int t = which * 256 + threadIdx.x;  // 0..2047
      #pragma unroll
      for (int q = 0; q < 2; ++q) {
        int idx = t + q * 2048;  // float4 index, 0..4095
        float4 w = ((const float4*)W2)[idx];
        ushort4 o;
        o.x = f2bf(w.x); o.y = f2bf(w.y); o.z = f2bf(w.z); o.w = f2bf(w.w);
        ((ushort4*)W2bf)[idx] = o;
      }
    } else {
      // split W1 -> bf16 hi + lo (residual) for bf16x3 fp32-accurate MFMA
      int t = (which - 8) * 256 + threadIdx.x;  // 0..2047
      #pragma unroll
      for (int q = 0; q < 2; ++q) {
        int idx = t + q * 2048;
        float4 w = ((const float4*)W1)[idx];
        ushort4 hi, lo;
        hi.x = f2bf(w.x); lo.x = f2bf(w.x - bf2f(hi.x));
        hi.y = f2bf(w.y); lo.y = f2bf(w.y - bf2f(hi.y));
        hi.z = f2bf(w.z); lo.z = f2bf(w.z - bf2f(hi.z));
        hi.w = f2bf(w.w); lo.w = f2bf(w.w - bf2f(hi.w));
        ((ushort4*)W1h)[idx] = hi;
        ((ushort4*)W1l)[idx] = lo;
      }
    }
    return;
  }
  int e0 = (b * 256 + threadIdx.x) * 4;
  if (rank != nullptr) {
    if (e0 + 4 <= E && ((E & 3) == 0)) {  // dst = ei+E is int4-aligned when E%4==0
      int4 d = *(const int4*)(dst + e0);
      int r0 = atomicAdd(&deg[d.x], 1);
      int r1 = atomicAdd(&deg[d.y], 1);
      int r2 = atomicAdd(&deg[d.z], 1);
      int r3 = atomicAdd(&deg[d.w], 1);
      *(int4*)(rank + e0) = make_int4(r0, r1, r2, r3);
    } else {
      for (int e = e0; e < E && e < e0 + 4; ++e) rank[e] = atomicAdd(&deg[dst[e]], 1);
    }
  } else {
    for (int e = e0; e < E && e < e0 + 4; ++e) atomicAdd(&deg[dst[e]], 1);
  }
}

// ---------------- exclusive prefix scan of deg -> ptr ----------------

__global__ __launch_bounds__(256) void scan_blocksum_kernel(const int* __restrict__ deg, int n,
                                                            int* __restrict__ blockSums) {
  __shared__ int sm[256];
  int t = threadIdx.x;
  int i = blockIdx.x * 256 + t;
  sm[t] = (i < n) ? deg[i] : 0;
  __syncthreads();
  for (int off = 128; off > 0; off >>= 1) {
    if (t < off) sm[t] += sm[t + off];
    __syncthreads();
  }
  if (t == 0) blockSums[blockIdx.x] = sm[0];
}

// single block, 512 threads; nb <= 512
__global__ __launch_bounds__(512) void scan_top_kernel(int* __restrict__ blockSums, int nb) {
  __shared__ int sm[512];
  int t = threadIdx.x;
  int v = (t < nb) ? blockSums[t] : 0;
  sm[t] = v;
  __syncthreads();
  for (int off = 1; off < 512; off <<= 1) {
    int x = (t >= off) ? sm[t - off] : 0;
    __syncthreads();
    sm[t] += x;
    __syncthreads();
  }
  if (t < nb) blockSums[t] = sm[t] - v;  // exclusive
}

// also computes dinv, and writes ptr[n] = E (ptr stays an immutable start-offset array)
__global__ __launch_bounds__(256) void scan_write_kernel(const int* __restrict__ deg, int n,
                                                         const int* __restrict__ blockSums,
                                                         int* __restrict__ ptr,
                                                         float* __restrict__ dinv) {
  __shared__ int sm[256];
  int t = threadIdx.x;
  int i = blockIdx.x * 256 + t;
  int v = (i < n) ? deg[i] : 0;
  sm[t] = v;
  __syncthreads();
  for (int off = 1; off < 256; off <<= 1) {
    int x = (t >= off) ? sm[t - off] : 0;
    __syncthreads();
    sm[t] += x;
    __syncthreads();
  }
  if (i < n) {
    int ex = blockSums[blockIdx.x] + sm[t] - v;
    ptr[i] = ex;                             // exclusive prefix (row start)
    dinv[i] = 1.0f / sqrtf((float)(v + 1));  // +1: self-loop
    if (i == n - 1) ptr[n] = ex + v;         // = E
  }
}

// ---------------- legacy fp32 VALU GEMM body (fallback path only) ----------------

__device__ __forceinline__ void gemm_body(const float* __restrict__ X,
                                          const float* __restrict__ W,
                                          const float* __restrict__ dinv,
                                          unsigned short* __restrict__ H, int n,
                                          int bid, int nblocks,
                                          float* __restrict__ Ws, float* __restrict__ Xs) {
  const int tid = threadIdx.x;
  const int tx = tid & 31;
  const int ty = tid >> 5;
  const int ntiles = (n + 31) >> 5;

  for (int tile = bid; tile < ntiles; tile += nblocks) {
    const int row0 = tile << 5;
    const int rows_here = min(32, n - row0);
    __syncthreads();
    {
      const float4* Xg = (const float4*)(X + (size_t)row0 * D);
      int tmax = rows_here * 32;
      for (int t = tid; t < tmax; t += 256) ((float4*)Xs)[t] = Xg[t];
    }
    float acc[4][4] = {{0.f}};
    #pragma unroll
    for (int kt = 0; kt < 128; kt += 64) {
      __syncthreads();
      for (int t = tid; t < 2048; t += 256) {
        int j  = t >> 4;
        int k4 = (t & 15) << 2;
        float4 w = ((const float4*)W)[j * 32 + (kt >> 2) + (t & 15)];
        Ws[(k4 + 0) * WS_PAD + j] = w.x;
        Ws[(k4 + 1) * WS_PAD + j] = w.y;
        Ws[(k4 + 2) * WS_PAD + j] = w.z;
        Ws[(k4 + 3) * WS_PAD + j] = w.w;
      }
      __syncthreads();
      #pragma unroll 4
      for (int k = 0; k < 64; ++k) {
        float4 w = *(const float4*)&Ws[k * WS_PAD + (tx << 2)];
        #pragma unroll
        for (int r = 0; r < 4; ++r) {
          float xv = Xs[(ty + 8 * r) * 128 + (kt + k)];
          acc[r][0] += xv * w.x;
          acc[r][1] += xv * w.y;
          acc[r][2] += xv * w.z;
          acc[r][3] += xv * w.w;
        }
      }
    }
    #pragma unroll
    for (int r = 0; r < 4; ++r) {
      int row = row0 + ty + 8 * r;
      if (row < n) {
        float s = dinv[row];
        unsigned h0 = f2bf(s * acc[r][0]);
        unsigned h1 = f2bf(s * acc[r][1]);
        unsigned h2 = f2bf(s * acc[r][2]);
        unsigned h3 = f2bf(s * acc[r][3]);
        ((uint2*)(H + (size_t)row * D))[tx] = make_uint2(h0 | (h1 << 16), h2 | (h3 << 16));
      }
    }
  }
}

// ---------------- legacy fused fill+GEMM (fallback path only; atomic fill) ----------------

__global__ __launch_bounds__(256) void fused_fill_gemm_kernel(
    const int* __restrict__ src, const int* __restrict__ dst,
    int* __restrict__ ptr, int* __restrict__ csr, int E,
    const float* __restrict__ X, const float* __restrict__ W,
    const float* __restrict__ dinv, unsigned short* __restrict__ H, int n) {
  __shared__ float Ws[64 * WS_PAD];
  __shared__ float Xs[32 * 128];
  int sub = blockIdx.x & 7;
  if (sub < 2) {
    int fb = (blockIdx.x >> 3) * 2 + sub;
    int stride = 512 * 256;
    for (int e = fb * 256 + threadIdx.x; e < E; e += stride) {
      int d = dst[e];
      int pos = atomicAdd(&ptr[d], 1);
      csr[pos] = src[e];
    }
  } else {
    int gb = (blockIdx.x >> 3) * 6 + (sub - 2);
    gemm_body(X, W, dinv, H, n, gb, 1536, Ws, Xs);
  }
}

__global__ __launch_bounds__(256) void gemm128_kernel(const float* __restrict__ X,
                                                      const float* __restrict__ W,
                                                      const float* __restrict__ dinv,
                                                      unsigned short* __restrict__ H, int n) {
  __shared__ float Ws[64 * WS_PAD];
  __shared__ float Xs[32 * 128];
  gemm_body(X, W, dinv, H, n, blockIdx.x, gridDim.x, Ws, Xs);
}

// ---------------- fused: atomic-free CSR fill || GEMM1 via MFMA bf16x3 ----------------

#define FUSED_GRID 2048
#define G1_PITCH 136

__global__ __launch_bounds__(256) void fused_fill_mfma_kernel(
    const int* __restrict__ src, const int* __restrict__ dst,
    const int* __restrict__ ptr, const int* __restrict__ rank,
    int* __restrict__ csr, int E,
    const float* __restrict__ X,
    const unsigned short* __restrict__ W1h, const unsigned short* __restrict__ W1l,
    const float* __restrict__ dinv, unsigned short* __restrict__ H, int n) {
  __shared__ unsigned short Ths[32 * G1_PITCH];  // 8.7 KB
  __shared__ unsigned short Tls[32 * G1_PITCH];  // 8.7 KB
  int sub = blockIdx.x & 7;
  if (sub < 2) {
    // atomic-free CSR fill, 512 blocks, 8 edges per thread
    int fb = (blockIdx.x >> 3) * 2 + sub;
    const int T8 = 512 * 256 * 8;
    int t = fb * 256 + threadIdx.x;
    const bool al16 = ((E & 3) == 0);
    for (int e0 = t * 8; e0 < E; e0 += T8) {
      if (e0 + 8 <= E && al16) {
        int4 d0 = ((const int4*)(dst + e0))[0];
        int4 d1 = ((const int4*)(dst + e0))[1];
        int4 s0 = ((const int4*)(src + e0))[0];
        int4 s1 = ((const int4*)(src + e0))[1];
        int4 r0 = ((const int4*)(rank + e0))[0];
        int4 r1 = ((const int4*)(rank + e0))[1];
        int p0 = ptr[d0.x] + r0.x;
        int p1 = ptr[d0.y] + r0.y;
        int p2 = ptr[d0.z] + r0.z;
        int p3 = ptr[d0.w] + r0.w;
        int p4 = ptr[d1.x] + r1.x;
        int p5 = ptr[d1.y] + r1.y;
        int p6 = ptr[d1.z] + r1.z;
        int p7 = ptr[d1.w] + r1.w;
        csr[p0] = s0.x; csr[p1] = s0.y; csr[p2] = s0.z; csr[p3] = s0.w;
        csr[p4] = s1.x; csr[p5] = s1.y; csr[p6] = s1.z; csr[p7] = s1.w;
      } else {
        for (int e = e0; e < E && e < e0 + 8; ++e)
          csr[ptr[dst[e]] + rank[e]] = src[e];
      }
    }
  } else {
    // GEMM1: 1536 blocks, 32 rows per tile, grid-strided
    int gb = (blockIdx.x >> 3) * 6 + (sub - 2);
    const int tid = threadIdx.x;
    const int wv = tid >> 6;       // 0..3
    const int lane = tid & 63;
    const int m = lane & 15;
    const int quad = lane >> 4;    // 0..3
    const int mt = wv >> 1;        // 0..1  (16-row m-tile)
    const int ntb = (wv & 1) * 4;  // n-tile base: 4 consecutive 16-col tiles
    const int ntiles = (n + 31) >> 5;

    for (int tile = gb; tile < ntiles; tile += 1536) {
      const int row0 = tile << 5;
      const int rows_here = min(32, n - row0);
      __syncthreads();  // protect LDS from previous iteration's readers
      {
        const float4* Xg = (const float4*)(X + (size_t)row0 * D);
        int tmax = rows_here * 32;
        for (int t = tid; t < tmax; t += 256) {
          float4 xv = Xg[t];
          int r = t >> 5, c4 = (t & 31) << 2;
          ushort4 hi, lo;
          hi.x = f2bf(xv.x); lo.x = f2bf(xv.x - bf2f(hi.x));
          hi.y = f2bf(xv.y); lo.y = f2bf(xv.y - bf2f(hi.y));
          hi.z = f2bf(xv.z); lo.z = f2bf(xv.z - bf2f(hi.z));
          hi.w = f2bf(xv.w); lo.w = f2bf(xv.w - bf2f(hi.w));
          *(ushort4*)&Ths[r * G1_PITCH + c4] = hi;
          *(ushort4*)&Tls[r * G1_PITCH + c4] = lo;
        }
      }
      __syncthreads();

      f32x4 acc0 = {0.f, 0.f, 0.f, 0.f};
      f32x4 acc1 = {0.f, 0.f, 0.f, 0.f};
      f32x4 acc2 = {0.f, 0.f, 0.f, 0.f};
      f32x4 acc3 = {0.f, 0.f, 0.f, 0.f};
      #pragma unroll
      for (int s = 0; s < 4; ++s) {
        int k = (s << 5) + (quad << 3);
        bf16x8 ah = *(const bf16x8*)&Ths[(mt * 16 + m) * G1_PITCH + k];
        bf16x8 al = *(const bf16x8*)&Tls[(mt * 16 + m) * G1_PITCH + k];
        bf16x8 bh0 = *(const bf16x8*)&W1h[(size_t)((ntb + 0) * 16 + m) * 128 + k];
        bf16x8 bl0 = *(const bf16x8*)&W1l[(size_t)((ntb + 0) * 16 + m) * 128 + k];
        acc0 = __builtin_amdgcn_mfma_f32_16x16x32_bf16(ah, bh0, acc0, 0, 0, 0);
        acc0 = __builtin_amdgcn_mfma_f32_16x16x32_bf16(al, bh0, acc0, 0, 0, 0);
        acc0 = __builtin_amdgcn_mfma_f32_16x16x32_bf16(ah, bl0, acc0, 0, 0, 0);
        bf16x8 bh1 = *(const bf16x8*)&W1h[(size_t)((ntb + 1) * 16 + m) * 128 + k];
        bf16x8 bl1 = *(const bf16x8*)&W1l[(size_t)((ntb + 1) * 16 + m) * 128 + k];
        acc1 = __builtin_amdgcn_mfma_f32_16x16x32_bf16(ah, bh1, acc1, 0, 0, 0);
        acc1 = __builtin_amdgcn_mfma_f32_16x16x32_bf16(al, bh1, acc1, 0, 0, 0);
        acc1 = __builtin_amdgcn_mfma_f32_16x16x32_bf16(ah, bl1, acc1, 0, 0, 0);
        bf16x8 bh2 = *(const bf16x8*)&W1h[(size_t)((ntb + 2) * 16 + m) * 128 + k];
        bf16x8 bl2 = *(const bf16x8*)&W1l[(size_t)((ntb + 2) * 16 + m) * 128 + k];
        acc2 = __builtin_amdgcn_mfma_f32_16x16x32_bf16(ah, bh2, acc2, 0, 0, 0);
        acc2 = __builtin_amdgcn_mfma_f32_16x16x32_bf16(al, bh2, acc2, 0, 0, 0);
        acc2 = __builtin_amdgcn_mfma_f32_16x16x32_bf16(ah, bl2, acc2, 0, 0, 0);
        bf16x8 bh3 = *(const bf16x8*)&W1h[(size_t)((ntb + 3) * 16 + m) * 128 + k];
        bf16x8 bl3 = *(const bf16x8*)&W1l[(size_t)((ntb + 3) * 16 + m) * 128 + k];
        acc3 = __builtin_amdgcn_mfma_f32_16x16x32_bf16(ah, bh3, acc3, 0, 0, 0);
        acc3 = __builtin_amdgcn_mfma_f32_16x16x32_bf16(al, bh3, acc3, 0, 0, 0);
        acc3 = __builtin_amdgcn_mfma_f32_16x16x32_bf16(ah, bl3, acc3, 0, 0, 0);
      }
      // C/D layout: col = lane&15 (m), row = quad*4 + r
      #pragma unroll
      for (int r = 0; r < 4; ++r) {
        int row = mt * 16 + (quad << 2) + r;
        int g = row0 + row;
        if (g < n) {
          float sc = dinv[g];
          H[(size_t)g * D + (ntb + 0) * 16 + m] = f2bf(sc * acc0[r]);
          H[(size_t)g * D + (ntb + 1) * 16 + m] = f2bf(sc * acc1[r]);
          H[(size_t)g * D + (ntb + 2) * 16 + m] = f2bf(sc * acc2[r]);
          H[(size_t)g * D + (ntb + 3) * 16 + m] = f2bf(sc * acc3[r]);
        }
      }
    }
  }
}

// ---------------- gather helper: accumulate row i of Hs (bf16), explicit bounds ----------------
// Software-pipelined 2 batches deep: issue batch k+1's 8 loads BEFORE summing batch k.
// Doubles per-wave loads-in-flight (8 -> 16); for the typical degree-16 row both
// batches issue back-to-back and only one L2-miss latency is exposed instead of two.

__device__ __forceinline__ void gather_row(const int* __restrict__ csr, int start, int end,
                                           const unsigned* __restrict__ Hu,
                                           int i, int lane, float& ax, float& ay) {
  unsigned v = Hu[(size_t)i * 64 + lane];  // self-loop term
  ax = __uint_as_float(v << 16);
  ay = __uint_as_float(v & 0xFFFF0000u);
  int e = start;
  int nb = (end - start) >> 3;  // full batches of 8
  if (nb > 0) {
    unsigned wa[8], wb[8];
    #pragma unroll
    for (int k = 0; k < 8; ++k) wa[k] = Hu[(size_t)csr[e + k] * 64 + lane];
    e += 8;
    for (int b = 1; b < nb; ++b) {
      #pragma unroll
      for (int k = 0; k < 8; ++k) wb[k] = Hu[(size_t)csr[e + k] * 64 + lane];
      e += 8;
      #pragma unroll
      for (int k = 0; k < 8; ++k) {
        ax += __uint_as_float(wa[k] << 16);
        ay += __uint_as_float(wa[k] & 0xFFFF0000u);
      }
      #pragma unroll
      for (int k = 0; k < 8; ++k) wa[k] = wb[k];
    }
    #pragma unroll
    for (int k = 0; k < 8; ++k) {
      ax += __uint_as_float(wa[k] << 16);
      ay += __uint_as_float(wa[k] & 0xFFFF0000u);
    }
  }
  for (; e < end; ++e) {
    unsigned w = Hu[(size_t)csr[e] * 64 + lane];
    ax += __uint_as_float(w << 16);
    ay += __uint_as_float(w & 0xFFFF0000u);
  }
}

// ---------------- standalone gather: new semantics (rptr[i], rptr[i+1]) ----------------

__global__ __launch_bounds__(256, 8) void gather_kernel(const int* __restrict__ csr,
                                                        const int* __restrict__ rptr,
                                                        const float* __restrict__ dinv,
                                                        const unsigned* __restrict__ Hu,
                                                        const float* __restrict__ bias,
                                                        const float* __restrict__ perturb,
                                                        float* __restrict__ out, int n) {
  int i = (blockIdx.x << 2) + (threadIdx.x >> 6);
  if (i >= n) return;
  int lane = threadIdx.x & 63;
  float ax, ay;
  gather_row(csr, rptr[i], rptr[i + 1], Hu, i, lane, ax, ay);
  float di = dinv[i];
  float2 p = ((const float2*)(perturb + (size_t)i * D))[lane];
  float2 o;
  o.x = bias[2 * lane + 0] + p.x + di * ax;
  o.y = bias[2 * lane + 1] + p.y + di * ay;
  ((float2*)(out + (size_t)i * D))[lane] = o;
}

// legacy semantics (rend[i-1], rend[i]) for the atomic-fill fallback path
__global__ __launch_bounds__(256, 8) void gather_kernel_old(const int* __restrict__ csr,
                                                            const int* __restrict__ rend,
                                                            const float* __restrict__ dinv,
                                                            const unsigned* __restrict__ Hu,
                                                            const float* __restrict__ bias,
                                                            const float* __restrict__ perturb,
                                                            float* __restrict__ out, int n) {
  int i = (blockIdx.x << 2) + (threadIdx.x >> 6);
  if (i >= n) return;
  int lane = threadIdx.x & 63;
  int start = (i == 0) ? 0 : rend[i - 1];
  float ax, ay;
  gather_row(csr, start, rend[i], Hu, i, lane, ax, ay);
  float di = dinv[i];
  float2 p = ((const float2*)(perturb + (size_t)i * D))[lane];
  float2 o;
  o.x = bias[2 * lane + 0] + p.x + di * ax;
  o.y = bias[2 * lane + 1] + p.y + di * ay;
  ((float2*)(out + (size_t)i * D))[lane] = o;
}

// ---------------- fused gather1 + GEMM2 (MFMA bf16) ----------------

#define GG_PITCH 136

__global__ __launch_bounds__(512, 8) void gather_gemm_kernel(
    const int* __restrict__ csr, const int* __restrict__ rptr,
    const float* __restrict__ dinv, const unsigned* __restrict__ Hu,
    const float* __restrict__ bias, const float* __restrict__ perturb,
    const unsigned short* __restrict__ W2bf, unsigned short* __restrict__ H2, int n) {
  __shared__ unsigned short Ts[32 * GG_PITCH];  // 8.5 KB
  const int tid = threadIdx.x;
  const int wv = tid >> 6;
  const int lane = tid & 63;
  const int base = blockIdx.x << 5;  // 32 nodes per block

  // phase 1: gather 4 nodes per wave -> Ts
  #pragma unroll
  for (int j = 0; j < 4; ++j) {
    int row = (wv << 2) + j;
    int i = base + row;
    if (i < n) {
      float ax, ay;
      gather_row(csr, rptr[i], rptr[i + 1], Hu, i, lane, ax, ay);
      float di = dinv[i];
      float2 p = ((const float2*)(perturb + (size_t)i * D))[lane];
      float ox = bias[2 * lane + 0] + p.x + di * ax;
      float oy = bias[2 * lane + 1] + p.y + di * ay;
      unsigned pack = (unsigned)f2bf(ox) | ((unsigned)f2bf(oy) << 16);
      *(unsigned*)&Ts[row * GG_PITCH + (lane << 1)] = pack;
    }
  }
  __syncthreads();

  // phase 2: R[32][128] = Ts @ W2bf^T ; wave wv: m-tile = wv>>2, n-tiles {wv&3, (wv&3)+4}
  const int mt = wv >> 2;
  const int nt0 = wv & 3;
  const int m = lane & 15;
  const int quad = lane >> 4;  // 0..3
  const unsigned short* Wrow0 = W2bf + (size_t)(nt0 * 16 + m) * 128;
  const unsigned short* Wrow1 = W2bf + (size_t)((nt0 + 4) * 16 + m) * 128;
  f32x4 acc0 = {0.f, 0.f, 0.f, 0.f};
  f32x4 acc1 = {0.f, 0.f, 0.f, 0.f};
  #pragma unroll
  for (int s = 0; s < 4; ++s) {
    int k = (s << 5) + (quad << 3);
    bf16x8 a  = *(const bf16x8*)&Ts[(mt * 16 + m) * GG_PITCH + k];
    bf16x8 b0 = *(const bf16x8*)&Wrow0[k];
    bf16x8 b1 = *(const bf16x8*)&Wrow1[k];
    acc0 = __builtin_amdgcn_mfma_f32_16x16x32_bf16(a, b0, acc0, 0, 0, 0);
    acc1 = __builtin_amdgcn_mfma_f32_16x16x32_bf16(a, b1, acc1, 0, 0, 0);
  }
  // C/D layout: col = lane&15, row = quad*4 + reg
  #pragma unroll
  for (int r = 0; r < 4; ++r) {
    int row = mt * 16 + (quad << 2) + r;
    int g = base + row;
    if (g < n) {
      float s = dinv[g];
      H2[(size_t)g * D + nt0 * 16 + m]       = f2bf(s * acc0[r]);
      H2[(size_t)g * D + (nt0 + 4) * 16 + m] = f2bf(s * acc1[r]);
    }
  }
}

// ---------------- launch ----------------

extern "C" void kernel_launch(void* const* d_in, const int* in_sizes, int n_in,
                              void* d_out, int out_size, void* d_ws, size_t ws_size,
                              hipStream_t stream) {
  const float* x  = (const float*)d_in[0];
  const int*   ei = (const int*)d_in[1];
  const float* pf = (const float*)d_in[2];
  const float* pl = (const float*)d_in[3];
  const float* W1 = (const float*)d_in[4];
  const float* b1 = (const float*)d_in[5];
  const float* W2 = (const float*)d_in[6];
  const float* b2 = (const float*)d_in[7];
  float* out = (float*)d_out;

  const int n = in_sizes[0] / D;
  const int E = in_sizes[1] / 2;
  const int* src = ei;      // edge_index[0]
  const int* dst = ei + E;  // edge_index[1]

  // workspace layout
  int*   deg       = (int*)d_ws;                     // [n]
  float* dinv      = (float*)d_ws + n;               // [n]
  int*   ptr       = (int*)d_ws + 2 * n;             // [n+1] (start offsets; immutable in fused path)
  int*   blockSums = (int*)d_ws + 3 * n + 1;         // [<=512]
  int*   csr       = (int*)d_ws + 3 * n + 1 + 512;   // [E]
  size_t a1_off = ((size_t)(3 * n + 1 + 512 + E) * 4 + 255) & ~(size_t)255;
  unsigned short* A1 = (unsigned short*)((char*)d_ws + a1_off);
  unsigned short* A2 = A1 + (size_t)n * D;
  unsigned short* W2bf = A2 + (size_t)n * D;     // [128*128] bf16, 32 KB
  unsigned short* W1h  = W2bf + 128 * 128;       // [128*128] bf16, 32 KB
  unsigned short* W1l  = W1h + 128 * 128;        // [128*128] bf16, 32 KB
  int* rank = (int*)A2;                          // [E] aliases A2 (dead until gather_gemm)
  size_t needed = a1_off + (2 * (size_t)n * D + 3 * 128 * 128) * sizeof(unsigned short);
  const bool fused_l2 = (ws_size >= needed);  // constant across calls -> capture-safe

  const int nb_n = (n + 255) / 256;
  const int nb_e4 = (E + 1023) / 1024;
  const int nb_g = (n + 3) / 4;

  hipMemsetAsync(deg, 0, (size_t)n * sizeof(int), stream);
  count_deg_kernel<<<nb_e4 + 16, 256, 0, stream>>>(
      dst, E, deg, fused_l2 ? rank : (int*)nullptr, W2,
      fused_l2 ? W2bf : (unsigned short*)nullptr, W1, W1h, W1l);
  scan_blocksum_kernel<<<nb_n, 256, 0, stream>>>(deg, n, blockSums);
  scan_top_kernel<<<1, 512, 0, stream>>>(blockSums, nb_n);
  scan_write_kernel<<<nb_n, 256, 0, stream>>>(deg, n, blockSums, ptr, dinv);

  if (fused_l2) {
    // layer 1: atomic-free CSR fill || Hs1 = dinv*(x@W1^T) via MFMA bf16x3 -> A1
    fused_fill_mfma_kernel<<<FUSED_GRID, 256, 0, stream>>>(src, dst, ptr, rank, csr, E, x,
                                                           W1h, W1l, dinv, A1, n);
    // gather1 + GEMM2 fused -> A2 (rank is dead from here) ; gather2 -> out
    gather_gemm_kernel<<<(n + 31) / 32, 512, 0, stream>>>(csr, ptr, dinv, (const unsigned*)A1,
                                                          b1, pf, W2bf, A2, n);
    gather_kernel<<<nb_g, 256, 0, stream>>>(csr, ptr, dinv, (const unsigned*)A2, b2, pl, out, n);
  } else {
    // fallback: fp32 VALU gemm, atomic fill (ptr becomes row_end), legacy gathers
    fused_fill_gemm_kernel<<<FUSED_GRID, 256, 0, stream>>>(src, dst, ptr, csr, E, x, W1, dinv, A1, n);
    gather_kernel_old<<<nb_g, 256, 0, stream>>>(csr, ptr, dinv, (const unsigned*)A1, b1, pf, out, n);
    gemm128_kernel<<<1024, 256, 0, stream>>>(out, W2, dinv, A1, n);
    gather_kernel_old<<<nb_g, 256, 0, stream>>>(csr, ptr, dinv, (const unsigned*)A1, b2, pl, out, n);
  }
}

// Round 9
// 490.477 us; speedup vs baseline: 1.1901x; 1.0705x over previous
//
#include <hip/hip_runtime.h>
#include <math.h>

#define D 128
#define WS_PAD 132  // 128+4: breaks stride-128 bank pattern, keeps 16B align

typedef short bf16x8 __attribute__((ext_vector_type(8)));  // 8 bf16 in 4 VGPRs
typedef float f32x4 __attribute__((ext_vector_type(4)));

__device__ __forceinline__ unsigned short f2bf(float f) {
  unsigned u = __float_as_uint(f);
  u += 0x7FFFu + ((u >> 16) & 1u);  // round-to-nearest-even
  return (unsigned short)(u >> 16);
}

__device__ __forceinline__ float bf2f(unsigned short h) {
  return __uint_as_float(((unsigned)h) << 16);
}

__device__ __forceinline__ float bflo(unsigned u) { return __uint_as_float(u << 16); }
__device__ __forceinline__ float bfhi(unsigned u) { return __uint_as_float(u & 0xFFFF0000u); }

// ---------------- degree count + edge rank (+ fused weight-table prep) ----------------
// rank[e] = position of edge e within its dst row = atomicAdd return value.
// Saving it makes the CSR fill atomic-free (R3 win: fill kernel 135us -> off top-5).

__global__ __launch_bounds__(256) void count_deg_kernel(const int* __restrict__ dst, int E,
                                                        int* __restrict__ deg,
                                                        int* __restrict__ rank,
                                                        const float* __restrict__ W2,
                                                        unsigned short* __restrict__ W2bf,
                                                        const float* __restrict__ W1,
                                                        unsigned short* __restrict__ W1h,
                                                        unsigned short* __restrict__ W1l) {
  int nbe = (E + 1023) >> 10;  // 4 edges per thread
  int b = blockIdx.x;
  if (b >= nbe) {
    if (W2bf == nullptr) return;
    int which = b - nbe;  // 0..15
    if (which < 8) {
      // convert W2 (128x128 fp32) -> bf16 once
      int t = which * 256 + threadIdx.x;  // 0..2047
      #pragma unroll
      for (int q = 0; q < 2; ++q) {
        int idx = t + q * 2048;  // float4 index, 0..4095
        float4 w = ((const float4*)W2)[idx];
        ushort4 o;
        o.x = f2bf(w.x); o.y = f2bf(w.y); o.z = f2bf(w.z); o.w = f2bf(w.w);
        ((ushort4*)W2bf)[idx] = o;
      }
    } else {
      // split W1 -> bf16 hi + lo (residual) for bf16x3 fp32-accurate MFMA
      int t = (which - 8) * 256 + threadIdx.x;  // 0..2047
      #pragma unroll
      for (int q = 0; q < 2; ++q) {
        int idx = t + q * 2048;
        float4 w = ((const float4*)W1)[idx];
        ushort4 hi, lo;
        hi.x = f2bf(w.x); lo.x = f2bf(w.x - bf2f(hi.x));
        hi.y = f2bf(w.y); lo.y = f2bf(w.y - bf2f(hi.y));
        hi.z = f2bf(w.z); lo.z = f2bf(w.z - bf2f(hi.z));
        hi.w = f2bf(w.w); lo.w = f2bf(w.w - bf2f(hi.w));
        ((ushort4*)W1h)[idx] = hi;
        ((ushort4*)W1l)[idx] = lo;
      }
    }
    return;
  }
  int e0 = (b * 256 + threadIdx.x) * 4;
  if (rank != nullptr) {
    if (e0 + 4 <= E && ((E & 3) == 0)) {  // dst = ei+E is int4-aligned when E%4==0
      int4 d = *(const int4*)(dst + e0);
      int r0 = atomicAdd(&deg[d.x], 1);
      int r1 = atomicAdd(&deg[d.y], 1);
      int r2 = atomicAdd(&deg[d.z], 1);
      int r3 = atomicAdd(&deg[d.w], 1);
      *(int4*)(rank + e0) = make_int4(r0, r1, r2, r3);
    } else {
      for (int e = e0; e < E && e < e0 + 4; ++e) rank[e] = atomicAdd(&deg[dst[e]], 1);
    }
  } else {
    for (int e = e0; e < E && e < e0 + 4; ++e) atomicAdd(&deg[dst[e]], 1);
  }
}

// ---------------- exclusive prefix scan of deg -> ptr ----------------

__global__ __launch_bounds__(256) void scan_blocksum_kernel(const int* __restrict__ deg, int n,
                                                            int* __restrict__ blockSums) {
  __shared__ int sm[256];
  int t = threadIdx.x;
  int i = blockIdx.x * 256 + t;
  sm[t] = (i < n) ? deg[i] : 0;
  __syncthreads();
  for (int off = 128; off > 0; off >>= 1) {
    if (t < off) sm[t] += sm[t + off];
    __syncthreads();
  }
  if (t == 0) blockSums[blockIdx.x] = sm[0];
}

// single block, 512 threads; nb <= 512
__global__ __launch_bounds__(512) void scan_top_kernel(int* __restrict__ blockSums, int nb) {
  __shared__ int sm[512];
  int t = threadIdx.x;
  int v = (t < nb) ? blockSums[t] : 0;
  sm[t] = v;
  __syncthreads();
  for (int off = 1; off < 512; off <<= 1) {
    int x = (t >= off) ? sm[t - off] : 0;
    __syncthreads();
    sm[t] += x;
    __syncthreads();
  }
  if (t < nb) blockSums[t] = sm[t] - v;  // exclusive
}

// also computes dinv, and writes ptr[n] = E (ptr stays an immutable start-offset array)
__global__ __launch_bounds__(256) void scan_write_kernel(const int* __restrict__ deg, int n,
                                                         const int* __restrict__ blockSums,
                                                         int* __restrict__ ptr,
                                                         float* __restrict__ dinv) {
  __shared__ int sm[256];
  int t = threadIdx.x;
  int i = blockIdx.x * 256 + t;
  int v = (i < n) ? deg[i] : 0;
  sm[t] = v;
  __syncthreads();
  for (int off = 1; off < 256; off <<= 1) {
    int x = (t >= off) ? sm[t - off] : 0;
    __syncthreads();
    sm[t] += x;
    __syncthreads();
  }
  if (i < n) {
    int ex = blockSums[blockIdx.x] + sm[t] - v;
    ptr[i] = ex;                             // exclusive prefix (row start)
    dinv[i] = 1.0f / sqrtf((float)(v + 1));  // +1: self-loop
    if (i == n - 1) ptr[n] = ex + v;         // = E
  }
}

// ---------------- legacy fp32 VALU GEMM body (fallback path only) ----------------

__device__ __forceinline__ void gemm_body(const float* __restrict__ X,
                                          const float* __restrict__ W,
                                          const float* __restrict__ dinv,
                                          unsigned short* __restrict__ H, int n,
                                          int bid, int nblocks,
                                          float* __restrict__ Ws, float* __restrict__ Xs) {
  const int tid = threadIdx.x;
  const int tx = tid & 31;
  const int ty = tid >> 5;
  const int ntiles = (n + 31) >> 5;

  for (int tile = bid; tile < ntiles; tile += nblocks) {
    const int row0 = tile << 5;
    const int rows_here = min(32, n - row0);
    __syncthreads();
    {
      const float4* Xg = (const float4*)(X + (size_t)row0 * D);
      int tmax = rows_here * 32;
      for (int t = tid; t < tmax; t += 256) ((float4*)Xs)[t] = Xg[t];
    }
    float acc[4][4] = {{0.f}};
    #pragma unroll
    for (int kt = 0; kt < 128; kt += 64) {
      __syncthreads();
      for (int t = tid; t < 2048; t += 256) {
        int j  = t >> 4;
        int k4 = (t & 15) << 2;
        float4 w = ((const float4*)W)[j * 32 + (kt >> 2) + (t & 15)];
        Ws[(k4 + 0) * WS_PAD + j] = w.x;
        Ws[(k4 + 1) * WS_PAD + j] = w.y;
        Ws[(k4 + 2) * WS_PAD + j] = w.z;
        Ws[(k4 + 3) * WS_PAD + j] = w.w;
      }
      __syncthreads();
      #pragma unroll 4
      for (int k = 0; k < 64; ++k) {
        float4 w = *(const float4*)&Ws[k * WS_PAD + (tx << 2)];
        #pragma unroll
        for (int r = 0; r < 4; ++r) {
          float xv = Xs[(ty + 8 * r) * 128 + (kt + k)];
          acc[r][0] += xv * w.x;
          acc[r][1] += xv * w.y;
          acc[r][2] += xv * w.z;
          acc[r][3] += xv * w.w;
        }
      }
    }
    #pragma unroll
    for (int r = 0; r < 4; ++r) {
      int row = row0 + ty + 8 * r;
      if (row < n) {
        float s = dinv[row];
        unsigned h0 = f2bf(s * acc[r][0]);
        unsigned h1 = f2bf(s * acc[r][1]);
        unsigned h2 = f2bf(s * acc[r][2]);
        unsigned h3 = f2bf(s * acc[r][3]);
        ((uint2*)(H + (size_t)row * D))[tx] = make_uint2(h0 | (h1 << 16), h2 | (h3 << 16));
      }
    }
  }
}

// ---------------- legacy fused fill+GEMM (fallback path only; atomic fill) ----------------

__global__ __launch_bounds__(256) void fused_fill_gemm_kernel(
    const int* __restrict__ src, const int* __restrict__ dst,
    int* __restrict__ ptr, int* __restrict__ csr, int E,
    const float* __restrict__ X, const float* __restrict__ W,
    const float* __restrict__ dinv, unsigned short* __restrict__ H, int n) {
  __shared__ float Ws[64 * WS_PAD];
  __shared__ float Xs[32 * 128];
  int sub = blockIdx.x & 7;
  if (sub < 2) {
    int fb = (blockIdx.x >> 3) * 2 + sub;
    int stride = 512 * 256;
    for (int e = fb * 256 + threadIdx.x; e < E; e += stride) {
      int d = dst[e];
      int pos = atomicAdd(&ptr[d], 1);
      csr[pos] = src[e];
    }
  } else {
    int gb = (blockIdx.x >> 3) * 6 + (sub - 2);
    gemm_body(X, W, dinv, H, n, gb, 1536, Ws, Xs);
  }
}

__global__ __launch_bounds__(256) void gemm128_kernel(const float* __restrict__ X,
                                                      const float* __restrict__ W,
                                                      const float* __restrict__ dinv,
                                                      unsigned short* __restrict__ H, int n) {
  __shared__ float Ws[64 * WS_PAD];
  __shared__ float Xs[32 * 128];
  gemm_body(X, W, dinv, H, n, blockIdx.x, gridDim.x, Ws, Xs);
}

// ---------------- fused: atomic-free CSR fill || GEMM1 via MFMA bf16x3 ----------------

#define FUSED_GRID 2048
#define G1_PITCH 136

__global__ __launch_bounds__(256) void fused_fill_mfma_kernel(
    const int* __restrict__ src, const int* __restrict__ dst,
    const int* __restrict__ ptr, const int* __restrict__ rank,
    int* __restrict__ csr, int E,
    const float* __restrict__ X,
    const unsigned short* __restrict__ W1h, const unsigned short* __restrict__ W1l,
    const float* __restrict__ dinv, unsigned short* __restrict__ H, int n) {
  __shared__ unsigned short Ths[32 * G1_PITCH];  // 8.7 KB
  __shared__ unsigned short Tls[32 * G1_PITCH];  // 8.7 KB
  int sub = blockIdx.x & 7;
  if (sub < 2) {
    // atomic-free CSR fill, 512 blocks, 8 edges per thread
    int fb = (blockIdx.x >> 3) * 2 + sub;
    const int T8 = 512 * 256 * 8;
    int t = fb * 256 + threadIdx.x;
    const bool al16 = ((E & 3) == 0);
    for (int e0 = t * 8; e0 < E; e0 += T8) {
      if (e0 + 8 <= E && al16) {
        int4 d0 = ((const int4*)(dst + e0))[0];
        int4 d1 = ((const int4*)(dst + e0))[1];
        int4 s0 = ((const int4*)(src + e0))[0];
        int4 s1 = ((const int4*)(src + e0))[1];
        int4 r0 = ((const int4*)(rank + e0))[0];
        int4 r1 = ((const int4*)(rank + e0))[1];
        int p0 = ptr[d0.x] + r0.x;
        int p1 = ptr[d0.y] + r0.y;
        int p2 = ptr[d0.z] + r0.z;
        int p3 = ptr[d0.w] + r0.w;
        int p4 = ptr[d1.x] + r1.x;
        int p5 = ptr[d1.y] + r1.y;
        int p6 = ptr[d1.z] + r1.z;
        int p7 = ptr[d1.w] + r1.w;
        csr[p0] = s0.x; csr[p1] = s0.y; csr[p2] = s0.z; csr[p3] = s0.w;
        csr[p4] = s1.x; csr[p5] = s1.y; csr[p6] = s1.z; csr[p7] = s1.w;
      } else {
        for (int e = e0; e < E && e < e0 + 8; ++e)
          csr[ptr[dst[e]] + rank[e]] = src[e];
      }
    }
  } else {
    // GEMM1: 1536 blocks, 32 rows per tile, grid-strided
    int gb = (blockIdx.x >> 3) * 6 + (sub - 2);
    const int tid = threadIdx.x;
    const int wv = tid >> 6;       // 0..3
    const int lane = tid & 63;
    const int m = lane & 15;
    const int quad = lane >> 4;    // 0..3
    const int mt = wv >> 1;        // 0..1  (16-row m-tile)
    const int ntb = (wv & 1) * 4;  // n-tile base: 4 consecutive 16-col tiles
    const int ntiles = (n + 31) >> 5;

    for (int tile = gb; tile < ntiles; tile += 1536) {
      const int row0 = tile << 5;
      const int rows_here = min(32, n - row0);
      __syncthreads();  // protect LDS from previous iteration's readers
      {
        const float4* Xg = (const float4*)(X + (size_t)row0 * D);
        int tmax = rows_here * 32;
        for (int t = tid; t < tmax; t += 256) {
          float4 xv = Xg[t];
          int r = t >> 5, c4 = (t & 31) << 2;
          ushort4 hi, lo;
          hi.x = f2bf(xv.x); lo.x = f2bf(xv.x - bf2f(hi.x));
          hi.y = f2bf(xv.y); lo.y = f2bf(xv.y - bf2f(hi.y));
          hi.z = f2bf(xv.z); lo.z = f2bf(xv.z - bf2f(hi.z));
          hi.w = f2bf(xv.w); lo.w = f2bf(xv.w - bf2f(hi.w));
          *(ushort4*)&Ths[r * G1_PITCH + c4] = hi;
          *(ushort4*)&Tls[r * G1_PITCH + c4] = lo;
        }
      }
      __syncthreads();

      f32x4 acc0 = {0.f, 0.f, 0.f, 0.f};
      f32x4 acc1 = {0.f, 0.f, 0.f, 0.f};
      f32x4 acc2 = {0.f, 0.f, 0.f, 0.f};
      f32x4 acc3 = {0.f, 0.f, 0.f, 0.f};
      #pragma unroll
      for (int s = 0; s < 4; ++s) {
        int k = (s << 5) + (quad << 3);
        bf16x8 ah = *(const bf16x8*)&Ths[(mt * 16 + m) * G1_PITCH + k];
        bf16x8 al = *(const bf16x8*)&Tls[(mt * 16 + m) * G1_PITCH + k];
        bf16x8 bh0 = *(const bf16x8*)&W1h[(size_t)((ntb + 0) * 16 + m) * 128 + k];
        bf16x8 bl0 = *(const bf16x8*)&W1l[(size_t)((ntb + 0) * 16 + m) * 128 + k];
        acc0 = __builtin_amdgcn_mfma_f32_16x16x32_bf16(ah, bh0, acc0, 0, 0, 0);
        acc0 = __builtin_amdgcn_mfma_f32_16x16x32_bf16(al, bh0, acc0, 0, 0, 0);
        acc0 = __builtin_amdgcn_mfma_f32_16x16x32_bf16(ah, bl0, acc0, 0, 0, 0);
        bf16x8 bh1 = *(const bf16x8*)&W1h[(size_t)((ntb + 1) * 16 + m) * 128 + k];
        bf16x8 bl1 = *(const bf16x8*)&W1l[(size_t)((ntb + 1) * 16 + m) * 128 + k];
        acc1 = __builtin_amdgcn_mfma_f32_16x16x32_bf16(ah, bh1, acc1, 0, 0, 0);
        acc1 = __builtin_amdgcn_mfma_f32_16x16x32_bf16(al, bh1, acc1, 0, 0, 0);
        acc1 = __builtin_amdgcn_mfma_f32_16x16x32_bf16(ah, bl1, acc1, 0, 0, 0);
        bf16x8 bh2 = *(const bf16x8*)&W1h[(size_t)((ntb + 2) * 16 + m) * 128 + k];
        bf16x8 bl2 = *(const bf16x8*)&W1l[(size_t)((ntb + 2) * 16 + m) * 128 + k];
        acc2 = __builtin_amdgcn_mfma_f32_16x16x32_bf16(ah, bh2, acc2, 0, 0, 0);
        acc2 = __builtin_amdgcn_mfma_f32_16x16x32_bf16(al, bh2, acc2, 0, 0, 0);
        acc2 = __builtin_amdgcn_mfma_f32_16x16x32_bf16(ah, bl2, acc2, 0, 0, 0);
        bf16x8 bh3 = *(const bf16x8*)&W1h[(size_t)((ntb + 3) * 16 + m) * 128 + k];
        bf16x8 bl3 = *(const bf16x8*)&W1l[(size_t)((ntb + 3) * 16 + m) * 128 + k];
        acc3 = __builtin_amdgcn_mfma_f32_16x16x32_bf16(ah, bh3, acc3, 0, 0, 0);
        acc3 = __builtin_amdgcn_mfma_f32_16x16x32_bf16(al, bh3, acc3, 0, 0, 0);
        acc3 = __builtin_amdgcn_mfma_f32_16x16x32_bf16(ah, bl3, acc3, 0, 0, 0);
      }
      // C/D layout: col = lane&15 (m), row = quad*4 + r
      #pragma unroll
      for (int r = 0; r < 4; ++r) {
        int row = mt * 16 + (quad << 2) + r;
        int g = row0 + row;
        if (g < n) {
          float sc = dinv[g];
          H[(size_t)g * D + (ntb + 0) * 16 + m] = f2bf(sc * acc0[r]);
          H[(size_t)g * D + (ntb + 1) * 16 + m] = f2bf(sc * acc1[r]);
          H[(size_t)g * D + (ntb + 2) * 16 + m] = f2bf(sc * acc2[r]);
          H[(size_t)g * D + (ntb + 3) * 16 + m] = f2bf(sc * acc3[r]);
        }
      }
    }
  }
}

// ---------------- NEW gather: 4 rows per wave, uint4 (16B) lanes ----------------
// Lane group g = lane>>4 owns row i0+g; lane sub = lane&15 covers cols [8*sub, 8*sub+8).
// One VMEM instruction reads 4 different neighbor rows (16 lines) instead of 1 row
// (4 lines): row-read instruction count /4, same bytes/lines. Accumulation stays
// lane-local (no cross-lane reduce). Tail divergence across the 4 rows is predicated;
// adds are unconditional on zero-init regs (bf(0)=0.0f). 2-step unroll keeps 32 lines
// in flight per wave (same as the old 8-batch).

__device__ __forceinline__ void gather_quad(const int* __restrict__ csr, int start, int end,
                                            const uint4* __restrict__ Hu4, int i, int sub,
                                            float acc[8]) {
  uint4 v = Hu4[(size_t)i * 16 + sub];  // self-loop term (each group loads its own row)
  acc[0] = bflo(v.x); acc[1] = bfhi(v.x);
  acc[2] = bflo(v.y); acc[3] = bfhi(v.y);
  acc[4] = bflo(v.z); acc[5] = bfhi(v.z);
  acc[6] = bflo(v.w); acc[7] = bfhi(v.w);
  int e = start;
  while (__ballot(e < end)) {
    uint4 w0 = {0u, 0u, 0u, 0u}, w1 = {0u, 0u, 0u, 0u};
    if (e < end)     w0 = Hu4[(size_t)csr[e] * 16 + sub];
    if (e + 1 < end) w1 = Hu4[(size_t)csr[e + 1] * 16 + sub];
    acc[0] += bflo(w0.x); acc[1] += bfhi(w0.x);
    acc[2] += bflo(w0.y); acc[3] += bfhi(w0.y);
    acc[4] += bflo(w0.z); acc[5] += bfhi(w0.z);
    acc[6] += bflo(w0.w); acc[7] += bfhi(w0.w);
    acc[0] += bflo(w1.x); acc[1] += bfhi(w1.x);
    acc[2] += bflo(w1.y); acc[3] += bfhi(w1.y);
    acc[4] += bflo(w1.z); acc[5] += bfhi(w1.z);
    acc[6] += bflo(w1.w); acc[7] += bfhi(w1.w);
    e += 2;
  }
}

// ---------------- legacy gather helper (fallback path only) ----------------

__device__ __forceinline__ void gather_row_legacy(const int* __restrict__ csr, int start, int end,
                                                  const unsigned* __restrict__ Hu,
                                                  int i, int lane, float& ax, float& ay) {
  unsigned v = Hu[(size_t)i * 64 + lane];
  ax = __uint_as_float(v << 16);
  ay = __uint_as_float(v & 0xFFFF0000u);
  for (int e = start; e < end; ++e) {
    unsigned w = Hu[(size_t)csr[e] * 64 + lane];
    ax += __uint_as_float(w << 16);
    ay += __uint_as_float(w & 0xFFFF0000u);
  }
}

// ---------------- standalone gather: 16 rows/block, quad layout ----------------

__global__ __launch_bounds__(256, 8) void gather_kernel(const int* __restrict__ csr,
                                                        const int* __restrict__ rptr,
                                                        const float* __restrict__ dinv,
                                                        const unsigned* __restrict__ Hu,
                                                        const float* __restrict__ bias,
                                                        const float* __restrict__ perturb,
                                                        float* __restrict__ out, int n) {
  const int lane = threadIdx.x & 63;
  const int g = lane >> 4;
  const int sub = lane & 15;
  int i = (blockIdx.x << 4) + ((threadIdx.x >> 6) << 2) + g;
  bool valid = i < n;
  int ic = valid ? i : (n - 1);
  int start = rptr[ic];
  int end = valid ? rptr[ic + 1] : start;
  float acc[8];
  gather_quad(csr, start, end, (const uint4*)Hu, ic, sub, acc);
  if (valid) {
    float di = dinv[i];
    float4 b0 = *(const float4*)&bias[sub * 8];
    float4 b1 = *(const float4*)&bias[sub * 8 + 4];
    float4 p0 = *(const float4*)&perturb[(size_t)i * D + sub * 8];
    float4 p1 = *(const float4*)&perturb[(size_t)i * D + sub * 8 + 4];
    float4 o0, o1;
    o0.x = b0.x + p0.x + di * acc[0];
    o0.y = b0.y + p0.y + di * acc[1];
    o0.z = b0.z + p0.z + di * acc[2];
    o0.w = b0.w + p0.w + di * acc[3];
    o1.x = b1.x + p1.x + di * acc[4];
    o1.y = b1.y + p1.y + di * acc[5];
    o1.z = b1.z + p1.z + di * acc[6];
    o1.w = b1.w + p1.w + di * acc[7];
    *(float4*)&out[(size_t)i * D + sub * 8] = o0;
    *(float4*)&out[(size_t)i * D + sub * 8 + 4] = o1;
  }
}

// legacy semantics (rend[i-1], rend[i]) for the atomic-fill fallback path
__global__ __launch_bounds__(256, 8) void gather_kernel_old(const int* __restrict__ csr,
                                                            const int* __restrict__ rend,
                                                            const float* __restrict__ dinv,
                                                            const unsigned* __restrict__ Hu,
                                                            const float* __restrict__ bias,
                                                            const float* __restrict__ perturb,
                                                            float* __restrict__ out, int n) {
  int i = (blockIdx.x << 2) + (threadIdx.x >> 6);
  if (i >= n) return;
  int lane = threadIdx.x & 63;
  int start = (i == 0) ? 0 : rend[i - 1];
  float ax, ay;
  gather_row_legacy(csr, start, rend[i], Hu, i, lane, ax, ay);
  float di = dinv[i];
  float2 p = ((const float2*)(perturb + (size_t)i * D))[lane];
  float2 o;
  o.x = bias[2 * lane + 0] + p.x + di * ax;
  o.y = bias[2 * lane + 1] + p.y + di * ay;
  ((float2*)(out + (size_t)i * D))[lane] = o;
}

// ---------------- fused gather1 + GEMM2 (MFMA bf16), quad-layout gather ----------------

#define GG_PITCH 136

__global__ __launch_bounds__(512, 8) void gather_gemm_kernel(
    const int* __restrict__ csr, const int* __restrict__ rptr,
    const float* __restrict__ dinv, const unsigned* __restrict__ Hu,
    const float* __restrict__ bias, const float* __restrict__ perturb,
    const unsigned short* __restrict__ W2bf, unsigned short* __restrict__ H2, int n) {
  __shared__ unsigned short Ts[32 * GG_PITCH];  // 8.5 KB
  const int tid = threadIdx.x;
  const int wv = tid >> 6;
  const int lane = tid & 63;
  const int base = blockIdx.x << 5;  // 32 nodes per block

  // phase 1: quad gather — wave wv covers rows [wv*4, wv*4+4), group g owns one row
  {
    const int g = lane >> 4;
    const int sub = lane & 15;
    int row_in_block = (wv << 2) + g;
    int i = base + row_in_block;
    bool valid = i < n;
    int ic = valid ? i : (n - 1);
    int start = rptr[ic];
    int end = valid ? rptr[ic + 1] : start;
    float acc[8];
    gather_quad(csr, start, end, (const uint4*)Hu, ic, sub, acc);
    if (valid) {
      float di = dinv[i];
      float4 b0 = *(const float4*)&bias[sub * 8];
      float4 b1 = *(const float4*)&bias[sub * 8 + 4];
      float4 p0 = *(const float4*)&perturb[(size_t)i * D + sub * 8];
      float4 p1 = *(const float4*)&perturb[(size_t)i * D + sub * 8 + 4];
      unsigned q0 = (unsigned)f2bf(b0.x + p0.x + di * acc[0]) |
                    ((unsigned)f2bf(b0.y + p0.y + di * acc[1]) << 16);
      unsigned q1 = (unsigned)f2bf(b0.z + p0.z + di * acc[2]) |
                    ((unsigned)f2bf(b0.w + p0.w + di * acc[3]) << 16);
      unsigned q2 = (unsigned)f2bf(b1.x + p1.x + di * acc[4]) |
                    ((unsigned)f2bf(b1.y + p1.y + di * acc[5]) << 16);
      unsigned q3 = (unsigned)f2bf(b1.z + p1.z + di * acc[6]) |
                    ((unsigned)f2bf(b1.w + p1.w + di * acc[7]) << 16);
      uint4 pack = make_uint4(q0, q1, q2, q3);
      *(uint4*)&Ts[row_in_block * GG_PITCH + sub * 8] = pack;
    }
  }
  __syncthreads();

  // phase 2: R[32][128] = Ts @ W2bf^T ; wave wv: m-tile = wv>>2, n-tiles {wv&3, (wv&3)+4}
  const int mt = wv >> 2;
  const int nt0 = wv & 3;
  const int m = lane & 15;
  const int quad = lane >> 4;  // 0..3
  const unsigned short* Wrow0 = W2bf + (size_t)(nt0 * 16 + m) * 128;
  const unsigned short* Wrow1 = W2bf + (size_t)((nt0 + 4) * 16 + m) * 128;
  f32x4 acc0 = {0.f, 0.f, 0.f, 0.f};
  f32x4 acc1 = {0.f, 0.f, 0.f, 0.f};
  #pragma unroll
  for (int s = 0; s < 4; ++s) {
    int k = (s << 5) + (quad << 3);
    bf16x8 a  = *(const bf16x8*)&Ts[(mt * 16 + m) * GG_PITCH + k];
    bf16x8 b0 = *(const bf16x8*)&Wrow0[k];
    bf16x8 b1 = *(const bf16x8*)&Wrow1[k];
    acc0 = __builtin_amdgcn_mfma_f32_16x16x32_bf16(a, b0, acc0, 0, 0, 0);
    acc1 = __builtin_amdgcn_mfma_f32_16x16x32_bf16(a, b1, acc1, 0, 0, 0);
  }
  // C/D layout: col = lane&15, row = quad*4 + reg
  #pragma unroll
  for (int r = 0; r < 4; ++r) {
    int row = mt * 16 + (quad << 2) + r;
    int gg = base + row;
    if (gg < n) {
      float s = dinv[gg];
      H2[(size_t)gg * D + nt0 * 16 + m]       = f2bf(s * acc0[r]);
      H2[(size_t)gg * D + (nt0 + 4) * 16 + m] = f2bf(s * acc1[r]);
    }
  }
}

// ---------------- launch ----------------

extern "C" void kernel_launch(void* const* d_in, const int* in_sizes, int n_in,
                              void* d_out, int out_size, void* d_ws, size_t ws_size,
                              hipStream_t stream) {
  const float* x  = (const float*)d_in[0];
  const int*   ei = (const int*)d_in[1];
  const float* pf = (const float*)d_in[2];
  const float* pl = (const float*)d_in[3];
  const float* W1 = (const float*)d_in[4];
  const float* b1 = (const float*)d_in[5];
  const float* W2 = (const float*)d_in[6];
  const float* b2 = (const float*)d_in[7];
  float* out = (float*)d_out;

  const int n = in_sizes[0] / D;
  const int E = in_sizes[1] / 2;
  const int* src = ei;      // edge_index[0]
  const int* dst = ei + E;  // edge_index[1]

  // workspace layout
  int*   deg       = (int*)d_ws;                     // [n]
  float* dinv      = (float*)d_ws + n;               // [n]
  int*   ptr       = (int*)d_ws + 2 * n;             // [n+1] (start offsets; immutable in fused path)
  int*   blockSums = (int*)d_ws + 3 * n + 1;         // [<=512]
  int*   csr       = (int*)d_ws + 3 * n + 1 + 512;   // [E]
  size_t a1_off = ((size_t)(3 * n + 1 + 512 + E) * 4 + 255) & ~(size_t)255;
  unsigned short* A1 = (unsigned short*)((char*)d_ws + a1_off);
  unsigned short* A2 = A1 + (size_t)n * D;
  unsigned short* W2bf = A2 + (size_t)n * D;     // [128*128] bf16, 32 KB
  unsigned short* W1h  = W2bf + 128 * 128;       // [128*128] bf16, 32 KB
  unsigned short* W1l  = W1h + 128 * 128;        // [128*128] bf16, 32 KB
  int* rank = (int*)A2;                          // [E] aliases A2 (dead until gather_gemm)
  size_t needed = a1_off + (2 * (size_t)n * D + 3 * 128 * 128) * sizeof(unsigned short);
  const bool fused_l2 = (ws_size >= needed);  // constant across calls -> capture-safe

  const int nb_n = (n + 255) / 256;
  const int nb_e4 = (E + 1023) / 1024;
  const int nb_g16 = (n + 15) / 16;
  const int nb_g4 = (n + 3) / 4;

  hipMemsetAsync(deg, 0, (size_t)n * sizeof(int), stream);
  count_deg_kernel<<<nb_e4 + 16, 256, 0, stream>>>(
      dst, E, deg, fused_l2 ? rank : (int*)nullptr, W2,
      fused_l2 ? W2bf : (unsigned short*)nullptr, W1, W1h, W1l);
  scan_blocksum_kernel<<<nb_n, 256, 0, stream>>>(deg, n, blockSums);
  scan_top_kernel<<<1, 512, 0, stream>>>(blockSums, nb_n);
  scan_write_kernel<<<nb_n, 256, 0, stream>>>(deg, n, blockSums, ptr, dinv);

  if (fused_l2) {
    // layer 1: atomic-free CSR fill || Hs1 = dinv*(x@W1^T) via MFMA bf16x3 -> A1
    fused_fill_mfma_kernel<<<FUSED_GRID, 256, 0, stream>>>(src, dst, ptr, rank, csr, E, x,
                                                           W1h, W1l, dinv, A1, n);
    // gather1 + GEMM2 fused -> A2 (rank is dead from here) ; gather2 -> out
    gather_gemm_kernel<<<(n + 31) / 32, 512, 0, stream>>>(csr, ptr, dinv, (const unsigned*)A1,
                                                          b1, pf, W2bf, A2, n);
    gather_kernel<<<nb_g16, 256, 0, stream>>>(csr, ptr, dinv, (const unsigned*)A2, b2, pl, out, n);
  } else {
    // fallback: fp32 VALU gemm, atomic fill (ptr becomes row_end), legacy gathers
    fused_fill_gemm_kernel<<<FUSED_GRID, 256, 0, stream>>>(src, dst, ptr, csr, E, x, W1, dinv, A1, n);
    gather_kernel_old<<<nb_g4, 256, 0, stream>>>(csr, ptr, dinv, (const unsigned*)A1, b1, pf, out, n);
    gemm128_kernel<<<1024, 256, 0, stream>>>(out, W2, dinv, A1, n);
    gather_kernel_old<<<nb_g4, 256, 0, stream>>>(csr, ptr, dinv, (const unsigned*)A1, b2, pl, out, n);
  }
}

// Round 10
// 460.225 us; speedup vs baseline: 1.2684x; 1.0657x over previous
//
#include <hip/hip_runtime.h>
#include <math.h>

#define D 128
#define WS_PAD 132  // 128+4: breaks stride-128 bank pattern, keeps 16B align

typedef short bf16x8 __attribute__((ext_vector_type(8)));  // 8 bf16 in 4 VGPRs
typedef float f32x4 __attribute__((ext_vector_type(4)));

__device__ __forceinline__ unsigned short f2bf(float f) {
  unsigned u = __float_as_uint(f);
  u += 0x7FFFu + ((u >> 16) & 1u);  // round-to-nearest-even
  return (unsigned short)(u >> 16);
}

__device__ __forceinline__ float bf2f(unsigned short h) {
  return __uint_as_float(((unsigned)h) << 16);
}

__device__ __forceinline__ float bflo(unsigned u) { return __uint_as_float(u << 16); }
__device__ __forceinline__ float bfhi(unsigned u) { return __uint_as_float(u & 0xFFFF0000u); }

// ---------------- weight-table prep (16 blocks, runs before count||GEMM1) ----------------

__global__ __launch_bounds__(256) void wprep_kernel(const float* __restrict__ W2,
                                                    unsigned short* __restrict__ W2bf,
                                                    const float* __restrict__ W1,
                                                    unsigned short* __restrict__ W1h,
                                                    unsigned short* __restrict__ W1l) {
  int which = blockIdx.x;  // 0..15
  if (which < 8) {
    int t = which * 256 + threadIdx.x;  // 0..2047
    #pragma unroll
    for (int q = 0; q < 2; ++q) {
      int idx = t + q * 2048;  // float4 index, 0..4095
      float4 w = ((const float4*)W2)[idx];
      ushort4 o;
      o.x = f2bf(w.x); o.y = f2bf(w.y); o.z = f2bf(w.z); o.w = f2bf(w.w);
      ((ushort4*)W2bf)[idx] = o;
    }
  } else {
    int t = (which - 8) * 256 + threadIdx.x;
    #pragma unroll
    for (int q = 0; q < 2; ++q) {
      int idx = t + q * 2048;
      float4 w = ((const float4*)W1)[idx];
      ushort4 hi, lo;
      hi.x = f2bf(w.x); lo.x = f2bf(w.x - bf2f(hi.x));
      hi.y = f2bf(w.y); lo.y = f2bf(w.y - bf2f(hi.y));
      hi.z = f2bf(w.z); lo.z = f2bf(w.z - bf2f(hi.z));
      hi.w = f2bf(w.w); lo.w = f2bf(w.w - bf2f(hi.w));
      ((ushort4*)W1h)[idx] = hi;
      ((ushort4*)W1l)[idx] = lo;
    }
  }
}

// ---------------- fused: degree count + rank (atomic-bound) || GEMM1_raw (MFMA) ----------------
// GEMM1 is graph-independent: H_raw = X @ W1^T (bf16, NO dinv scaling — deferred to the
// gather, which multiplies each row by dinv[src] in fp32). This lets GEMM1 fully overlap
// the atomic-throughput-bound count phase instead of running serially after the scans.

#define FUSED_GRID 2048
#define G1_PITCH 136

__global__ __launch_bounds__(256) void count_gemm1_kernel(
    const int* __restrict__ dst, int E, int* __restrict__ deg, int* __restrict__ rank,
    const float* __restrict__ X,
    const unsigned short* __restrict__ W1h, const unsigned short* __restrict__ W1l,
    unsigned short* __restrict__ H, int n) {
  __shared__ unsigned short Ths[32 * G1_PITCH];  // 8.7 KB
  __shared__ unsigned short Tls[32 * G1_PITCH];  // 8.7 KB
  int sub = blockIdx.x & 7;
  if (sub < 4) {
    // count + rank: 1024 blocks, 4 edges/thread, grid-strided
    int cb = (blockIdx.x >> 3) * 4 + sub;
    const int T4 = 1024 * 256 * 4;
    int t = cb * 256 + threadIdx.x;
    const bool al16 = ((E & 3) == 0);
    for (int e0 = t * 4; e0 < E; e0 += T4) {
      if (e0 + 4 <= E && al16) {
        int4 d = *(const int4*)(dst + e0);
        int r0 = atomicAdd(&deg[d.x], 1);
        int r1 = atomicAdd(&deg[d.y], 1);
        int r2 = atomicAdd(&deg[d.z], 1);
        int r3 = atomicAdd(&deg[d.w], 1);
        *(int4*)(rank + e0) = make_int4(r0, r1, r2, r3);
      } else {
        for (int e = e0; e < E && e < e0 + 4; ++e) rank[e] = atomicAdd(&deg[dst[e]], 1);
      }
    }
  } else {
    // GEMM1_raw: 1024 blocks, 32 rows per tile, grid-strided; bf16x3 fp32-accurate
    int gb = (blockIdx.x >> 3) * 4 + (sub - 4);
    const int tid = threadIdx.x;
    const int wv = tid >> 6;       // 0..3
    const int lane = tid & 63;
    const int m = lane & 15;
    const int quad = lane >> 4;    // 0..3
    const int mt = wv >> 1;        // 0..1  (16-row m-tile)
    const int ntb = (wv & 1) * 4;  // n-tile base: 4 consecutive 16-col tiles
    const int ntiles = (n + 31) >> 5;

    for (int tile = gb; tile < ntiles; tile += 1024) {
      const int row0 = tile << 5;
      const int rows_here = min(32, n - row0);
      __syncthreads();  // protect LDS from previous iteration's readers
      {
        const float4* Xg = (const float4*)(X + (size_t)row0 * D);
        int tmax = rows_here * 32;
        for (int t = tid; t < tmax; t += 256) {
          float4 xv = Xg[t];
          int r = t >> 5, c4 = (t & 31) << 2;
          ushort4 hi, lo;
          hi.x = f2bf(xv.x); lo.x = f2bf(xv.x - bf2f(hi.x));
          hi.y = f2bf(xv.y); lo.y = f2bf(xv.y - bf2f(hi.y));
          hi.z = f2bf(xv.z); lo.z = f2bf(xv.z - bf2f(hi.z));
          hi.w = f2bf(xv.w); lo.w = f2bf(xv.w - bf2f(hi.w));
          *(ushort4*)&Ths[r * G1_PITCH + c4] = hi;
          *(ushort4*)&Tls[r * G1_PITCH + c4] = lo;
        }
      }
      __syncthreads();

      f32x4 acc0 = {0.f, 0.f, 0.f, 0.f};
      f32x4 acc1 = {0.f, 0.f, 0.f, 0.f};
      f32x4 acc2 = {0.f, 0.f, 0.f, 0.f};
      f32x4 acc3 = {0.f, 0.f, 0.f, 0.f};
      #pragma unroll
      for (int s = 0; s < 4; ++s) {
        int k = (s << 5) + (quad << 3);
        bf16x8 ah = *(const bf16x8*)&Ths[(mt * 16 + m) * G1_PITCH + k];
        bf16x8 al = *(const bf16x8*)&Tls[(mt * 16 + m) * G1_PITCH + k];
        bf16x8 bh0 = *(const bf16x8*)&W1h[(size_t)((ntb + 0) * 16 + m) * 128 + k];
        bf16x8 bl0 = *(const bf16x8*)&W1l[(size_t)((ntb + 0) * 16 + m) * 128 + k];
        acc0 = __builtin_amdgcn_mfma_f32_16x16x32_bf16(ah, bh0, acc0, 0, 0, 0);
        acc0 = __builtin_amdgcn_mfma_f32_16x16x32_bf16(al, bh0, acc0, 0, 0, 0);
        acc0 = __builtin_amdgcn_mfma_f32_16x16x32_bf16(ah, bl0, acc0, 0, 0, 0);
        bf16x8 bh1 = *(const bf16x8*)&W1h[(size_t)((ntb + 1) * 16 + m) * 128 + k];
        bf16x8 bl1 = *(const bf16x8*)&W1l[(size_t)((ntb + 1) * 16 + m) * 128 + k];
        acc1 = __builtin_amdgcn_mfma_f32_16x16x32_bf16(ah, bh1, acc1, 0, 0, 0);
        acc1 = __builtin_amdgcn_mfma_f32_16x16x32_bf16(al, bh1, acc1, 0, 0, 0);
        acc1 = __builtin_amdgcn_mfma_f32_16x16x32_bf16(ah, bl1, acc1, 0, 0, 0);
        bf16x8 bh2 = *(const bf16x8*)&W1h[(size_t)((ntb + 2) * 16 + m) * 128 + k];
        bf16x8 bl2 = *(const bf16x8*)&W1l[(size_t)((ntb + 2) * 16 + m) * 128 + k];
        acc2 = __builtin_amdgcn_mfma_f32_16x16x32_bf16(ah, bh2, acc2, 0, 0, 0);
        acc2 = __builtin_amdgcn_mfma_f32_16x16x32_bf16(al, bh2, acc2, 0, 0, 0);
        acc2 = __builtin_amdgcn_mfma_f32_16x16x32_bf16(ah, bl2, acc2, 0, 0, 0);
        bf16x8 bh3 = *(const bf16x8*)&W1h[(size_t)((ntb + 3) * 16 + m) * 128 + k];
        bf16x8 bl3 = *(const bf16x8*)&W1l[(size_t)((ntb + 3) * 16 + m) * 128 + k];
        acc3 = __builtin_amdgcn_mfma_f32_16x16x32_bf16(ah, bh3, acc3, 0, 0, 0);
        acc3 = __builtin_amdgcn_mfma_f32_16x16x32_bf16(al, bh3, acc3, 0, 0, 0);
        acc3 = __builtin_amdgcn_mfma_f32_16x16x32_bf16(ah, bl3, acc3, 0, 0, 0);
      }
      // C/D layout: col = lane&15 (m), row = quad*4 + r  — NO dinv (deferred to gather)
      #pragma unroll
      for (int r = 0; r < 4; ++r) {
        int row = mt * 16 + (quad << 2) + r;
        int g = row0 + row;
        if (g < n) {
          H[(size_t)g * D + (ntb + 0) * 16 + m] = f2bf(acc0[r]);
          H[(size_t)g * D + (ntb + 1) * 16 + m] = f2bf(acc1[r]);
          H[(size_t)g * D + (ntb + 2) * 16 + m] = f2bf(acc2[r]);
          H[(size_t)g * D + (ntb + 3) * 16 + m] = f2bf(acc3[r]);
        }
      }
    }
  }
}

// ---------------- standalone atomic-free CSR fill ----------------

__global__ __launch_bounds__(256) void fill_kernel(const int* __restrict__ src,
                                                   const int* __restrict__ dst,
                                                   const int* __restrict__ ptr,
                                                   const int* __restrict__ rank,
                                                   int* __restrict__ csr, int E) {
  const int T8 = FUSED_GRID * 256 * 8;
  int t = blockIdx.x * 256 + threadIdx.x;
  const bool al16 = ((E & 3) == 0);
  for (int e0 = t * 8; e0 < E; e0 += T8) {
    if (e0 + 8 <= E && al16) {
      int4 d0 = ((const int4*)(dst + e0))[0];
      int4 d1 = ((const int4*)(dst + e0))[1];
      int4 s0 = ((const int4*)(src + e0))[0];
      int4 s1 = ((const int4*)(src + e0))[1];
      int4 r0 = ((const int4*)(rank + e0))[0];
      int4 r1 = ((const int4*)(rank + e0))[1];
      csr[ptr[d0.x] + r0.x] = s0.x;
      csr[ptr[d0.y] + r0.y] = s0.y;
      csr[ptr[d0.z] + r0.z] = s0.z;
      csr[ptr[d0.w] + r0.w] = s0.w;
      csr[ptr[d1.x] + r1.x] = s1.x;
      csr[ptr[d1.y] + r1.y] = s1.y;
      csr[ptr[d1.z] + r1.z] = s1.z;
      csr[ptr[d1.w] + r1.w] = s1.w;
    } else {
      for (int e = e0; e < E && e < e0 + 8; ++e)
        csr[ptr[dst[e]] + rank[e]] = src[e];
    }
  }
}

// ---------------- exclusive prefix scan of deg -> ptr ----------------

__global__ __launch_bounds__(256) void scan_blocksum_kernel(const int* __restrict__ deg, int n,
                                                            int* __restrict__ blockSums) {
  __shared__ int sm[256];
  int t = threadIdx.x;
  int i = blockIdx.x * 256 + t;
  sm[t] = (i < n) ? deg[i] : 0;
  __syncthreads();
  for (int off = 128; off > 0; off >>= 1) {
    if (t < off) sm[t] += sm[t + off];
    __syncthreads();
  }
  if (t == 0) blockSums[blockIdx.x] = sm[0];
}

// single block, 512 threads; nb <= 512
__global__ __launch_bounds__(512) void scan_top_kernel(int* __restrict__ blockSums, int nb) {
  __shared__ int sm[512];
  int t = threadIdx.x;
  int v = (t < nb) ? blockSums[t] : 0;
  sm[t] = v;
  __syncthreads();
  for (int off = 1; off < 512; off <<= 1) {
    int x = (t >= off) ? sm[t - off] : 0;
    __syncthreads();
    sm[t] += x;
    __syncthreads();
  }
  if (t < nb) blockSums[t] = sm[t] - v;  // exclusive
}

// also computes dinv, and writes ptr[n] = E (ptr stays an immutable start-offset array)
__global__ __launch_bounds__(256) void scan_write_kernel(const int* __restrict__ deg, int n,
                                                         const int* __restrict__ blockSums,
                                                         int* __restrict__ ptr,
                                                         float* __restrict__ dinv) {
  __shared__ int sm[256];
  int t = threadIdx.x;
  int i = blockIdx.x * 256 + t;
  int v = (i < n) ? deg[i] : 0;
  sm[t] = v;
  __syncthreads();
  for (int off = 1; off < 256; off <<= 1) {
    int x = (t >= off) ? sm[t - off] : 0;
    __syncthreads();
    sm[t] += x;
    __syncthreads();
  }
  if (i < n) {
    int ex = blockSums[blockIdx.x] + sm[t] - v;
    ptr[i] = ex;                             // exclusive prefix (row start)
    dinv[i] = 1.0f / sqrtf((float)(v + 1));  // +1: self-loop
    if (i == n - 1) ptr[n] = ex + v;         // = E
  }
}

// ---------------- legacy fp32 VALU GEMM body (fallback path only) ----------------

__device__ __forceinline__ void gemm_body(const float* __restrict__ X,
                                          const float* __restrict__ W,
                                          const float* __restrict__ dinv,
                                          unsigned short* __restrict__ H, int n,
                                          int bid, int nblocks,
                                          float* __restrict__ Ws, float* __restrict__ Xs) {
  const int tid = threadIdx.x;
  const int tx = tid & 31;
  const int ty = tid >> 5;
  const int ntiles = (n + 31) >> 5;

  for (int tile = bid; tile < ntiles; tile += nblocks) {
    const int row0 = tile << 5;
    const int rows_here = min(32, n - row0);
    __syncthreads();
    {
      const float4* Xg = (const float4*)(X + (size_t)row0 * D);
      int tmax = rows_here * 32;
      for (int t = tid; t < tmax; t += 256) ((float4*)Xs)[t] = Xg[t];
    }
    float acc[4][4] = {{0.f}};
    #pragma unroll
    for (int kt = 0; kt < 128; kt += 64) {
      __syncthreads();
      for (int t = tid; t < 2048; t += 256) {
        int j  = t >> 4;
        int k4 = (t & 15) << 2;
        float4 w = ((const float4*)W)[j * 32 + (kt >> 2) + (t & 15)];
        Ws[(k4 + 0) * WS_PAD + j] = w.x;
        Ws[(k4 + 1) * WS_PAD + j] = w.y;
        Ws[(k4 + 2) * WS_PAD + j] = w.z;
        Ws[(k4 + 3) * WS_PAD + j] = w.w;
      }
      __syncthreads();
      #pragma unroll 4
      for (int k = 0; k < 64; ++k) {
        float4 w = *(const float4*)&Ws[k * WS_PAD + (tx << 2)];
        #pragma unroll
        for (int r = 0; r < 4; ++r) {
          float xv = Xs[(ty + 8 * r) * 128 + (kt + k)];
          acc[r][0] += xv * w.x;
          acc[r][1] += xv * w.y;
          acc[r][2] += xv * w.z;
          acc[r][3] += xv * w.w;
        }
      }
    }
    #pragma unroll
    for (int r = 0; r < 4; ++r) {
      int row = row0 + ty + 8 * r;
      if (row < n) {
        float s = dinv[row];
        unsigned h0 = f2bf(s * acc[r][0]);
        unsigned h1 = f2bf(s * acc[r][1]);
        unsigned h2 = f2bf(s * acc[r][2]);
        unsigned h3 = f2bf(s * acc[r][3]);
        ((uint2*)(H + (size_t)row * D))[tx] = make_uint2(h0 | (h1 << 16), h2 | (h3 << 16));
      }
    }
  }
}

// ---------------- legacy kernels (fallback path only) ----------------

__global__ __launch_bounds__(256) void count_legacy_kernel(const int* __restrict__ dst, int E,
                                                           int* __restrict__ deg) {
  int e = blockIdx.x * 256 + threadIdx.x;
  if (e < E) atomicAdd(&deg[dst[e]], 1);
}

__global__ __launch_bounds__(256) void fused_fill_gemm_kernel(
    const int* __restrict__ src, const int* __restrict__ dst,
    int* __restrict__ ptr, int* __restrict__ csr, int E,
    const float* __restrict__ X, const float* __restrict__ W,
    const float* __restrict__ dinv, unsigned short* __restrict__ H, int n) {
  __shared__ float Ws[64 * WS_PAD];
  __shared__ float Xs[32 * 128];
  int sub = blockIdx.x & 7;
  if (sub < 2) {
    int fb = (blockIdx.x >> 3) * 2 + sub;
    int stride = 512 * 256;
    for (int e = fb * 256 + threadIdx.x; e < E; e += stride) {
      int d = dst[e];
      int pos = atomicAdd(&ptr[d], 1);
      csr[pos] = src[e];
    }
  } else {
    int gb = (blockIdx.x >> 3) * 6 + (sub - 2);
    gemm_body(X, W, dinv, H, n, gb, 1536, Ws, Xs);
  }
}

__global__ __launch_bounds__(256) void gemm128_kernel(const float* __restrict__ X,
                                                      const float* __restrict__ W,
                                                      const float* __restrict__ dinv,
                                                      unsigned short* __restrict__ H, int n) {
  __shared__ float Ws[64 * WS_PAD];
  __shared__ float Xs[32 * 128];
  gemm_body(X, W, dinv, H, n, blockIdx.x, gridDim.x, Ws, Xs);
}

__device__ __forceinline__ void gather_row_legacy(const int* __restrict__ csr, int start, int end,
                                                  const unsigned* __restrict__ Hu,
                                                  int i, int lane, float& ax, float& ay) {
  unsigned v = Hu[(size_t)i * 64 + lane];
  ax = __uint_as_float(v << 16);
  ay = __uint_as_float(v & 0xFFFF0000u);
  for (int e = start; e < end; ++e) {
    unsigned w = Hu[(size_t)csr[e] * 64 + lane];
    ax += __uint_as_float(w << 16);
    ay += __uint_as_float(w & 0xFFFF0000u);
  }
}

__global__ __launch_bounds__(256, 8) void gather_kernel_old(const int* __restrict__ csr,
                                                            const int* __restrict__ rend,
                                                            const float* __restrict__ dinv,
                                                            const unsigned* __restrict__ Hu,
                                                            const float* __restrict__ bias,
                                                            const float* __restrict__ perturb,
                                                            float* __restrict__ out, int n) {
  int i = (blockIdx.x << 2) + (threadIdx.x >> 6);
  if (i >= n) return;
  int lane = threadIdx.x & 63;
  int start = (i == 0) ? 0 : rend[i - 1];
  float ax, ay;
  gather_row_legacy(csr, start, rend[i], Hu, i, lane, ax, ay);
  float di = dinv[i];
  float2 p = ((const float2*)(perturb + (size_t)i * D))[lane];
  float2 o;
  o.x = bias[2 * lane + 0] + p.x + di * ax;
  o.y = bias[2 * lane + 1] + p.y + di * ay;
  ((float2*)(out + (size_t)i * D))[lane] = o;
}

// ---------------- quad gather helpers: 4 rows per wave, uint4 (16B) lanes ----------------
// Lane group g = lane>>4 owns row i0+g; lane sub = lane&15 covers cols [8*sub, 8*sub+8).

// plain: rows pre-scaled by dinv[src] (used for A2 in gather2)
__device__ __forceinline__ void gather_quad(const int* __restrict__ csr, int start, int end,
                                            const uint4* __restrict__ Hu4, int i, int sub,
                                            float acc[8]) {
  uint4 v = Hu4[(size_t)i * 16 + sub];
  acc[0] = bflo(v.x); acc[1] = bfhi(v.x);
  acc[2] = bflo(v.y); acc[3] = bfhi(v.y);
  acc[4] = bflo(v.z); acc[5] = bfhi(v.z);
  acc[6] = bflo(v.w); acc[7] = bfhi(v.w);
  int e = start;
  while (__ballot(e < end)) {
    uint4 w0 = {0u, 0u, 0u, 0u}, w1 = {0u, 0u, 0u, 0u};
    if (e < end)     w0 = Hu4[(size_t)csr[e] * 16 + sub];
    if (e + 1 < end) w1 = Hu4[(size_t)csr[e + 1] * 16 + sub];
    acc[0] += bflo(w0.x); acc[1] += bfhi(w0.x);
    acc[2] += bflo(w0.y); acc[3] += bfhi(w0.y);
    acc[4] += bflo(w0.z); acc[5] += bfhi(w0.z);
    acc[6] += bflo(w0.w); acc[7] += bfhi(w0.w);
    acc[0] += bflo(w1.x); acc[1] += bfhi(w1.x);
    acc[2] += bflo(w1.y); acc[3] += bfhi(w1.y);
    acc[4] += bflo(w1.z); acc[5] += bfhi(w1.z);
    acc[6] += bflo(w1.w); acc[7] += bfhi(w1.w);
    e += 2;
  }
}

// weighted: rows are RAW (no dinv); multiply each by dinv[src] in fp32 during gather.
// dinv is 400KB (L2-resident); its load is parallel to the 600cy row fetch -> no chain ext.
__device__ __forceinline__ void gather_quad_w(const int* __restrict__ csr, int start, int end,
                                              const uint4* __restrict__ Hu4,
                                              const float* __restrict__ dinv,
                                              int i, int sub, float acc[8]) {
  float ds = dinv[i];
  uint4 v = Hu4[(size_t)i * 16 + sub];
  acc[0] = ds * bflo(v.x); acc[1] = ds * bfhi(v.x);
  acc[2] = ds * bflo(v.y); acc[3] = ds * bfhi(v.y);
  acc[4] = ds * bflo(v.z); acc[5] = ds * bfhi(v.z);
  acc[6] = ds * bflo(v.w); acc[7] = ds * bfhi(v.w);
  int e = start;
  while (__ballot(e < end)) {
    uint4 w0 = {0u, 0u, 0u, 0u}, w1 = {0u, 0u, 0u, 0u};
    float d0 = 0.f, d1 = 0.f;
    if (e < end)     { int j = csr[e];     w0 = Hu4[(size_t)j * 16 + sub]; d0 = dinv[j]; }
    if (e + 1 < end) { int j = csr[e + 1]; w1 = Hu4[(size_t)j * 16 + sub]; d1 = dinv[j]; }
    acc[0] += d0 * bflo(w0.x); acc[1] += d0 * bfhi(w0.x);
    acc[2] += d0 * bflo(w0.y); acc[3] += d0 * bfhi(w0.y);
    acc[4] += d0 * bflo(w0.z); acc[5] += d0 * bfhi(w0.z);
    acc[6] += d0 * bflo(w0.w); acc[7] += d0 * bfhi(w0.w);
    acc[0] += d1 * bflo(w1.x); acc[1] += d1 * bfhi(w1.x);
    acc[2] += d1 * bflo(w1.y); acc[3] += d1 * bfhi(w1.y);
    acc[4] += d1 * bflo(w1.z); acc[5] += d1 * bfhi(w1.z);
    acc[6] += d1 * bflo(w1.w); acc[7] += d1 * bfhi(w1.w);
    e += 2;
  }
}

// ---------------- standalone gather (gather2): 16 rows/block, quad layout, A2 prescaled ----------------

__global__ __launch_bounds__(256, 8) void gather_kernel(const int* __restrict__ csr,
                                                        const int* __restrict__ rptr,
                                                        const float* __restrict__ dinv,
                                                        const unsigned* __restrict__ Hu,
                                                        const float* __restrict__ bias,
                                                        const float* __restrict__ perturb,
                                                        float* __restrict__ out, int n) {
  const int lane = threadIdx.x & 63;
  const int g = lane >> 4;
  const int sub = lane & 15;
  int i = (blockIdx.x << 4) + ((threadIdx.x >> 6) << 2) + g;
  bool valid = i < n;
  int ic = valid ? i : (n - 1);
  int start = rptr[ic];
  int end = valid ? rptr[ic + 1] : start;
  float acc[8];
  gather_quad(csr, start, end, (const uint4*)Hu, ic, sub, acc);
  if (valid) {
    float di = dinv[i];
    float4 b0 = *(const float4*)&bias[sub * 8];
    float4 b1 = *(const float4*)&bias[sub * 8 + 4];
    float4 p0 = *(const float4*)&perturb[(size_t)i * D + sub * 8];
    float4 p1 = *(const float4*)&perturb[(size_t)i * D + sub * 8 + 4];
    float4 o0, o1;
    o0.x = b0.x + p0.x + di * acc[0];
    o0.y = b0.y + p0.y + di * acc[1];
    o0.z = b0.z + p0.z + di * acc[2];
    o0.w = b0.w + p0.w + di * acc[3];
    o1.x = b1.x + p1.x + di * acc[4];
    o1.y = b1.y + p1.y + di * acc[5];
    o1.z = b1.z + p1.z + di * acc[6];
    o1.w = b1.w + p1.w + di * acc[7];
    *(float4*)&out[(size_t)i * D + sub * 8] = o0;
    *(float4*)&out[(size_t)i * D + sub * 8 + 4] = o1;
  }
}

// ---------------- fused gather1 (dinv-weighted) + GEMM2 (MFMA bf16) ----------------

#define GG_PITCH 136

__global__ __launch_bounds__(512, 8) void gather_gemm_kernel(
    const int* __restrict__ csr, const int* __restrict__ rptr,
    const float* __restrict__ dinv, const unsigned* __restrict__ Hu,
    const float* __restrict__ bias, const float* __restrict__ perturb,
    const unsigned short* __restrict__ W2bf, unsigned short* __restrict__ H2, int n) {
  __shared__ unsigned short Ts[32 * GG_PITCH];  // 8.5 KB
  const int tid = threadIdx.x;
  const int wv = tid >> 6;
  const int lane = tid & 63;
  const int base = blockIdx.x << 5;  // 32 nodes per block

  // phase 1: weighted quad gather over RAW A1 — wave wv covers rows [wv*4, wv*4+4)
  {
    const int g = lane >> 4;
    const int sub = lane & 15;
    int row_in_block = (wv << 2) + g;
    int i = base + row_in_block;
    bool valid = i < n;
    int ic = valid ? i : (n - 1);
    int start = rptr[ic];
    int end = valid ? rptr[ic + 1] : start;
    float acc[8];
    gather_quad_w(csr, start, end, (const uint4*)Hu, dinv, ic, sub, acc);
    if (valid) {
      float di = dinv[i];
      float4 b0 = *(const float4*)&bias[sub * 8];
      float4 b1 = *(const float4*)&bias[sub * 8 + 4];
      float4 p0 = *(const float4*)&perturb[(size_t)i * D + sub * 8];
      float4 p1 = *(const float4*)&perturb[(size_t)i * D + sub * 8 + 4];
      unsigned q0 = (unsigned)f2bf(b0.x + p0.x + di * acc[0]) |
                    ((unsigned)f2bf(b0.y + p0.y + di * acc[1]) << 16);
      unsigned q1 = (unsigned)f2bf(b0.z + p0.z + di * acc[2]) |
                    ((unsigned)f2bf(b0.w + p0.w + di * acc[3]) << 16);
      unsigned q2 = (unsigned)f2bf(b1.x + p1.x + di * acc[4]) |
                    ((unsigned)f2bf(b1.y + p1.y + di * acc[5]) << 16);
      unsigned q3 = (unsigned)f2bf(b1.z + p1.z + di * acc[6]) |
                    ((unsigned)f2bf(b1.w + p1.w + di * acc[7]) << 16);
      uint4 pack = make_uint4(q0, q1, q2, q3);
      *(uint4*)&Ts[row_in_block * GG_PITCH + sub * 8] = pack;
    }
  }
  __syncthreads();

  // phase 2: R[32][128] = Ts @ W2bf^T ; wave wv: m-tile = wv>>2, n-tiles {wv&3, (wv&3)+4}
  const int mt = wv >> 2;
  const int nt0 = wv & 3;
  const int m = lane & 15;
  const int quad = lane >> 4;  // 0..3
  const unsigned short* Wrow0 = W2bf + (size_t)(nt0 * 16 + m) * 128;
  const unsigned short* Wrow1 = W2bf + (size_t)((nt0 + 4) * 16 + m) * 128;
  f32x4 acc0 = {0.f, 0.f, 0.f, 0.f};
  f32x4 acc1 = {0.f, 0.f, 0.f, 0.f};
  #pragma unroll
  for (int s = 0; s < 4; ++s) {
    int k = (s << 5) + (quad << 3);
    bf16x8 a  = *(const bf16x8*)&Ts[(mt * 16 + m) * GG_PITCH + k];
    bf16x8 b0 = *(const bf16x8*)&Wrow0[k];
    bf16x8 b1 = *(const bf16x8*)&Wrow1[k];
    acc0 = __builtin_amdgcn_mfma_f32_16x16x32_bf16(a, b0, acc0, 0, 0, 0);
    acc1 = __builtin_amdgcn_mfma_f32_16x16x32_bf16(a, b1, acc1, 0, 0, 0);
  }
  // C/D layout: col = lane&15, row = quad*4 + reg ; A2 stays prescaled by dinv
  #pragma unroll
  for (int r = 0; r < 4; ++r) {
    int row = mt * 16 + (quad << 2) + r;
    int gg = base + row;
    if (gg < n) {
      float s = dinv[gg];
      H2[(size_t)gg * D + nt0 * 16 + m]       = f2bf(s * acc0[r]);
      H2[(size_t)gg * D + (nt0 + 4) * 16 + m] = f2bf(s * acc1[r]);
    }
  }
}

// ---------------- launch ----------------

extern "C" void kernel_launch(void* const* d_in, const int* in_sizes, int n_in,
                              void* d_out, int out_size, void* d_ws, size_t ws_size,
                              hipStream_t stream) {
  const float* x  = (const float*)d_in[0];
  const int*   ei = (const int*)d_in[1];
  const float* pf = (const float*)d_in[2];
  const float* pl = (const float*)d_in[3];
  const float* W1 = (const float*)d_in[4];
  const float* b1 = (const float*)d_in[5];
  const float* W2 = (const float*)d_in[6];
  const float* b2 = (const float*)d_in[7];
  float* out = (float*)d_out;

  const int n = in_sizes[0] / D;
  const int E = in_sizes[1] / 2;
  const int* src = ei;      // edge_index[0]
  const int* dst = ei + E;  // edge_index[1]

  // workspace layout
  int*   deg       = (int*)d_ws;                     // [n]
  float* dinv      = (float*)d_ws + n;               // [n]
  int*   ptr       = (int*)d_ws + 2 * n;             // [n+1] (start offsets; immutable in fused path)
  int*   blockSums = (int*)d_ws + 3 * n + 1;         // [<=512]
  int*   csr       = (int*)d_ws + 3 * n + 1 + 512;   // [E]
  size_t a1_off = ((size_t)(3 * n + 1 + 512 + E) * 4 + 255) & ~(size_t)255;
  unsigned short* A1 = (unsigned short*)((char*)d_ws + a1_off);
  unsigned short* A2 = A1 + (size_t)n * D;
  unsigned short* W2bf = A2 + (size_t)n * D;     // [128*128] bf16, 32 KB
  unsigned short* W1h  = W2bf + 128 * 128;       // [128*128] bf16, 32 KB
  unsigned short* W1l  = W1h + 128 * 128;        // [128*128] bf16, 32 KB
  int* rank = (int*)A2;                          // [E] aliases A2 (dead until gather_gemm)
  size_t needed = a1_off + (2 * (size_t)n * D + 3 * 128 * 128) * sizeof(unsigned short);
  const bool fused_l2 = (ws_size >= needed);  // constant across calls -> capture-safe

  const int nb_n = (n + 255) / 256;
  const int nb_e = (E + 255) / 256;
  const int nb_g16 = (n + 15) / 16;
  const int nb_g4 = (n + 3) / 4;

  hipMemsetAsync(deg, 0, (size_t)n * sizeof(int), stream);

  if (fused_l2) {
    // W tables first (tiny); then count+rank || GEMM1_raw fully overlapped
    wprep_kernel<<<16, 256, 0, stream>>>(W2, W2bf, W1, W1h, W1l);
    count_gemm1_kernel<<<FUSED_GRID, 256, 0, stream>>>(dst, E, deg, rank, x, W1h, W1l, A1, n);
    scan_blocksum_kernel<<<nb_n, 256, 0, stream>>>(deg, n, blockSums);
    scan_top_kernel<<<1, 512, 0, stream>>>(blockSums, nb_n);
    scan_write_kernel<<<nb_n, 256, 0, stream>>>(deg, n, blockSums, ptr, dinv);
    // atomic-free fill (standalone, ~bandwidth-bound)
    fill_kernel<<<FUSED_GRID, 256, 0, stream>>>(src, dst, ptr, rank, csr, E);
    // gather1 (dinv-weighted over raw A1) + GEMM2 -> A2 ; gather2 -> out
    gather_gemm_kernel<<<(n + 31) / 32, 512, 0, stream>>>(csr, ptr, dinv, (const unsigned*)A1,
                                                          b1, pf, W2bf, A2, n);
    gather_kernel<<<nb_g16, 256, 0, stream>>>(csr, ptr, dinv, (const unsigned*)A2, b2, pl, out, n);
  } else {
    // fallback: fp32 VALU gemm, atomic fill (ptr becomes row_end), legacy gathers
    count_legacy_kernel<<<nb_e, 256, 0, stream>>>(dst, E, deg);
    scan_blocksum_kernel<<<nb_n, 256, 0, stream>>>(deg, n, blockSums);
    scan_top_kernel<<<1, 512, 0, stream>>>(blockSums, nb_n);
    scan_write_kernel<<<nb_n, 256, 0, stream>>>(deg, n, blockSums, ptr, dinv);
    fused_fill_gemm_kernel<<<FUSED_GRID, 256, 0, stream>>>(src, dst, ptr, csr, E, x, W1, dinv, A1, n);
    gather_kernel_old<<<nb_g4, 256, 0, stream>>>(csr, ptr, dinv, (const unsigned*)A1, b1, pf, out, n);
    gemm128_kernel<<<1024, 256, 0, stream>>>(out, W2, dinv, A1, n);
    gather_kernel_old<<<nb_g4, 256, 0, stream>>>(csr, ptr, dinv, (const unsigned*)A1, b2, pl, out, n);
  }
}